// Round 3
// baseline (192.970 us; speedup 1.0000x reference)
//
#include <hip/hip_runtime.h>
#include <hip/hip_bf16.h>
#include <cstdint>

#define DEVI __device__ __forceinline__

typedef __attribute__((ext_vector_type(8))) short bf16x8;
typedef __attribute__((ext_vector_type(4))) short bf16x4;
typedef __attribute__((ext_vector_type(4))) float f32x4;

DEVI short f2bf(float f) {
  unsigned u = __float_as_uint(f);
  u += 0x7fff + ((u >> 16) & 1);   // round-to-nearest-even
  return (short)(u >> 16);
}
DEVI float bf2f(short s) { return __uint_as_float(((unsigned)(unsigned short)s) << 16); }

DEVI void gl_lds16(const short* g, short* l) {
  __builtin_amdgcn_global_load_lds((const __attribute__((address_space(1))) unsigned*)g,
                                   (__attribute__((address_space(3))) unsigned*)l, 16, 0, 0);
}

// ===========================================================================
// 128x128 GEMM, BK=64 (R15-proven base). R19:
//  - 8-phase 256^2 qkproj RETIRED: at K=16 steps / grid 256 (1 block/CU,
//    2 lockstep waves/SIMD) it never leaves the pipeline ramp (8700 cyc/step
//    vs 3300 at 4k^3, all pipes <25%). gemm_bt gets 2 independent blocks/CU
//    + backfill queue -> cross-block latency hiding (m114).
//  - BIASMODE 2: two-segment col bias/scale (Q: bq & *scale; K: bk & *1).
//  - PV now writes FINAL fp32 out (P @ z, z = y@Wvo precomputed): the
//    associativity fusion kills ctxY round-trip + the old outproj dispatch.
// MODE 0 plain / 2 causal-PV (kend=(bi+1)*128) / 4 triangular (live causal
// tiles only). DECODE 3: complement bi on (z&2) to balance resident pairing.
// ===========================================================================
constexpr int BM = 128, BN = 128, BK = 64;

template<int MODE, int BIASMODE, bool OUTF32, int DECODE>
__global__ __launch_bounds__(256, 2)
void gemm_bt(const short* __restrict__ A, const short* __restrict__ B,
             void* __restrict__ Cv, const float* __restrict__ b0,
             const float* __restrict__ b1, float scale,
             int K, int lda, int ldb, int ldc,
             long long sA, long long sB, long long sC, int tdim)
{
  const int nwg = gridDim.x, orig = blockIdx.x;
  const int q8 = nwg >> 3, r8 = nwg & 7;
  const int xcd = orig & 7, idx8 = orig >> 3;
  const int wg = (xcd < r8 ? xcd * (q8 + 1) : r8 * (q8 + 1) + (xcd - r8) * q8) + idx8;
  const int bz = blockIdx.z;

  int bi, bj;
  if constexpr (MODE == 4) {
    // triangular decode: wg = bi*(bi+1)/2 + bj, bj <= bi
    int b = (int)((__fsqrt_rn(8.f * (float)wg + 1.f) - 1.f) * 0.5f);
    if ((b + 1) * (b + 2) / 2 <= wg) ++b;          // float-edge fixup
    if (b * (b + 1) / 2 > wg) --b;
    bi = b; bj = wg - b * (b + 1) / 2;
  } else {
    bi = wg / tdim;
    bj = wg - bi * tdim;
    if constexpr (DECODE == 3) { if (bz & 2) bi = (nwg / tdim) - 1 - bi; }
  }

  A += (long long)bz * sA;
  B += (long long)bz * sB;

  __shared__ __align__(16) short lA[2][BM * BK];   // 2 x 16 KB
  __shared__ __align__(16) short lB[2][BN * BK];   // 2 x 16 KB

  const int tid = threadIdx.x, wave = tid >> 6, lane = tid & 63;
  const int wr = wave >> 1, wc = wave & 1;
  const int brow = bi * BM, bcol = bj * BN;
  const int fr = lane & 15, h = lane >> 4;

  const int ck0 = ((h ^ (fr & 7))) * 8;            // 128B-row swizzle, ks=0
  const int swc = ((tid & 7) ^ ((tid >> 3) & 7)) * 8;
  const short* pA = A + (long long)(brow + (tid >> 3)) * lda + swc;
  const short* pB = B + (long long)(bcol + (tid >> 3)) * ldb + swc;

  f32x4 acc[4][4] = {};
  const int kend = (MODE == 2) ? (bi + 1) * BM : K;
  const int nt = kend / BK;

  auto stage = [&](int buf, int t) {
    const long long ko = (long long)t * BK;
#pragma unroll
    for (int j = 0; j < 4; ++j)
      gl_lds16(pA + (long long)(j * 32) * lda + ko, &lA[buf][j * 2048 + tid * 8]);
#pragma unroll
    for (int j = 0; j < 4; ++j)
      gl_lds16(pB + (long long)(j * 32) * ldb + ko, &lB[buf][j * 2048 + tid * 8]);
  };

  stage(0, 0);
  __syncthreads();

  int cur = 0;
  for (int t = 0; t < nt; ++t) {
    if (t + 1 < nt) stage(cur ^ 1, t + 1);

    const short* bufA = lA[cur];
    const short* bufB = lB[cur];
    bf16x8 af[4], bg[4];
#pragma unroll
    for (int m = 0; m < 4; ++m)
      af[m] = *(const bf16x8*)&bufA[(wr * 64 + m * 16 + fr) * BK + ck0];
#pragma unroll
    for (int n = 0; n < 4; ++n)
      bg[n] = *(const bf16x8*)&bufB[(wc * 64 + n * 16 + fr) * BK + ck0];
#pragma unroll
    for (int m = 0; m < 4; ++m)
#pragma unroll
      for (int n = 0; n < 4; ++n)
        acc[m][n] = __builtin_amdgcn_mfma_f32_16x16x32_bf16(af[m], bg[n], acc[m][n], 0, 0, 0);
#pragma unroll
    for (int m = 0; m < 4; ++m)
      af[m] = *(const bf16x8*)&bufA[((wr * 64 + m * 16 + fr) * BK + ck0) ^ 32];
#pragma unroll
    for (int n = 0; n < 4; ++n)
      bg[n] = *(const bf16x8*)&bufB[((wc * 64 + n * 16 + fr) * BK + ck0) ^ 32];
#pragma unroll
    for (int m = 0; m < 4; ++m)
#pragma unroll
      for (int n = 0; n < 4; ++n)
        acc[m][n] = __builtin_amdgcn_mfma_f32_16x16x32_bf16(af[m], bg[n], acc[m][n], 0, 0, 0);

    __syncthreads();
    cur ^= 1;
  }

  // epilogue, n-innermost (64B line completed in 4 consecutive stores)
  const int lrow = h * 4;
  float* Cf = (float*)Cv + (long long)bz * sC;
  short* Cs = (short*)Cv + (long long)bz * sC;
  int colg[4]; float bvv[4], scl[4];
#pragma unroll
  for (int n = 0; n < 4; ++n) {
    colg[n] = bcol + wc * 64 + n * 16 + fr;
    if constexpr (BIASMODE == 1) { bvv[n] = b0[colg[n]]; scl[n] = scale; }
    else if constexpr (BIASMODE == 2) {
      const int seg = colg[n] >> 10;
      bvv[n] = seg ? b1[colg[n] & 1023] : b0[colg[n] & 1023];
      scl[n] = seg ? 1.f : scale;
    } else { bvv[n] = 0.f; scl[n] = scale; }
  }
#pragma unroll
  for (int m = 0; m < 4; ++m) {
    const int row = brow + wr * 64 + m * 16 + lrow;
#pragma unroll
    for (int j = 0; j < 4; ++j) {
#pragma unroll
      for (int n = 0; n < 4; ++n) {
        const float val = (acc[m][n][j] + bvv[n]) * scl[n];
        if constexpr (OUTF32) Cf[(long long)(row + j) * ldc + colg[n]] = val;
        else                  Cs[(long long)(row + j) * ldc + colg[n]] = f2bf(val);
      }
    }
  }
}

// ---------------------------------------------------------------------------
// Causal-trimmed softmax: row t has t+1 live cols; load only chunks c0<=t,
// store only c0<roundup128(t+1) (keeps required zeros in the diagonal tile).
__global__ __launch_bounds__(256)
void softmax_causal_bf16_k(short* __restrict__ sc)
{
  const int T = 2048;
  const long long row = blockIdx.x;
  const int t = (int)(row & (T - 1));
  short* ps = sc + row * (long long)T;
  const int tid = threadIdx.x, wave = tid >> 6, lane = tid & 63;
  const int c0 = tid * 8;
  const int wlim = ((t >> 7) + 1) << 7;   // exclusive write limit, 128-aligned

  bf16x8 v = {};
  if (c0 <= t) v = *(const bf16x8*)&ps[c0];
  float x[8];
#pragma unroll
  for (int j = 0; j < 8; ++j) x[j] = bf2f(v[j]);

  float mx = -3.0e38f;
#pragma unroll
  for (int j = 0; j < 8; ++j) if (c0 + j <= t) mx = fmaxf(mx, x[j]);
#pragma unroll
  for (int o = 32; o; o >>= 1) mx = fmaxf(mx, __shfl_xor(mx, o, 64));
  __shared__ float red[8];
  if (lane == 0) red[wave] = mx;
  __syncthreads();
  const float M = fmaxf(fmaxf(red[0], red[1]), fmaxf(red[2], red[3]));

  float e[8], s = 0.f;
#pragma unroll
  for (int j = 0; j < 8; ++j) { e[j] = (c0 + j <= t) ? __expf(x[j] - M) : 0.f; s += e[j]; }
#pragma unroll
  for (int o = 32; o; o >>= 1) s += __shfl_xor(s, o, 64);
  if (lane == 0) red[4 + wave] = s;
  __syncthreads();
  const float inv = 1.f / (red[4] + red[5] + red[6] + red[7]);

  if (c0 < wlim) {
    bf16x8 ov;
#pragma unroll
    for (int j = 0; j < 8; ++j) ov[j] = f2bf(e[j] * inv);
    *(bf16x8*)&ps[c0] = ov;
  }
}

// ---------------------------------------------------------------------------
// y fp32 -> bf16, plain vectorized convert (yT no longer needed: PV consumes
// zT = (y@Wvo)^T instead of y^T).
__global__ __launch_bounds__(256)
void cvt_y_k(const float* __restrict__ y, short* __restrict__ ybf)
{
  const long long i = (long long)blockIdx.x * 256 + threadIdx.x;  // 8-elem chunk
  const float4 v0 = ((const float4*)y)[i * 2];
  const float4 v1 = ((const float4*)y)[i * 2 + 1];
  bf16x8 o;
  o[0] = f2bf(v0.x); o[1] = f2bf(v0.y); o[2] = f2bf(v0.z); o[3] = f2bf(v0.w);
  o[4] = f2bf(v1.x); o[5] = f2bf(v1.y); o[6] = f2bf(v1.z); o[7] = f2bf(v1.w);
  ((bf16x8*)ybf)[i] = o;
}

// z=0,1,2: W -> W^T bf16 (Wq,Wk,Wo); z=3: Wv -> plain bf16 (no transpose)
__global__ __launch_bounds__(256)
void cvt_w_all_k(const float* __restrict__ w0, const float* __restrict__ w1,
                 const float* __restrict__ w2, const float* __restrict__ w3,
                 short* __restrict__ o0, short* __restrict__ o1,
                 short* __restrict__ o2, short* __restrict__ o3)
{
  const int tx = threadIdx.x & 31, ty = threadIdx.x >> 5;
  const int r0 = blockIdx.y * 32, c0 = blockIdx.x * 32;
  if (blockIdx.z == 3) {          // plain convert
#pragma unroll
    for (int i = 0; i < 4; ++i)
      o3[(long long)(r0 + ty + 8 * i) * 1024 + c0 + tx] =
          f2bf(w3[(long long)(r0 + ty + 8 * i) * 1024 + c0 + tx]);
    return;
  }
  const float* in = (blockIdx.z == 0) ? w0 : (blockIdx.z == 1 ? w1 : w2);
  short* out      = (blockIdx.z == 0) ? o0 : (blockIdx.z == 1 ? o1 : o2);
  __shared__ float tile[32][33];
#pragma unroll
  for (int i = 0; i < 4; ++i)
    tile[ty + 8 * i][tx] = in[(long long)(r0 + ty + 8 * i) * 1024 + c0 + tx];
  __syncthreads();
#pragma unroll
  for (int i = 0; i < 4; ++i)
    out[(long long)(c0 + ty + 8 * i) * 1024 + r0 + tx] = f2bf(tile[tx][ty + 8 * i]);
}

// outb[j] = bo[j]
__global__ __launch_bounds__(256)
void bias_init_k(const float* __restrict__ bo, float* __restrict__ outb)
{
  const int j = blockIdx.x * 256 + threadIdx.x;
  outb[j] = bo[j];
}

// outb[j] += sum over 16 rows of bv[r]*Wo[r][j]
__global__ __launch_bounds__(256)
void bias_fold_k(const float* __restrict__ bv, const float* __restrict__ Wo,
                 float* __restrict__ outb)
{
  const int r0 = blockIdx.x * 16;
  const int c4 = threadIdx.x;
  float4 acc = make_float4(0.f, 0.f, 0.f, 0.f);
  for (int r = 0; r < 16; ++r) {
    const float s = bv[r0 + r];
    const float4 w = ((const float4*)(Wo + (long long)(r0 + r) * 1024))[c4];
    acc.x += s * w.x; acc.y += s * w.y; acc.z += s * w.z; acc.w += s * w.w;
  }
  atomicAdd(&outb[c4 * 4 + 0], acc.x);
  atomicAdd(&outb[c4 * 4 + 1], acc.y);
  atomicAdd(&outb[c4 * 4 + 2], acc.z);
  atomicAdd(&outb[c4 * 4 + 3], acc.w);
}

// WvoT = bf16( part0 + part1 + part2 + part3 )  (split-K combine, 1M elems)
__global__ __launch_bounds__(256)
void combine4_k(const float* __restrict__ p, short* __restrict__ out)
{
  const long long i = (long long)blockIdx.x * 256 + threadIdx.x;  // float4 idx
  const float4 a = ((const float4*)p)[i];
  const float4 b = ((const float4*)(p + 1048576))[i];
  const float4 c = ((const float4*)(p + 2097152))[i];
  const float4 d = ((const float4*)(p + 3145728))[i];
  bf16x4 o;
  o[0] = f2bf(a.x + b.x + c.x + d.x);
  o[1] = f2bf(a.y + b.y + c.y + d.y);
  o[2] = f2bf(a.z + b.z + c.z + d.z);
  o[3] = f2bf(a.w + b.w + c.w + d.w);
  ((bf16x4*)out)[i] = o;
}

// ---------------------------------------------------------------------------
extern "C" void kernel_launch(void* const* d_in, const int* in_sizes, int n_in,
                              void* d_out, int out_size, void* d_ws, size_t ws_size,
                              hipStream_t stream)
{
  (void)in_sizes; (void)n_in; (void)out_size; (void)ws_size;
  const float* y  = (const float*)d_in[0];
  const float* Wq = (const float*)d_in[1];
  const float* bq = (const float*)d_in[2];
  const float* Wk = (const float*)d_in[3];
  const float* bk = (const float*)d_in[4];
  const float* Wv = (const float*)d_in[5];
  const float* bv = (const float*)d_in[6];
  const float* Wo = (const float*)d_in[7];
  const float* bo = (const float*)d_in[8];
  float* out = (float*)d_out;

  const int T = 2048, H = 1024, DK = 1024;
  const long long MT = 8192;                          // B*T

  // workspace layout (shorts); ~128 MB
  short* ws    = (short*)d_ws;
  short* ybf   = ws;                                  // MT*1024
  short* WqkT  = ybf + MT * H;                        // 2*1024*1024
  short* WoT   = WqkT + 2ll * 1024 * 1024;            // 1024*1024
  short* WvBf  = WoT + 1024ll * 1024;                 // 1024*1024
  short* WvoT  = WvBf + 1024ll * 1024;                // 1024*1024 ((Wv@Wo)^T)
  short* QKb   = WvoT + 1024ll * 1024;                // MT*2048 (Q | K)
  short* zT    = QKb + MT * 2048;                     // 1024 x 8192 ((y@Wvo)^T)
  short* scores = zT + MT * 1024;                     // 4*T*T bf16
  float* bvWoBo = (float*)(scores + 4ll * T * T);     // 1024 fp32
  float* wvoPart = bvWoBo + 1024;                     // 4 x 1M fp32 (16MB)

  // 1. conversions + bias fold (bvWoBo = bv@Wo + bo)
  cvt_y_k<<<4096, 256, 0, stream>>>(y, ybf);
  cvt_w_all_k<<<dim3(32, 32, 4), 256, 0, stream>>>(
      Wq, Wk, Wo, Wv, WqkT, WqkT + 1024ll * 1024, WoT, WvBf);
  bias_init_k<<<4, 256, 0, stream>>>(bo, bvWoBo);
  bias_fold_k<<<64, 256, 0, stream>>>(bv, Wo, bvWoBo);

  // 2. WvoT = (Wv@Wo)^T via A=WoT, B=WvBf — split-K x4, fp32 partials
  gemm_bt<0, 0, true, 0><<<dim3(64, 1, 4), 256, 0, stream>>>(
      WoT, WvBf, wvoPart, nullptr, nullptr, 1.f, 256, 1024, 1024, 1024,
      256, 256, 1048576, 8);
  combine4_k<<<1024, 256, 0, stream>>>(wvoPart, WvoT);

  // 3. QK projection as gemm_bt (1024 wgs = 2 resident/CU + backfill;
  //    BIASMODE 2: Q seg gets bq & /32, K seg gets bk)
  gemm_bt<0, 2, false, 0><<<dim3(64 * 16, 1, 1), 256, 0, stream>>>(
      ybf, WqkT, QKb, bq, bk, 1.f / 32.f, H, H, H, 2048, 0, 0, 0, 16);

  // 4. zT = (y @ WvWo)^T = WvoT @ y^T : A=WvoT [1024x1024], B=ybf [8192x1024]
  gemm_bt<0, 0, false, 0><<<dim3(512, 1, 1), 256, 0, stream>>>(
      WvoT, ybf, zT, nullptr, nullptr, 1.f, 1024, 1024, 1024, 8192,
      0, 0, 0, 64);

  // 5. scores = Q @ K^T -> bf16, TRIANGULAR grid (136 live tiles/batch)
  gemm_bt<4, 0, false, 0><<<dim3(136, 1, 4), 256, 0, stream>>>(
      QKb, QKb + 1024, scores, nullptr, nullptr, 1.f, DK, 2048, 2048, T,
      (long long)T * 2048, (long long)T * 2048, (long long)T * T, 16);

  // 6. causal softmax in place (trimmed to live columns)
  softmax_causal_bf16_k<<<(int)MT, 256, 0, stream>>>(scores);

  // 7. out = P @ z + (bv@Wo + bo)  — FINAL output, fp32 + bias, causal kend,
  //    z-complement pairing balance
  gemm_bt<2, 1, true, 3><<<dim3(16 * 8, 1, 4), 256, 0, stream>>>(
      scores, zT, out, bvWoBo, nullptr, 1.f, T, T, 8192, 1024,
      (long long)T * T, 2048, 2048ll * 1024, 8);
}

// Round 4
// 192.544 us; speedup vs baseline: 1.0022x; 1.0022x over previous
//
#include <hip/hip_runtime.h>
#include <hip/hip_bf16.h>
#include <cstdint>

#define DEVI __device__ __forceinline__

typedef __attribute__((ext_vector_type(8))) short bf16x8;
typedef __attribute__((ext_vector_type(4))) short bf16x4;
typedef __attribute__((ext_vector_type(4))) float f32x4;

DEVI short f2bf(float f) {
  unsigned u = __float_as_uint(f);
  u += 0x7fff + ((u >> 16) & 1);   // round-to-nearest-even
  return (short)(u >> 16);
}
DEVI float bf2f(short s) { return __uint_as_float(((unsigned)(unsigned short)s) << 16); }

DEVI void gl_lds16(const short* g, short* l) {
  __builtin_amdgcn_global_load_lds((const __attribute__((address_space(1))) unsigned*)g,
                                   (__attribute__((address_space(3))) unsigned*)l, 16, 0, 0);
}

// ===========================================================================
// 128x128 GEMM, BK=64 (R15-proven base).
// R20: QK-projection ELIMINATED via softmax shift-invariance:
//   scores = (1/32)[ y (Wq Wk^T) y^T + (Wk bq) y^T ] + rowconst (dropped).
//   G = (y M + w)/32 (17.2 GF) replaces QK-proj (34.4 GF, the 56us dispatch);
//   scores = G @ y^T needs NO transposed/projected K buffer.
// K=1024 gemm_bt plateau measured ~610 TF (3 structures, all pipes <25%) —
// shape property (16 BK-steps), not schedule; attack core next if confirmed.
// MODE 0 plain / 2 causal-PV (kend=(bi+1)*128) / 4 triangular (live causal
// tiles only). DECODE 3: complement bi on (z&2) to balance resident pairing.
// BIASMODE 0 none / 1 col fp32 (+scale).
// ===========================================================================
constexpr int BM = 128, BN = 128, BK = 64;

template<int MODE, int BIASMODE, bool OUTF32, int DECODE>
__global__ __launch_bounds__(256, 2)
void gemm_bt(const short* __restrict__ A, const short* __restrict__ B,
             void* __restrict__ Cv, const float* __restrict__ b0,
             float scale, int K, int lda, int ldb, int ldc,
             long long sA, long long sB, long long sC, int tdim)
{
  const int nwg = gridDim.x, orig = blockIdx.x;
  const int q8 = nwg >> 3, r8 = nwg & 7;
  const int xcd = orig & 7, idx8 = orig >> 3;
  const int wg = (xcd < r8 ? xcd * (q8 + 1) : r8 * (q8 + 1) + (xcd - r8) * q8) + idx8;
  const int bz = blockIdx.z;

  int bi, bj;
  if constexpr (MODE == 4) {
    // triangular decode: wg = bi*(bi+1)/2 + bj, bj <= bi
    int b = (int)((__fsqrt_rn(8.f * (float)wg + 1.f) - 1.f) * 0.5f);
    if ((b + 1) * (b + 2) / 2 <= wg) ++b;          // float-edge fixup
    if (b * (b + 1) / 2 > wg) --b;
    bi = b; bj = wg - b * (b + 1) / 2;
  } else {
    bi = wg / tdim;
    bj = wg - bi * tdim;
    if constexpr (DECODE == 3) { if (bz & 2) bi = (nwg / tdim) - 1 - bi; }
  }

  A += (long long)bz * sA;
  B += (long long)bz * sB;

  __shared__ __align__(16) short lA[2][BM * BK];   // 2 x 16 KB
  __shared__ __align__(16) short lB[2][BN * BK];   // 2 x 16 KB

  const int tid = threadIdx.x, wave = tid >> 6, lane = tid & 63;
  const int wr = wave >> 1, wc = wave & 1;
  const int brow = bi * BM, bcol = bj * BN;
  const int fr = lane & 15, h = lane >> 4;

  const int ck0 = ((h ^ (fr & 7))) * 8;            // 128B-row swizzle, ks=0
  const int swc = ((tid & 7) ^ ((tid >> 3) & 7)) * 8;
  const short* pA = A + (long long)(brow + (tid >> 3)) * lda + swc;
  const short* pB = B + (long long)(bcol + (tid >> 3)) * ldb + swc;

  f32x4 acc[4][4] = {};
  const int kend = (MODE == 2) ? (bi + 1) * BM : K;
  const int nt = kend / BK;

  auto stage = [&](int buf, int t) {
    const long long ko = (long long)t * BK;
#pragma unroll
    for (int j = 0; j < 4; ++j)
      gl_lds16(pA + (long long)(j * 32) * lda + ko, &lA[buf][j * 2048 + tid * 8]);
#pragma unroll
    for (int j = 0; j < 4; ++j)
      gl_lds16(pB + (long long)(j * 32) * ldb + ko, &lB[buf][j * 2048 + tid * 8]);
  };

  stage(0, 0);
  __syncthreads();

  int cur = 0;
  for (int t = 0; t < nt; ++t) {
    if (t + 1 < nt) stage(cur ^ 1, t + 1);

    const short* bufA = lA[cur];
    const short* bufB = lB[cur];
    bf16x8 af[4], bg[4];
#pragma unroll
    for (int m = 0; m < 4; ++m)
      af[m] = *(const bf16x8*)&bufA[(wr * 64 + m * 16 + fr) * BK + ck0];
#pragma unroll
    for (int n = 0; n < 4; ++n)
      bg[n] = *(const bf16x8*)&bufB[(wc * 64 + n * 16 + fr) * BK + ck0];
#pragma unroll
    for (int m = 0; m < 4; ++m)
#pragma unroll
      for (int n = 0; n < 4; ++n)
        acc[m][n] = __builtin_amdgcn_mfma_f32_16x16x32_bf16(af[m], bg[n], acc[m][n], 0, 0, 0);
#pragma unroll
    for (int m = 0; m < 4; ++m)
      af[m] = *(const bf16x8*)&bufA[((wr * 64 + m * 16 + fr) * BK + ck0) ^ 32];
#pragma unroll
    for (int n = 0; n < 4; ++n)
      bg[n] = *(const bf16x8*)&bufB[((wc * 64 + n * 16 + fr) * BK + ck0) ^ 32];
#pragma unroll
    for (int m = 0; m < 4; ++m)
#pragma unroll
      for (int n = 0; n < 4; ++n)
        acc[m][n] = __builtin_amdgcn_mfma_f32_16x16x32_bf16(af[m], bg[n], acc[m][n], 0, 0, 0);

    __syncthreads();
    cur ^= 1;
  }

  // epilogue, n-innermost (64B line completed in 4 consecutive stores)
  const int lrow = h * 4;
  float* Cf = (float*)Cv + (long long)bz * sC;
  short* Cs = (short*)Cv + (long long)bz * sC;
  int colg[4]; float bvv[4];
#pragma unroll
  for (int n = 0; n < 4; ++n) {
    colg[n] = bcol + wc * 64 + n * 16 + fr;
    bvv[n] = (BIASMODE == 1) ? b0[colg[n]] : 0.f;
  }
#pragma unroll
  for (int m = 0; m < 4; ++m) {
    const int row = brow + wr * 64 + m * 16 + lrow;
#pragma unroll
    for (int j = 0; j < 4; ++j) {
#pragma unroll
      for (int n = 0; n < 4; ++n) {
        const float val = (acc[m][n][j] + bvv[n]) * scale;
        if constexpr (OUTF32) Cf[(long long)(row + j) * ldc + colg[n]] = val;
        else                  Cs[(long long)(row + j) * ldc + colg[n]] = f2bf(val);
      }
    }
  }
}

// ---------------------------------------------------------------------------
// Causal-trimmed softmax: row t has t+1 live cols; load only chunks c0<=t,
// store only c0<roundup128(t+1) (keeps required zeros in the diagonal tile).
__global__ __launch_bounds__(256)
void softmax_causal_bf16_k(short* __restrict__ sc)
{
  const int T = 2048;
  const long long row = blockIdx.x;
  const int t = (int)(row & (T - 1));
  short* ps = sc + row * (long long)T;
  const int tid = threadIdx.x, wave = tid >> 6, lane = tid & 63;
  const int c0 = tid * 8;
  const int wlim = ((t >> 7) + 1) << 7;   // exclusive write limit, 128-aligned

  bf16x8 v = {};
  if (c0 <= t) v = *(const bf16x8*)&ps[c0];
  float x[8];
#pragma unroll
  for (int j = 0; j < 8; ++j) x[j] = bf2f(v[j]);

  float mx = -3.0e38f;
#pragma unroll
  for (int j = 0; j < 8; ++j) if (c0 + j <= t) mx = fmaxf(mx, x[j]);
#pragma unroll
  for (int o = 32; o; o >>= 1) mx = fmaxf(mx, __shfl_xor(mx, o, 64));
  __shared__ float red[8];
  if (lane == 0) red[wave] = mx;
  __syncthreads();
  const float M = fmaxf(fmaxf(red[0], red[1]), fmaxf(red[2], red[3]));

  float e[8], s = 0.f;
#pragma unroll
  for (int j = 0; j < 8; ++j) { e[j] = (c0 + j <= t) ? __expf(x[j] - M) : 0.f; s += e[j]; }
#pragma unroll
  for (int o = 32; o; o >>= 1) s += __shfl_xor(s, o, 64);
  if (lane == 0) red[4 + wave] = s;
  __syncthreads();
  const float inv = 1.f / (red[4] + red[5] + red[6] + red[7]);

  if (c0 < wlim) {
    bf16x8 ov;
#pragma unroll
    for (int j = 0; j < 8; ++j) ov[j] = f2bf(e[j] * inv);
    *(bf16x8*)&ps[c0] = ov;
  }
}

// ---------------------------------------------------------------------------
// y fp32 -> bf16, plain vectorized convert
__global__ __launch_bounds__(256)
void cvt_y_k(const float* __restrict__ y, short* __restrict__ ybf)
{
  const long long i = (long long)blockIdx.x * 256 + threadIdx.x;  // 8-elem chunk
  const float4 v0 = ((const float4*)y)[i * 2];
  const float4 v1 = ((const float4*)y)[i * 2 + 1];
  bf16x8 o;
  o[0] = f2bf(v0.x); o[1] = f2bf(v0.y); o[2] = f2bf(v0.z); o[3] = f2bf(v0.w);
  o[4] = f2bf(v1.x); o[5] = f2bf(v1.y); o[6] = f2bf(v1.z); o[7] = f2bf(v1.w);
  ((bf16x8*)ybf)[i] = o;
}

// z=0: Wq plain; z=1: Wk plain; z=2: Wo TRANSPOSE -> WoT; z=3: Wv plain
__global__ __launch_bounds__(256)
void cvt_w_all_k(const float* __restrict__ w0, const float* __restrict__ w1,
                 const float* __restrict__ w2, const float* __restrict__ w3,
                 short* __restrict__ o0, short* __restrict__ o1,
                 short* __restrict__ o2, short* __restrict__ o3)
{
  const int tx = threadIdx.x & 31, ty = threadIdx.x >> 5;
  const int r0 = blockIdx.y * 32, c0 = blockIdx.x * 32;
  if (blockIdx.z != 2) {          // plain convert
    const float* in = (blockIdx.z == 0) ? w0 : (blockIdx.z == 1 ? w1 : w3);
    short* out      = (blockIdx.z == 0) ? o0 : (blockIdx.z == 1 ? o1 : o3);
#pragma unroll
    for (int i = 0; i < 4; ++i)
      out[(long long)(r0 + ty + 8 * i) * 1024 + c0 + tx] =
          f2bf(in[(long long)(r0 + ty + 8 * i) * 1024 + c0 + tx]);
    return;
  }
  __shared__ float tile[32][33];
#pragma unroll
  for (int i = 0; i < 4; ++i)
    tile[ty + 8 * i][tx] = w2[(long long)(r0 + ty + 8 * i) * 1024 + c0 + tx];
  __syncthreads();
#pragma unroll
  for (int i = 0; i < 4; ++i)
    o2[(long long)(c0 + ty + 8 * i) * 1024 + r0 + tx] = f2bf(tile[tx][ty + 8 * i]);
}

// outb[j] = bo[j]
__global__ __launch_bounds__(256)
void bias_init_k(const float* __restrict__ bo, float* __restrict__ outb)
{
  const int j = blockIdx.x * 256 + threadIdx.x;
  outb[j] = bo[j];
}

// outb[j] += sum over 16 rows of bv[r]*Wo[r][j]
__global__ __launch_bounds__(256)
void bias_fold_k(const float* __restrict__ bv, const float* __restrict__ Wo,
                 float* __restrict__ outb)
{
  const int r0 = blockIdx.x * 16;
  const int c4 = threadIdx.x;
  float4 acc = make_float4(0.f, 0.f, 0.f, 0.f);
  for (int r = 0; r < 16; ++r) {
    const float s = bv[r0 + r];
    const float4 w = ((const float4*)(Wo + (long long)(r0 + r) * 1024))[c4];
    acc.x += s * w.x; acc.y += s * w.y; acc.z += s * w.z; acc.w += s * w.w;
  }
  atomicAdd(&outb[c4 * 4 + 0], acc.x);
  atomicAdd(&outb[c4 * 4 + 1], acc.y);
  atomicAdd(&outb[c4 * 4 + 2], acc.z);
  atomicAdd(&outb[c4 * 4 + 3], acc.w);
}

// w[row] = sum_d Wk[row][d] * bq[d]   (fp32 GEMV, 1024 rows)
__global__ __launch_bounds__(256)
void wkbq_gemv_k(const float* __restrict__ Wk, const float* __restrict__ bq,
                 float* __restrict__ w)
{
  const int row = blockIdx.x, tid = threadIdx.x;
  const float4 a = ((const float4*)(Wk + (long long)row * 1024))[tid];
  const float4 b = ((const float4*)bq)[tid];
  float s = a.x * b.x + a.y * b.y + a.z * b.z + a.w * b.w;
#pragma unroll
  for (int o = 32; o; o >>= 1) s += __shfl_xor(s, o, 64);
  __shared__ float red[4];
  if ((tid & 63) == 0) red[tid >> 6] = s;
  __syncthreads();
  if (tid == 0) w[row] = red[0] + red[1] + red[2] + red[3];
}

// out = bf16( part0 + part1 + part2 + part3 )  (split-K combine, 1M elems)
__global__ __launch_bounds__(256)
void combine4_k(const float* __restrict__ p, short* __restrict__ out)
{
  const long long i = (long long)blockIdx.x * 256 + threadIdx.x;  // float4 idx
  const float4 a = ((const float4*)p)[i];
  const float4 b = ((const float4*)(p + 1048576))[i];
  const float4 c = ((const float4*)(p + 2097152))[i];
  const float4 d = ((const float4*)(p + 3145728))[i];
  bf16x4 o;
  o[0] = f2bf(a.x + b.x + c.x + d.x);
  o[1] = f2bf(a.y + b.y + c.y + d.y);
  o[2] = f2bf(a.z + b.z + c.z + d.z);
  o[3] = f2bf(a.w + b.w + c.w + d.w);
  ((bf16x4*)out)[i] = o;
}

// ---------------------------------------------------------------------------
extern "C" void kernel_launch(void* const* d_in, const int* in_sizes, int n_in,
                              void* d_out, int out_size, void* d_ws, size_t ws_size,
                              hipStream_t stream)
{
  (void)in_sizes; (void)n_in; (void)out_size; (void)ws_size;
  const float* y  = (const float*)d_in[0];
  const float* Wq = (const float*)d_in[1];
  const float* bq = (const float*)d_in[2];
  const float* Wk = (const float*)d_in[3];
  const float* bk = (const float*)d_in[4];
  const float* Wv = (const float*)d_in[5];
  const float* bv = (const float*)d_in[6];
  const float* Wo = (const float*)d_in[7];
  const float* bo = (const float*)d_in[8];
  float* out = (float*)d_out;
  (void)bk;   // bk only contributes row-constant score terms -> softmax-invariant

  const int T = 2048;
  const long long MT = 8192;                          // B*T
  const long long MM = 1048576;                       // 1024*1024

  // workspace layout (shorts); ~113 MB
  short* ws    = (short*)d_ws;
  short* ybf   = ws;                                  // 16 MB
  short* WqBf  = ybf + MT * 1024;                     // 2 MB
  short* WkBf  = WqBf + MM;
  short* WoT   = WkBf + MM;
  short* WvBf  = WoT + MM;
  short* MTb   = WvBf + MM;                           // (Wk Wq^T) bf16
  short* WvoT  = MTb + MM;                            // ((Wv Wo)^T) bf16
  short* G     = WvoT + MM;                           // 8192x1024 bf16
  short* zT    = G + MT * 1024;                       // 1024x8192 bf16
  short* scores = zT + MT * 1024;                     // 4*T*T bf16 (32 MB)
  float* bvWoBo = (float*)(scores + 4ll * T * T);     // 1024 fp32
  float* wvec   = bvWoBo + 1024;                      // 1024 fp32
  float* part   = wvec + 1024;                        // 4 x 1M fp32 (16 MB, shared)

  // 1. conversions + small precomputes
  cvt_y_k<<<4096, 256, 0, stream>>>(y, ybf);
  cvt_w_all_k<<<dim3(32, 32, 4), 256, 0, stream>>>(
      Wq, Wk, Wo, Wv, WqBf, WkBf, WoT, WvBf);
  bias_init_k<<<4, 256, 0, stream>>>(bo, bvWoBo);
  bias_fold_k<<<64, 256, 0, stream>>>(bv, Wo, bvWoBo);      // bv@Wo + bo
  wkbq_gemv_k<<<1024, 256, 0, stream>>>(Wk, bq, wvec);      // w = Wk @ bq

  // 2. WvoT = (Wv@Wo)^T : split-K x4 fp32 partials, combine (part reused)
  gemm_bt<0, 0, true, 0><<<dim3(64, 1, 4), 256, 0, stream>>>(
      WoT, WvBf, part, nullptr, 1.f, 256, 1024, 1024, 1024,
      256, 256, 1048576, 8);
  combine4_k<<<1024, 256, 0, stream>>>(part, WvoT);

  // 3. MTb = Wk @ Wq^T : split-K x4 fp32 partials, combine (part reused)
  gemm_bt<0, 0, true, 0><<<dim3(64, 1, 4), 256, 0, stream>>>(
      WkBf, WqBf, part, nullptr, 1.f, 256, 1024, 1024, 1024,
      256, 256, 1048576, 8);
  combine4_k<<<1024, 256, 0, stream>>>(part, MTb);

  // 4. zT = (y @ Wvo)^T : A=WvoT [1024x1024], B=ybf [8192x1024]
  gemm_bt<0, 0, false, 0><<<dim3(512, 1, 1), 256, 0, stream>>>(
      WvoT, ybf, zT, nullptr, 1.f, 1024, 1024, 1024, 8192,
      0, 0, 0, 64);

  // 5. G = (y @ M + w) / 32 : A=ybf, B=MTb, col-bias wvec, scale 1/32
  gemm_bt<0, 1, false, 0><<<dim3(512, 1, 1), 256, 0, stream>>>(
      ybf, MTb, G, wvec, 1.f / 32.f, 1024, 1024, 1024, 1024,
      0, 0, 0, 8);

  // 6. scores = G @ y^T -> bf16, TRIANGULAR grid (136 live tiles/batch)
  gemm_bt<4, 0, false, 0><<<dim3(136, 1, 4), 256, 0, stream>>>(
      G, ybf, scores, nullptr, 1.f, 1024, 1024, 1024, T,
      (long long)T * 1024, (long long)T * 1024, (long long)T * T, 16);

  // 7. causal softmax in place (trimmed to live columns)
  softmax_causal_bf16_k<<<(int)MT, 256, 0, stream>>>(scores);

  // 8. out = P @ z + (bv@Wo + bo)  — final fp32, causal kend, pairing balance
  gemm_bt<2, 1, true, 3><<<dim3(16 * 8, 1, 4), 256, 0, stream>>>(
      scores, zT, out, bvWoBo, 1.f, T, T, 8192, 1024,
      (long long)T * T, 2048, 2048ll * 1024, 8);
}

// Round 5
// 186.087 us; speedup vs baseline: 1.0370x; 1.0347x over previous
//
#include <hip/hip_runtime.h>
#include <hip/hip_bf16.h>
#include <cstdint>

#define DEVI __device__ __forceinline__

typedef __attribute__((ext_vector_type(8))) short bf16x8;
typedef __attribute__((ext_vector_type(4))) short bf16x4;
typedef __attribute__((ext_vector_type(4))) float f32x4;

DEVI short f2bf(float f) {
  unsigned u = __float_as_uint(f);
  u += 0x7fff + ((u >> 16) & 1);   // round-to-nearest-even
  return (short)(u >> 16);
}
DEVI float bf2f(short s) { return __uint_as_float(((unsigned)(unsigned short)s) << 16); }

DEVI void gl_lds16(const short* g, short* l) {
  __builtin_amdgcn_global_load_lds((const __attribute__((address_space(1))) unsigned*)g,
                                   (__attribute__((address_space(3))) unsigned*)l, 16, 0, 0);
}

// ===========================================================================
// 128x128 GEMM, BK=64, DOUBLE-buffered (2 blocks/CU) — for scores/PV/splitK
// whose grids only supply ~2 wgs/CU anyway.
// R21 evidence: zT (B-weight L2-resident) 614 TF vs scores 368 TF, both 16
// K-steps, both 2 blocks/CU; m102 shape curve tracks blocks/CU. The K=1024
// plateau is residency/latency, not K-step count.
// MODE 0 plain / 2 causal-PV (kend=(bi+1)*128) / 4 triangular.
// DECODE 3: complement bi on (z&2) to balance resident pairing.
// BIASMODE 0 none / 1 col fp32 (+scale).
// ===========================================================================
constexpr int BM = 128, BN = 128, BK = 64;

template<int MODE, int BIASMODE, bool OUTF32, int DECODE>
__global__ __launch_bounds__(256, 2)
void gemm_bt(const short* __restrict__ A, const short* __restrict__ B,
             void* __restrict__ Cv, const float* __restrict__ b0,
             float scale, int K, int lda, int ldb, int ldc,
             long long sA, long long sB, long long sC, int tdim)
{
  const int nwg = gridDim.x, orig = blockIdx.x;
  const int q8 = nwg >> 3, r8 = nwg & 7;
  const int xcd = orig & 7, idx8 = orig >> 3;
  const int wg = (xcd < r8 ? xcd * (q8 + 1) : r8 * (q8 + 1) + (xcd - r8) * q8) + idx8;
  const int bz = blockIdx.z;

  int bi, bj;
  if constexpr (MODE == 4) {
    // triangular decode: wg = bi*(bi+1)/2 + bj, bj <= bi
    int b = (int)((__fsqrt_rn(8.f * (float)wg + 1.f) - 1.f) * 0.5f);
    if ((b + 1) * (b + 2) / 2 <= wg) ++b;          // float-edge fixup
    if (b * (b + 1) / 2 > wg) --b;
    bi = b; bj = wg - b * (b + 1) / 2;
  } else {
    bi = wg / tdim;
    bj = wg - bi * tdim;
    if constexpr (DECODE == 3) { if (bz & 2) bi = (nwg / tdim) - 1 - bi; }
  }

  A += (long long)bz * sA;
  B += (long long)bz * sB;

  __shared__ __align__(16) short lA[2][BM * BK];   // 2 x 16 KB
  __shared__ __align__(16) short lB[2][BN * BK];   // 2 x 16 KB

  const int tid = threadIdx.x, wave = tid >> 6, lane = tid & 63;
  const int wr = wave >> 1, wc = wave & 1;
  const int brow = bi * BM, bcol = bj * BN;
  const int fr = lane & 15, h = lane >> 4;

  const int ck0 = ((h ^ (fr & 7))) * 8;            // 128B-row swizzle, ks=0
  const int swc = ((tid & 7) ^ ((tid >> 3) & 7)) * 8;
  const short* pA = A + (long long)(brow + (tid >> 3)) * lda + swc;
  const short* pB = B + (long long)(bcol + (tid >> 3)) * ldb + swc;

  f32x4 acc[4][4] = {};
  const int kend = (MODE == 2) ? (bi + 1) * BM : K;
  const int nt = kend / BK;

  auto stage = [&](int buf, int t) {
    const long long ko = (long long)t * BK;
#pragma unroll
    for (int j = 0; j < 4; ++j)
      gl_lds16(pA + (long long)(j * 32) * lda + ko, &lA[buf][j * 2048 + tid * 8]);
#pragma unroll
    for (int j = 0; j < 4; ++j)
      gl_lds16(pB + (long long)(j * 32) * ldb + ko, &lB[buf][j * 2048 + tid * 8]);
  };

  stage(0, 0);
  __syncthreads();

  int cur = 0;
  for (int t = 0; t < nt; ++t) {
    if (t + 1 < nt) stage(cur ^ 1, t + 1);

    const short* bufA = lA[cur];
    const short* bufB = lB[cur];
    bf16x8 af[4], bg[4];
#pragma unroll
    for (int m = 0; m < 4; ++m)
      af[m] = *(const bf16x8*)&bufA[(wr * 64 + m * 16 + fr) * BK + ck0];
#pragma unroll
    for (int n = 0; n < 4; ++n)
      bg[n] = *(const bf16x8*)&bufB[(wc * 64 + n * 16 + fr) * BK + ck0];
#pragma unroll
    for (int m = 0; m < 4; ++m)
#pragma unroll
      for (int n = 0; n < 4; ++n)
        acc[m][n] = __builtin_amdgcn_mfma_f32_16x16x32_bf16(af[m], bg[n], acc[m][n], 0, 0, 0);
#pragma unroll
    for (int m = 0; m < 4; ++m)
      af[m] = *(const bf16x8*)&bufA[((wr * 64 + m * 16 + fr) * BK + ck0) ^ 32];
#pragma unroll
    for (int n = 0; n < 4; ++n)
      bg[n] = *(const bf16x8*)&bufB[((wc * 64 + n * 16 + fr) * BK + ck0) ^ 32];
#pragma unroll
    for (int m = 0; m < 4; ++m)
#pragma unroll
      for (int n = 0; n < 4; ++n)
        acc[m][n] = __builtin_amdgcn_mfma_f32_16x16x32_bf16(af[m], bg[n], acc[m][n], 0, 0, 0);

    __syncthreads();
    cur ^= 1;
  }

  // epilogue, n-innermost (64B line completed in 4 consecutive stores)
  const int lrow = h * 4;
  float* Cf = (float*)Cv + (long long)bz * sC;
  short* Cs = (short*)Cv + (long long)bz * sC;
  int colg[4]; float bvv[4];
#pragma unroll
  for (int n = 0; n < 4; ++n) {
    colg[n] = bcol + wc * 64 + n * 16 + fr;
    bvv[n] = (BIASMODE == 1) ? b0[colg[n]] : 0.f;
  }
#pragma unroll
  for (int m = 0; m < 4; ++m) {
    const int row = brow + wr * 64 + m * 16 + lrow;
#pragma unroll
    for (int j = 0; j < 4; ++j) {
#pragma unroll
      for (int n = 0; n < 4; ++n) {
        const float val = (acc[m][n][j] + bvv[n]) * scale;
        if constexpr (OUTF32) Cf[(long long)(row + j) * ldc + colg[n]] = val;
        else                  Cs[(long long)(row + j) * ldc + colg[n]] = f2bf(val);
      }
    }
  }
}

// ===========================================================================
// R21: merged zT+G dispatch, SINGLE-buffered LDS (32 KB) + launch_bounds
// (256,4) => 4 resident blocks/CU. Cross-block overlap (m114) replaces the
// intra-block double-buffer in the latency-bound 16-K-step regime.
// 1024 wgs; XCD swizzle puts zT (wg<512) on XCD 0-3, G on XCD 4-7: balanced,
// and each half's 2MB weight matrix stays resident in its own per-XCD L2.
//   zT half: C[1024][8192] = WvoT @ ybf^T   (A=WvoT, B=ybf, ldc=8192)
//   G  half: C[8192][1024] = ybf @ MTb^T, +wvec, /32 (A=ybf, B=MTb, ldc=1024)
// ===========================================================================
__global__ __launch_bounds__(256, 4)
void gemm_zg(const short* __restrict__ WvoT, const short* __restrict__ ybf,
             const short* __restrict__ MTb, short* __restrict__ zT,
             short* __restrict__ G, const float* __restrict__ wvec)
{
  const int orig = blockIdx.x;                  // 1024 wgs
  const int xcd = orig & 7, idx8 = orig >> 3;
  const int wg = xcd * 128 + idx8;              // nwg=1024 -> q8=128, r8=0

  const short *A, *B; short* C; const float* b0; float scale; int ldc, tdim, lwg;
  if (wg < 512) { A = WvoT; B = ybf; C = zT; b0 = nullptr; scale = 1.f;
                  ldc = 8192; tdim = 64; lwg = wg; }
  else          { A = ybf; B = MTb; C = G; b0 = wvec; scale = 1.f / 32.f;
                  ldc = 1024; tdim = 8; lwg = wg - 512; }
  const int bi = lwg / tdim, bj = lwg - bi * tdim;

  __shared__ __align__(16) short lA[BM * BK];   // 16 KB
  __shared__ __align__(16) short lB[BN * BK];   // 16 KB

  const int tid = threadIdx.x, wave = tid >> 6, lane = tid & 63;
  const int wr = wave >> 1, wc = wave & 1;
  const int brow = bi * BM, bcol = bj * BN;
  const int fr = lane & 15, h = lane >> 4;

  const int ck0 = ((h ^ (fr & 7))) * 8;
  const int swc = ((tid & 7) ^ ((tid >> 3) & 7)) * 8;
  const short* pA = A + (long long)(brow + (tid >> 3)) * 1024 + swc;
  const short* pB = B + (long long)(bcol + (tid >> 3)) * 1024 + swc;

  f32x4 acc[4][4] = {};

  for (int t = 0; t < 16; ++t) {
    const long long ko = (long long)t * BK;
#pragma unroll
    for (int j = 0; j < 4; ++j)
      gl_lds16(pA + (long long)(j * 32) * 1024 + ko, &lA[j * 2048 + tid * 8]);
#pragma unroll
    for (int j = 0; j < 4; ++j)
      gl_lds16(pB + (long long)(j * 32) * 1024 + ko, &lB[j * 2048 + tid * 8]);
    __syncthreads();     // implicit vmcnt(0): all gl_lds landed

    bf16x8 af[4], bg[4];
#pragma unroll
    for (int m = 0; m < 4; ++m)
      af[m] = *(const bf16x8*)&lA[(wr * 64 + m * 16 + fr) * BK + ck0];
#pragma unroll
    for (int n = 0; n < 4; ++n)
      bg[n] = *(const bf16x8*)&lB[(wc * 64 + n * 16 + fr) * BK + ck0];
#pragma unroll
    for (int m = 0; m < 4; ++m)
#pragma unroll
      for (int n = 0; n < 4; ++n)
        acc[m][n] = __builtin_amdgcn_mfma_f32_16x16x32_bf16(af[m], bg[n], acc[m][n], 0, 0, 0);
#pragma unroll
    for (int m = 0; m < 4; ++m)
      af[m] = *(const bf16x8*)&lA[((wr * 64 + m * 16 + fr) * BK + ck0) ^ 32];
#pragma unroll
    for (int n = 0; n < 4; ++n)
      bg[n] = *(const bf16x8*)&lB[((wc * 64 + n * 16 + fr) * BK + ck0) ^ 32];
#pragma unroll
    for (int m = 0; m < 4; ++m)
#pragma unroll
      for (int n = 0; n < 4; ++n)
        acc[m][n] = __builtin_amdgcn_mfma_f32_16x16x32_bf16(af[m], bg[n], acc[m][n], 0, 0, 0);
    __syncthreads();     // all reads done before next stage overwrites
  }

  const int lrow = h * 4;
  int colg[4]; float bvv[4];
#pragma unroll
  for (int n = 0; n < 4; ++n) {
    colg[n] = bcol + wc * 64 + n * 16 + fr;
    bvv[n] = b0 ? b0[colg[n]] : 0.f;
  }
#pragma unroll
  for (int m = 0; m < 4; ++m) {
    const int row = brow + wr * 64 + m * 16 + lrow;
#pragma unroll
    for (int j = 0; j < 4; ++j) {
#pragma unroll
      for (int n = 0; n < 4; ++n)
        C[(long long)(row + j) * ldc + colg[n]] = f2bf((acc[m][n][j] + bvv[n]) * scale);
    }
  }
}

// ---------------------------------------------------------------------------
// Causal-trimmed softmax: row t has t+1 live cols; load only chunks c0<=t,
// store only c0<roundup128(t+1) (keeps required zeros in the diagonal tile).
__global__ __launch_bounds__(256)
void softmax_causal_bf16_k(short* __restrict__ sc)
{
  const int T = 2048;
  const long long row = blockIdx.x;
  const int t = (int)(row & (T - 1));
  short* ps = sc + row * (long long)T;
  const int tid = threadIdx.x, wave = tid >> 6, lane = tid & 63;
  const int c0 = tid * 8;
  const int wlim = ((t >> 7) + 1) << 7;   // exclusive write limit, 128-aligned

  bf16x8 v = {};
  if (c0 <= t) v = *(const bf16x8*)&ps[c0];
  float x[8];
#pragma unroll
  for (int j = 0; j < 8; ++j) x[j] = bf2f(v[j]);

  float mx = -3.0e38f;
#pragma unroll
  for (int j = 0; j < 8; ++j) if (c0 + j <= t) mx = fmaxf(mx, x[j]);
#pragma unroll
  for (int o = 32; o; o >>= 1) mx = fmaxf(mx, __shfl_xor(mx, o, 64));
  __shared__ float red[8];
  if (lane == 0) red[wave] = mx;
  __syncthreads();
  const float M = fmaxf(fmaxf(red[0], red[1]), fmaxf(red[2], red[3]));

  float e[8], s = 0.f;
#pragma unroll
  for (int j = 0; j < 8; ++j) { e[j] = (c0 + j <= t) ? __expf(x[j] - M) : 0.f; s += e[j]; }
#pragma unroll
  for (int o = 32; o; o >>= 1) s += __shfl_xor(s, o, 64);
  if (lane == 0) red[4 + wave] = s;
  __syncthreads();
  const float inv = 1.f / (red[4] + red[5] + red[6] + red[7]);

  if (c0 < wlim) {
    bf16x8 ov;
#pragma unroll
    for (int j = 0; j < 8; ++j) ov[j] = f2bf(e[j] * inv);
    *(bf16x8*)&ps[c0] = ov;
  }
}

// ---------------------------------------------------------------------------
// y fp32 -> bf16, plain vectorized convert
__global__ __launch_bounds__(256)
void cvt_y_k(const float* __restrict__ y, short* __restrict__ ybf)
{
  const long long i = (long long)blockIdx.x * 256 + threadIdx.x;  // 8-elem chunk
  const float4 v0 = ((const float4*)y)[i * 2];
  const float4 v1 = ((const float4*)y)[i * 2 + 1];
  bf16x8 o;
  o[0] = f2bf(v0.x); o[1] = f2bf(v0.y); o[2] = f2bf(v0.z); o[3] = f2bf(v0.w);
  o[4] = f2bf(v1.x); o[5] = f2bf(v1.y); o[6] = f2bf(v1.z); o[7] = f2bf(v1.w);
  ((bf16x8*)ybf)[i] = o;
}

// z=0: Wq plain; z=1: Wk plain; z=2: Wo TRANSPOSE -> WoT; z=3: Wv plain
__global__ __launch_bounds__(256)
void cvt_w_all_k(const float* __restrict__ w0, const float* __restrict__ w1,
                 const float* __restrict__ w2, const float* __restrict__ w3,
                 short* __restrict__ o0, short* __restrict__ o1,
                 short* __restrict__ o2, short* __restrict__ o3)
{
  const int tx = threadIdx.x & 31, ty = threadIdx.x >> 5;
  const int r0 = blockIdx.y * 32, c0 = blockIdx.x * 32;
  if (blockIdx.z != 2) {          // plain convert
    const float* in = (blockIdx.z == 0) ? w0 : (blockIdx.z == 1 ? w1 : w3);
    short* out      = (blockIdx.z == 0) ? o0 : (blockIdx.z == 1 ? o1 : o3);
#pragma unroll
    for (int i = 0; i < 4; ++i)
      out[(long long)(r0 + ty + 8 * i) * 1024 + c0 + tx] =
          f2bf(in[(long long)(r0 + ty + 8 * i) * 1024 + c0 + tx]);
    return;
  }
  __shared__ float tile[32][33];
#pragma unroll
  for (int i = 0; i < 4; ++i)
    tile[ty + 8 * i][tx] = w2[(long long)(r0 + ty + 8 * i) * 1024 + c0 + tx];
  __syncthreads();
#pragma unroll
  for (int i = 0; i < 4; ++i)
    o2[(long long)(c0 + ty + 8 * i) * 1024 + r0 + tx] = f2bf(tile[tx][ty + 8 * i]);
}

// outb[j] = bo[j]
__global__ __launch_bounds__(256)
void bias_init_k(const float* __restrict__ bo, float* __restrict__ outb)
{
  const int j = blockIdx.x * 256 + threadIdx.x;
  outb[j] = bo[j];
}

// outb[j] += sum over 16 rows of bv[r]*Wo[r][j]
__global__ __launch_bounds__(256)
void bias_fold_k(const float* __restrict__ bv, const float* __restrict__ Wo,
                 float* __restrict__ outb)
{
  const int r0 = blockIdx.x * 16;
  const int c4 = threadIdx.x;
  float4 acc = make_float4(0.f, 0.f, 0.f, 0.f);
  for (int r = 0; r < 16; ++r) {
    const float s = bv[r0 + r];
    const float4 w = ((const float4*)(Wo + (long long)(r0 + r) * 1024))[c4];
    acc.x += s * w.x; acc.y += s * w.y; acc.z += s * w.z; acc.w += s * w.w;
  }
  atomicAdd(&outb[c4 * 4 + 0], acc.x);
  atomicAdd(&outb[c4 * 4 + 1], acc.y);
  atomicAdd(&outb[c4 * 4 + 2], acc.z);
  atomicAdd(&outb[c4 * 4 + 3], acc.w);
}

// w[row] = sum_d Wk[row][d] * bq[d]   (fp32 GEMV, 1024 rows)
__global__ __launch_bounds__(256)
void wkbq_gemv_k(const float* __restrict__ Wk, const float* __restrict__ bq,
                 float* __restrict__ w)
{
  const int row = blockIdx.x, tid = threadIdx.x;
  const float4 a = ((const float4*)(Wk + (long long)row * 1024))[tid];
  const float4 b = ((const float4*)bq)[tid];
  float s = a.x * b.x + a.y * b.y + a.z * b.z + a.w * b.w;
#pragma unroll
  for (int o = 32; o; o >>= 1) s += __shfl_xor(s, o, 64);
  __shared__ float red[4];
  if ((tid & 63) == 0) red[tid >> 6] = s;
  __syncthreads();
  if (tid == 0) w[row] = red[0] + red[1] + red[2] + red[3];
}

// out = bf16( part0 + part1 + part2 + part3 )  (split-K combine, 1M elems)
__global__ __launch_bounds__(256)
void combine4_k(const float* __restrict__ p, short* __restrict__ out)
{
  const long long i = (long long)blockIdx.x * 256 + threadIdx.x;  // float4 idx
  const float4 a = ((const float4*)p)[i];
  const float4 b = ((const float4*)(p + 1048576))[i];
  const float4 c = ((const float4*)(p + 2097152))[i];
  const float4 d = ((const float4*)(p + 3145728))[i];
  bf16x4 o;
  o[0] = f2bf(a.x + b.x + c.x + d.x);
  o[1] = f2bf(a.y + b.y + c.y + d.y);
  o[2] = f2bf(a.z + b.z + c.z + d.z);
  o[3] = f2bf(a.w + b.w + c.w + d.w);
  ((bf16x4*)out)[i] = o;
}

// ---------------------------------------------------------------------------
extern "C" void kernel_launch(void* const* d_in, const int* in_sizes, int n_in,
                              void* d_out, int out_size, void* d_ws, size_t ws_size,
                              hipStream_t stream)
{
  (void)in_sizes; (void)n_in; (void)out_size; (void)ws_size;
  const float* y  = (const float*)d_in[0];
  const float* Wq = (const float*)d_in[1];
  const float* bq = (const float*)d_in[2];
  const float* Wk = (const float*)d_in[3];
  const float* bk = (const float*)d_in[4];
  const float* Wv = (const float*)d_in[5];
  const float* bv = (const float*)d_in[6];
  const float* Wo = (const float*)d_in[7];
  const float* bo = (const float*)d_in[8];
  float* out = (float*)d_out;
  (void)bk;   // bk only contributes row-constant score terms -> softmax-invariant

  const int T = 2048;
  const long long MT = 8192;                          // B*T
  const long long MM = 1048576;                       // 1024*1024

  // workspace layout (shorts); ~113 MB
  short* ws    = (short*)d_ws;
  short* ybf   = ws;                                  // 16 MB
  short* WqBf  = ybf + MT * 1024;                     // 2 MB
  short* WkBf  = WqBf + MM;
  short* WoT   = WkBf + MM;
  short* WvBf  = WoT + MM;
  short* MTb   = WvBf + MM;                           // (Wk Wq^T) bf16
  short* WvoT  = MTb + MM;                            // ((Wv Wo)^T) bf16
  short* G     = WvoT + MM;                           // 8192x1024 bf16
  short* zT    = G + MT * 1024;                       // 1024x8192 bf16
  short* scores = zT + MT * 1024;                     // 4*T*T bf16 (32 MB)
  float* bvWoBo = (float*)(scores + 4ll * T * T);     // 1024 fp32
  float* wvec   = bvWoBo + 1024;                      // 1024 fp32
  float* part   = wvec + 1024;                        // 4 x 1M fp32 (16 MB, shared)

  // 1. conversions + small precomputes
  cvt_y_k<<<4096, 256, 0, stream>>>(y, ybf);
  cvt_w_all_k<<<dim3(32, 32, 4), 256, 0, stream>>>(
      Wq, Wk, Wo, Wv, WqBf, WkBf, WoT, WvBf);
  bias_init_k<<<4, 256, 0, stream>>>(bo, bvWoBo);
  bias_fold_k<<<64, 256, 0, stream>>>(bv, Wo, bvWoBo);      // bv@Wo + bo
  wkbq_gemv_k<<<1024, 256, 0, stream>>>(Wk, bq, wvec);      // w = Wk @ bq

  // 2. WvoT = (Wv@Wo)^T : split-K x4 fp32 partials, combine (part reused)
  gemm_bt<0, 0, true, 0><<<dim3(64, 1, 4), 256, 0, stream>>>(
      WoT, WvBf, part, nullptr, 1.f, 256, 1024, 1024, 1024,
      256, 256, 1048576, 8);
  combine4_k<<<1024, 256, 0, stream>>>(part, WvoT);

  // 3. MTb = Wk @ Wq^T : split-K x4 fp32 partials, combine (part reused)
  gemm_bt<0, 0, true, 0><<<dim3(64, 1, 4), 256, 0, stream>>>(
      WkBf, WqBf, part, nullptr, 1.f, 256, 1024, 1024, 1024,
      256, 256, 1048576, 8);
  combine4_k<<<1024, 256, 0, stream>>>(part, MTb);

  // 4+5 merged. zT = (y@Wvo)^T on XCD 0-3; G = (y@M + w)/32 on XCD 4-7.
  //    1024 wgs, single-buffered LDS, 4 blocks/CU.
  gemm_zg<<<1024, 256, 0, stream>>>(WvoT, ybf, MTb, zT, G, wvec);

  // 6. scores = G @ y^T -> bf16, TRIANGULAR grid (136 live tiles/batch)
  gemm_bt<4, 0, false, 0><<<dim3(136, 1, 4), 256, 0, stream>>>(
      G, ybf, scores, nullptr, 1.f, 1024, 1024, 1024, T,
      (long long)T * 1024, (long long)T * 1024, (long long)T * T, 16);

  // 7. causal softmax in place (trimmed to live columns)
  softmax_causal_bf16_k<<<(int)MT, 256, 0, stream>>>(scores);

  // 8. out = P @ z + (bv@Wo + bo)  — final fp32, causal kend, pairing balance
  gemm_bt<2, 1, true, 3><<<dim3(16 * 8, 1, 4), 256, 0, stream>>>(
      scores, zT, out, bvWoBo, 1.f, T, T, 8192, 1024,
      (long long)T * T, 2048, 2048ll * 1024, 8);
}

// Round 6
// 179.960 us; speedup vs baseline: 1.0723x; 1.0340x over previous
//
#include <hip/hip_runtime.h>
#include <hip/hip_bf16.h>
#include <cstdint>

#define DEVI __device__ __forceinline__

typedef __attribute__((ext_vector_type(8))) short bf16x8;
typedef __attribute__((ext_vector_type(4))) short bf16x4;
typedef __attribute__((ext_vector_type(4))) float f32x4;

DEVI short f2bf(float f) {
  unsigned u = __float_as_uint(f);
  u += 0x7fff + ((u >> 16) & 1);   // round-to-nearest-even
  return (short)(u >> 16);
}
DEVI float bf2f(short s) { return __uint_as_float(((unsigned)(unsigned short)s) << 16); }

DEVI void gl_lds16(const short* g, short* l) {
  __builtin_amdgcn_global_load_lds((const __attribute__((address_space(1))) unsigned*)g,
                                   (__attribute__((address_space(3))) unsigned*)l, 16, 0, 0);
}

// ===========================================================================
// 128x128 GEMM, BK=64, DOUBLE-buffered (2 blocks/CU) — kept for split-K
// precomputes and PV (their grids/sizes don't benefit from SB-occ4).
// R22 evidence chain: 2 blocks/CU dbuf = 372-614 TF (latency-bound, occ 12.5%);
// 4 blocks/CU single-buffer (gemm_zg) = >=715 TF. Occupancy, not K-steps,
// governs the K=1024 plateau.
// MODE 0 plain / 2 causal-PV (kend=(bi+1)*128) / 4 triangular.
// DECODE 3: complement bi on (z&2) to balance resident pairing.
// BIASMODE 0 none / 1 col fp32 (+scale).
// ===========================================================================
constexpr int BM = 128, BN = 128, BK = 64;

template<int MODE, int BIASMODE, bool OUTF32, int DECODE>
__global__ __launch_bounds__(256, 2)
void gemm_bt(const short* __restrict__ A, const short* __restrict__ B,
             void* __restrict__ Cv, const float* __restrict__ b0,
             float scale, int K, int lda, int ldb, int ldc,
             long long sA, long long sB, long long sC, int tdim)
{
  const int nwg = gridDim.x, orig = blockIdx.x;
  const int q8 = nwg >> 3, r8 = nwg & 7;
  const int xcd = orig & 7, idx8 = orig >> 3;
  const int wg = (xcd < r8 ? xcd * (q8 + 1) : r8 * (q8 + 1) + (xcd - r8) * q8) + idx8;
  const int bz = blockIdx.z;

  int bi, bj;
  if constexpr (MODE == 4) {
    int b = (int)((__fsqrt_rn(8.f * (float)wg + 1.f) - 1.f) * 0.5f);
    if ((b + 1) * (b + 2) / 2 <= wg) ++b;
    if (b * (b + 1) / 2 > wg) --b;
    bi = b; bj = wg - b * (b + 1) / 2;
  } else {
    bi = wg / tdim;
    bj = wg - bi * tdim;
    if constexpr (DECODE == 3) { if (bz & 2) bi = (nwg / tdim) - 1 - bi; }
  }

  A += (long long)bz * sA;
  B += (long long)bz * sB;

  __shared__ __align__(16) short lA[2][BM * BK];   // 2 x 16 KB
  __shared__ __align__(16) short lB[2][BN * BK];   // 2 x 16 KB

  const int tid = threadIdx.x, wave = tid >> 6, lane = tid & 63;
  const int wr = wave >> 1, wc = wave & 1;
  const int brow = bi * BM, bcol = bj * BN;
  const int fr = lane & 15, h = lane >> 4;

  const int ck0 = ((h ^ (fr & 7))) * 8;            // 128B-row swizzle
  const int swc = ((tid & 7) ^ ((tid >> 3) & 7)) * 8;
  const short* pA = A + (long long)(brow + (tid >> 3)) * lda + swc;
  const short* pB = B + (long long)(bcol + (tid >> 3)) * ldb + swc;

  f32x4 acc[4][4] = {};
  const int kend = (MODE == 2) ? (bi + 1) * BM : K;
  const int nt = kend / BK;

  auto stage = [&](int buf, int t) {
    const long long ko = (long long)t * BK;
#pragma unroll
    for (int j = 0; j < 4; ++j)
      gl_lds16(pA + (long long)(j * 32) * lda + ko, &lA[buf][j * 2048 + tid * 8]);
#pragma unroll
    for (int j = 0; j < 4; ++j)
      gl_lds16(pB + (long long)(j * 32) * ldb + ko, &lB[buf][j * 2048 + tid * 8]);
  };

  stage(0, 0);
  __syncthreads();

  int cur = 0;
  for (int t = 0; t < nt; ++t) {
    if (t + 1 < nt) stage(cur ^ 1, t + 1);

    const short* bufA = lA[cur];
    const short* bufB = lB[cur];
    bf16x8 af[4], bg[4];
#pragma unroll
    for (int m = 0; m < 4; ++m)
      af[m] = *(const bf16x8*)&bufA[(wr * 64 + m * 16 + fr) * BK + ck0];
#pragma unroll
    for (int n = 0; n < 4; ++n)
      bg[n] = *(const bf16x8*)&bufB[(wc * 64 + n * 16 + fr) * BK + ck0];
#pragma unroll
    for (int m = 0; m < 4; ++m)
#pragma unroll
      for (int n = 0; n < 4; ++n)
        acc[m][n] = __builtin_amdgcn_mfma_f32_16x16x32_bf16(af[m], bg[n], acc[m][n], 0, 0, 0);
#pragma unroll
    for (int m = 0; m < 4; ++m)
      af[m] = *(const bf16x8*)&bufA[((wr * 64 + m * 16 + fr) * BK + ck0) ^ 32];
#pragma unroll
    for (int n = 0; n < 4; ++n)
      bg[n] = *(const bf16x8*)&bufB[((wc * 64 + n * 16 + fr) * BK + ck0) ^ 32];
#pragma unroll
    for (int m = 0; m < 4; ++m)
#pragma unroll
      for (int n = 0; n < 4; ++n)
        acc[m][n] = __builtin_amdgcn_mfma_f32_16x16x32_bf16(af[m], bg[n], acc[m][n], 0, 0, 0);

    __syncthreads();
    cur ^= 1;
  }

  const int lrow = h * 4;
  float* Cf = (float*)Cv + (long long)bz * sC;
  short* Cs = (short*)Cv + (long long)bz * sC;
  int colg[4]; float bvv[4];
#pragma unroll
  for (int n = 0; n < 4; ++n) {
    colg[n] = bcol + wc * 64 + n * 16 + fr;
    bvv[n] = (BIASMODE == 1) ? b0[colg[n]] : 0.f;
  }
#pragma unroll
  for (int m = 0; m < 4; ++m) {
    const int row = brow + wr * 64 + m * 16 + lrow;
#pragma unroll
    for (int j = 0; j < 4; ++j) {
#pragma unroll
      for (int n = 0; n < 4; ++n) {
        const float val = (acc[m][n][j] + bvv[n]) * scale;
        if constexpr (OUTF32) Cf[(long long)(row + j) * ldc + colg[n]] = val;
        else                  Cs[(long long)(row + j) * ldc + colg[n]] = f2bf(val);
      }
    }
  }
}

// ===========================================================================
// Single-buffered 128x128 core (32 KB LDS, 4 blocks/CU) — the occ-4 engine.
// G kernel: G = (ybf @ MTb^T + wvec)/32, 512 wgs.
// ===========================================================================
__global__ __launch_bounds__(256, 4)
void gemm_g(const short* __restrict__ ybf, const short* __restrict__ MTb,
            short* __restrict__ G, const float* __restrict__ wvec)
{
  const int orig = blockIdx.x;                  // 512 wgs
  const int xcd = orig & 7, idx8 = orig >> 3;
  const int wg = xcd * 64 + idx8;               // q8=64, r8=0
  const int bi = wg >> 3, bj = wg & 7;

  __shared__ __align__(16) short lA[BM * BK];   // 16 KB
  __shared__ __align__(16) short lB[BN * BK];   // 16 KB

  const int tid = threadIdx.x, wave = tid >> 6, lane = tid & 63;
  const int wr = wave >> 1, wc = wave & 1;
  const int brow = bi * BM, bcol = bj * BN;
  const int fr = lane & 15, h = lane >> 4;

  const int ck0 = ((h ^ (fr & 7))) * 8;
  const int swc = ((tid & 7) ^ ((tid >> 3) & 7)) * 8;
  const short* pA = ybf + (long long)(brow + (tid >> 3)) * 1024 + swc;
  const short* pB = MTb + (long long)(bcol + (tid >> 3)) * 1024 + swc;

  f32x4 acc[4][4] = {};

  for (int t = 0; t < 16; ++t) {
    const long long ko = (long long)t * BK;
#pragma unroll
    for (int j = 0; j < 4; ++j)
      gl_lds16(pA + (long long)(j * 32) * 1024 + ko, &lA[j * 2048 + tid * 8]);
#pragma unroll
    for (int j = 0; j < 4; ++j)
      gl_lds16(pB + (long long)(j * 32) * 1024 + ko, &lB[j * 2048 + tid * 8]);
    __syncthreads();

    bf16x8 af[4], bg[4];
#pragma unroll
    for (int m = 0; m < 4; ++m)
      af[m] = *(const bf16x8*)&lA[(wr * 64 + m * 16 + fr) * BK + ck0];
#pragma unroll
    for (int n = 0; n < 4; ++n)
      bg[n] = *(const bf16x8*)&lB[(wc * 64 + n * 16 + fr) * BK + ck0];
#pragma unroll
    for (int m = 0; m < 4; ++m)
#pragma unroll
      for (int n = 0; n < 4; ++n)
        acc[m][n] = __builtin_amdgcn_mfma_f32_16x16x32_bf16(af[m], bg[n], acc[m][n], 0, 0, 0);
#pragma unroll
    for (int m = 0; m < 4; ++m)
      af[m] = *(const bf16x8*)&lA[((wr * 64 + m * 16 + fr) * BK + ck0) ^ 32];
#pragma unroll
    for (int n = 0; n < 4; ++n)
      bg[n] = *(const bf16x8*)&lB[((wc * 64 + n * 16 + fr) * BK + ck0) ^ 32];
#pragma unroll
    for (int m = 0; m < 4; ++m)
#pragma unroll
      for (int n = 0; n < 4; ++n)
        acc[m][n] = __builtin_amdgcn_mfma_f32_16x16x32_bf16(af[m], bg[n], acc[m][n], 0, 0, 0);
    __syncthreads();
  }

  const int lrow = h * 4;
  int colg[4]; float bvv[4];
#pragma unroll
  for (int n = 0; n < 4; ++n) {
    colg[n] = bcol + wc * 64 + n * 16 + fr;
    bvv[n] = wvec[colg[n]];
  }
#pragma unroll
  for (int m = 0; m < 4; ++m) {
    const int row = brow + wr * 64 + m * 16 + lrow;
#pragma unroll
    for (int j = 0; j < 4; ++j)
#pragma unroll
      for (int n = 0; n < 4; ++n)
        G[(long long)(row + j) * 1024 + colg[n]] =
            f2bf((acc[m][n][j] + bvv[n]) * (1.f / 32.f));
  }
}

// ===========================================================================
// R22: merged scores+zT dispatch, single-buffered, 1056 wgs = 4.1 blocks/CU.
//   wg < 544:  scores job — z = wg/136, triangular tile (bi,bj), bj<=bi:
//              scores[z] = G[z] @ ybf[z]^T   (ldc=2048)
//   wg >= 544: zT job — lwg: bi=lwg/64, bj=lwg%64:
//              zT = WvoT @ ybf^T             (ldc=8192)
// Both K=1024 (16 steps), lda=ldb=1024, bf16 out, scale 1, no bias.
// Independent jobs (PV needs zT only after softmax); both share ybf (L2).
// 1056 = 8*132 -> bijective XCD swizzle.
// ===========================================================================
__global__ __launch_bounds__(256, 4)
void gemm_sz(const short* __restrict__ G, const short* __restrict__ ybf,
             const short* __restrict__ WvoT, short* __restrict__ scores,
             short* __restrict__ zT)
{
  const int orig = blockIdx.x;                  // 1056 wgs
  const int xcd = orig & 7, idx8 = orig >> 3;
  const int wg = xcd * 132 + idx8;              // q8=132, r8=0

  const short *A, *B; short* C; int ldc, bi, bj;
  if (wg < 544) {
    const int z = wg / 136, t = wg - z * 136;
    int b = (int)((__fsqrt_rn(8.f * (float)t + 1.f) - 1.f) * 0.5f);
    if ((b + 1) * (b + 2) / 2 <= t) ++b;
    if (b * (b + 1) / 2 > t) --b;
    bi = b; bj = t - b * (b + 1) / 2;
    A = G + (long long)z * 2048 * 1024;
    B = ybf + (long long)z * 2048 * 1024;
    C = scores + (long long)z * 2048 * 2048;
    ldc = 2048;
  } else {
    const int lwg = wg - 544;
    bi = lwg >> 6; bj = lwg & 63;
    A = WvoT; B = ybf; C = zT; ldc = 8192;
  }

  __shared__ __align__(16) short lA[BM * BK];   // 16 KB
  __shared__ __align__(16) short lB[BN * BK];   // 16 KB

  const int tid = threadIdx.x, wave = tid >> 6, lane = tid & 63;
  const int wr = wave >> 1, wc = wave & 1;
  const int brow = bi * BM, bcol = bj * BN;
  const int fr = lane & 15, h = lane >> 4;

  const int ck0 = ((h ^ (fr & 7))) * 8;
  const int swc = ((tid & 7) ^ ((tid >> 3) & 7)) * 8;
  const short* pA = A + (long long)(brow + (tid >> 3)) * 1024 + swc;
  const short* pB = B + (long long)(bcol + (tid >> 3)) * 1024 + swc;

  f32x4 acc[4][4] = {};

  for (int t = 0; t < 16; ++t) {
    const long long ko = (long long)t * BK;
#pragma unroll
    for (int j = 0; j < 4; ++j)
      gl_lds16(pA + (long long)(j * 32) * 1024 + ko, &lA[j * 2048 + tid * 8]);
#pragma unroll
    for (int j = 0; j < 4; ++j)
      gl_lds16(pB + (long long)(j * 32) * 1024 + ko, &lB[j * 2048 + tid * 8]);
    __syncthreads();

    bf16x8 af[4], bg[4];
#pragma unroll
    for (int m = 0; m < 4; ++m)
      af[m] = *(const bf16x8*)&lA[(wr * 64 + m * 16 + fr) * BK + ck0];
#pragma unroll
    for (int n = 0; n < 4; ++n)
      bg[n] = *(const bf16x8*)&lB[(wc * 64 + n * 16 + fr) * BK + ck0];
#pragma unroll
    for (int m = 0; m < 4; ++m)
#pragma unroll
      for (int n = 0; n < 4; ++n)
        acc[m][n] = __builtin_amdgcn_mfma_f32_16x16x32_bf16(af[m], bg[n], acc[m][n], 0, 0, 0);
#pragma unroll
    for (int m = 0; m < 4; ++m)
      af[m] = *(const bf16x8*)&lA[((wr * 64 + m * 16 + fr) * BK + ck0) ^ 32];
#pragma unroll
    for (int n = 0; n < 4; ++n)
      bg[n] = *(const bf16x8*)&lB[((wc * 64 + n * 16 + fr) * BK + ck0) ^ 32];
#pragma unroll
    for (int m = 0; m < 4; ++m)
#pragma unroll
      for (int n = 0; n < 4; ++n)
        acc[m][n] = __builtin_amdgcn_mfma_f32_16x16x32_bf16(af[m], bg[n], acc[m][n], 0, 0, 0);
    __syncthreads();
  }

  const int lrow = h * 4;
  int colg[4];
#pragma unroll
  for (int n = 0; n < 4; ++n) colg[n] = bcol + wc * 64 + n * 16 + fr;
#pragma unroll
  for (int m = 0; m < 4; ++m) {
    const int row = brow + wr * 64 + m * 16 + lrow;
#pragma unroll
    for (int j = 0; j < 4; ++j)
#pragma unroll
      for (int n = 0; n < 4; ++n)
        C[(long long)(row + j) * ldc + colg[n]] = f2bf(acc[m][n][j]);
  }
}

// ---------------------------------------------------------------------------
// Causal-trimmed softmax: row t has t+1 live cols; load only chunks c0<=t,
// store only c0<roundup128(t+1) (keeps required zeros in the diagonal tile).
__global__ __launch_bounds__(256)
void softmax_causal_bf16_k(short* __restrict__ sc)
{
  const int T = 2048;
  const long long row = blockIdx.x;
  const int t = (int)(row & (T - 1));
  short* ps = sc + row * (long long)T;
  const int tid = threadIdx.x, wave = tid >> 6, lane = tid & 63;
  const int c0 = tid * 8;
  const int wlim = ((t >> 7) + 1) << 7;

  bf16x8 v = {};
  if (c0 <= t) v = *(const bf16x8*)&ps[c0];
  float x[8];
#pragma unroll
  for (int j = 0; j < 8; ++j) x[j] = bf2f(v[j]);

  float mx = -3.0e38f;
#pragma unroll
  for (int j = 0; j < 8; ++j) if (c0 + j <= t) mx = fmaxf(mx, x[j]);
#pragma unroll
  for (int o = 32; o; o >>= 1) mx = fmaxf(mx, __shfl_xor(mx, o, 64));
  __shared__ float red[8];
  if (lane == 0) red[wave] = mx;
  __syncthreads();
  const float M = fmaxf(fmaxf(red[0], red[1]), fmaxf(red[2], red[3]));

  float e[8], s = 0.f;
#pragma unroll
  for (int j = 0; j < 8; ++j) { e[j] = (c0 + j <= t) ? __expf(x[j] - M) : 0.f; s += e[j]; }
#pragma unroll
  for (int o = 32; o; o >>= 1) s += __shfl_xor(s, o, 64);
  if (lane == 0) red[4 + wave] = s;
  __syncthreads();
  const float inv = 1.f / (red[4] + red[5] + red[6] + red[7]);

  if (c0 < wlim) {
    bf16x8 ov;
#pragma unroll
    for (int j = 0; j < 8; ++j) ov[j] = f2bf(e[j] * inv);
    *(bf16x8*)&ps[c0] = ov;
  }
}

// ---------------------------------------------------------------------------
__global__ __launch_bounds__(256)
void cvt_y_k(const float* __restrict__ y, short* __restrict__ ybf)
{
  const long long i = (long long)blockIdx.x * 256 + threadIdx.x;
  const float4 v0 = ((const float4*)y)[i * 2];
  const float4 v1 = ((const float4*)y)[i * 2 + 1];
  bf16x8 o;
  o[0] = f2bf(v0.x); o[1] = f2bf(v0.y); o[2] = f2bf(v0.z); o[3] = f2bf(v0.w);
  o[4] = f2bf(v1.x); o[5] = f2bf(v1.y); o[6] = f2bf(v1.z); o[7] = f2bf(v1.w);
  ((bf16x8*)ybf)[i] = o;
}

// z=0: Wq plain; z=1: Wk plain; z=2: Wo TRANSPOSE -> WoT; z=3: Wv plain
__global__ __launch_bounds__(256)
void cvt_w_all_k(const float* __restrict__ w0, const float* __restrict__ w1,
                 const float* __restrict__ w2, const float* __restrict__ w3,
                 short* __restrict__ o0, short* __restrict__ o1,
                 short* __restrict__ o2, short* __restrict__ o3)
{
  const int tx = threadIdx.x & 31, ty = threadIdx.x >> 5;
  const int r0 = blockIdx.y * 32, c0 = blockIdx.x * 32;
  if (blockIdx.z != 2) {
    const float* in = (blockIdx.z == 0) ? w0 : (blockIdx.z == 1 ? w1 : w3);
    short* out      = (blockIdx.z == 0) ? o0 : (blockIdx.z == 1 ? o1 : o3);
#pragma unroll
    for (int i = 0; i < 4; ++i)
      out[(long long)(r0 + ty + 8 * i) * 1024 + c0 + tx] =
          f2bf(in[(long long)(r0 + ty + 8 * i) * 1024 + c0 + tx]);
    return;
  }
  __shared__ float tile[32][33];
#pragma unroll
  for (int i = 0; i < 4; ++i)
    tile[ty + 8 * i][tx] = w2[(long long)(r0 + ty + 8 * i) * 1024 + c0 + tx];
  __syncthreads();
#pragma unroll
  for (int i = 0; i < 4; ++i)
    o2[(long long)(c0 + ty + 8 * i) * 1024 + r0 + tx] = f2bf(tile[tx][ty + 8 * i]);
}

// outb[j] = bo[j]
__global__ __launch_bounds__(256)
void bias_init_k(const float* __restrict__ bo, float* __restrict__ outb)
{
  const int j = blockIdx.x * 256 + threadIdx.x;
  outb[j] = bo[j];
}

// outb[j] += sum over 16 rows of bv[r]*Wo[r][j]
__global__ __launch_bounds__(256)
void bias_fold_k(const float* __restrict__ bv, const float* __restrict__ Wo,
                 float* __restrict__ outb)
{
  const int r0 = blockIdx.x * 16;
  const int c4 = threadIdx.x;
  float4 acc = make_float4(0.f, 0.f, 0.f, 0.f);
  for (int r = 0; r < 16; ++r) {
    const float s = bv[r0 + r];
    const float4 w = ((const float4*)(Wo + (long long)(r0 + r) * 1024))[c4];
    acc.x += s * w.x; acc.y += s * w.y; acc.z += s * w.z; acc.w += s * w.w;
  }
  atomicAdd(&outb[c4 * 4 + 0], acc.x);
  atomicAdd(&outb[c4 * 4 + 1], acc.y);
  atomicAdd(&outb[c4 * 4 + 2], acc.z);
  atomicAdd(&outb[c4 * 4 + 3], acc.w);
}

// w[row] = sum_d Wk[row][d] * bq[d]   (fp32 GEMV, 1024 rows)
__global__ __launch_bounds__(256)
void wkbq_gemv_k(const float* __restrict__ Wk, const float* __restrict__ bq,
                 float* __restrict__ w)
{
  const int row = blockIdx.x, tid = threadIdx.x;
  const float4 a = ((const float4*)(Wk + (long long)row * 1024))[tid];
  const float4 b = ((const float4*)bq)[tid];
  float s = a.x * b.x + a.y * b.y + a.z * b.z + a.w * b.w;
#pragma unroll
  for (int o = 32; o; o >>= 1) s += __shfl_xor(s, o, 64);
  __shared__ float red[4];
  if ((tid & 63) == 0) red[tid >> 6] = s;
  __syncthreads();
  if (tid == 0) w[row] = red[0] + red[1] + red[2] + red[3];
}

// out = bf16( part0 + part1 + part2 + part3 )  (split-K combine, 1M elems)
__global__ __launch_bounds__(256)
void combine4_k(const float* __restrict__ p, short* __restrict__ out)
{
  const long long i = (long long)blockIdx.x * 256 + threadIdx.x;
  const float4 a = ((const float4*)p)[i];
  const float4 b = ((const float4*)(p + 1048576))[i];
  const float4 c = ((const float4*)(p + 2097152))[i];
  const float4 d = ((const float4*)(p + 3145728))[i];
  bf16x4 o;
  o[0] = f2bf(a.x + b.x + c.x + d.x);
  o[1] = f2bf(a.y + b.y + c.y + d.y);
  o[2] = f2bf(a.z + b.z + c.z + d.z);
  o[3] = f2bf(a.w + b.w + c.w + d.w);
  ((bf16x4*)out)[i] = o;
}

// ---------------------------------------------------------------------------
extern "C" void kernel_launch(void* const* d_in, const int* in_sizes, int n_in,
                              void* d_out, int out_size, void* d_ws, size_t ws_size,
                              hipStream_t stream)
{
  (void)in_sizes; (void)n_in; (void)out_size; (void)ws_size;
  const float* y  = (const float*)d_in[0];
  const float* Wq = (const float*)d_in[1];
  const float* bq = (const float*)d_in[2];
  const float* Wk = (const float*)d_in[3];
  const float* bk = (const float*)d_in[4];
  const float* Wv = (const float*)d_in[5];
  const float* bv = (const float*)d_in[6];
  const float* Wo = (const float*)d_in[7];
  const float* bo = (const float*)d_in[8];
  float* out = (float*)d_out;
  (void)bk;   // bk only contributes row-constant score terms -> softmax-invariant

  const int T = 2048;
  const long long MT = 8192;                          // B*T
  const long long MM = 1048576;                       // 1024*1024

  // workspace layout (shorts); ~113 MB
  short* ws    = (short*)d_ws;
  short* ybf   = ws;                                  // 16 MB
  short* WqBf  = ybf + MT * 1024;                     // 2 MB
  short* WkBf  = WqBf + MM;
  short* WoT   = WkBf + MM;
  short* WvBf  = WoT + MM;
  short* MTb   = WvBf + MM;                           // (Wk Wq^T) bf16
  short* WvoT  = MTb + MM;                            // ((Wv Wo)^T) bf16
  short* G     = WvoT + MM;                           // 8192x1024 bf16
  short* zT    = G + MT * 1024;                       // 1024x8192 bf16
  short* scores = zT + MT * 1024;                     // 4*T*T bf16 (32 MB)
  float* bvWoBo = (float*)(scores + 4ll * T * T);     // 1024 fp32
  float* wvec   = bvWoBo + 1024;                      // 1024 fp32
  float* part   = wvec + 1024;                        // 4 x 1M fp32 (16 MB, shared)

  // 1. conversions + small precomputes
  cvt_y_k<<<4096, 256, 0, stream>>>(y, ybf);
  cvt_w_all_k<<<dim3(32, 32, 4), 256, 0, stream>>>(
      Wq, Wk, Wo, Wv, WqBf, WkBf, WoT, WvBf);
  bias_init_k<<<4, 256, 0, stream>>>(bo, bvWoBo);
  bias_fold_k<<<64, 256, 0, stream>>>(bv, Wo, bvWoBo);      // bv@Wo + bo
  wkbq_gemv_k<<<1024, 256, 0, stream>>>(Wk, bq, wvec);      // w = Wk @ bq

  // 2. MTb = Wk @ Wq^T : split-K x4 fp32 partials, combine (part reused)
  gemm_bt<0, 0, true, 0><<<dim3(64, 1, 4), 256, 0, stream>>>(
      WkBf, WqBf, part, nullptr, 1.f, 256, 1024, 1024, 1024,
      256, 256, 1048576, 8);
  combine4_k<<<1024, 256, 0, stream>>>(part, MTb);

  // 3. WvoT = (Wv@Wo)^T : split-K x4 fp32 partials, combine (part reused)
  gemm_bt<0, 0, true, 0><<<dim3(64, 1, 4), 256, 0, stream>>>(
      WoT, WvBf, part, nullptr, 1.f, 256, 1024, 1024, 1024,
      256, 256, 1048576, 8);
  combine4_k<<<1024, 256, 0, stream>>>(part, WvoT);

  // 4. G = (y @ M + w) / 32 : SB occ-4 core, 512 wgs
  gemm_g<<<512, 256, 0, stream>>>(ybf, MTb, G, wvec);

  // 5. merged scores (triangular, 544) + zT (512): 1056 wgs, 4.1 blocks/CU
  gemm_sz<<<1056, 256, 0, stream>>>(G, ybf, WvoT, scores, zT);

  // 6. causal softmax in place (trimmed to live columns)
  softmax_causal_bf16_k<<<(int)MT, 256, 0, stream>>>(scores);

  // 7. out = P @ z + (bv@Wo + bo)  — final fp32, causal kend, pairing balance
  gemm_bt<2, 1, true, 3><<<dim3(16 * 8, 1, 4), 256, 0, stream>>>(
      scores, zT, out, bvWoBo, 1.f, T, T, 8192, 1024,
      (long long)T * T, 2048, 2048ll * 1024, 8);
}

// Round 7
// 175.262 us; speedup vs baseline: 1.1010x; 1.0268x over previous
//
#include <hip/hip_runtime.h>
#include <hip/hip_bf16.h>
#include <cstdint>

#define DEVI __device__ __forceinline__

typedef __attribute__((ext_vector_type(8))) short bf16x8;
typedef __attribute__((ext_vector_type(4))) short bf16x4;
typedef __attribute__((ext_vector_type(4))) float f32x4;

DEVI short f2bf(float f) {
  unsigned u = __float_as_uint(f);
  u += 0x7fff + ((u >> 16) & 1);   // round-to-nearest-even
  return (short)(u >> 16);
}
DEVI float bf2f(short s) { return __uint_as_float(((unsigned)(unsigned short)s) << 16); }

DEVI void gl_lds16(const short* g, short* l) {
  __builtin_amdgcn_global_load_lds((const __attribute__((address_space(1))) unsigned*)g,
                                   (__attribute__((address_space(3))) unsigned*)l, 16, 0, 0);
}

// ===========================================================================
// 128x128 GEMM, BK=64, double-buffered — now used ONLY for the two tiny
// split-K weight precomputes (grid 256, uniform).
// Occupancy ladder evidence (R20-R22): occ-2 dbuf = 372-614 TF on K=1024
// shapes; occ-4 single-buffer = 662-715 TF. Occupancy governs this regime.
// ===========================================================================
constexpr int BM = 128, BN = 128, BK = 64;

template<int MODE, int BIASMODE, bool OUTF32, int DECODE>
__global__ __launch_bounds__(256, 2)
void gemm_bt(const short* __restrict__ A, const short* __restrict__ B,
             void* __restrict__ Cv, const float* __restrict__ b0,
             float scale, int K, int lda, int ldb, int ldc,
             long long sA, long long sB, long long sC, int tdim)
{
  const int nwg = gridDim.x, orig = blockIdx.x;
  const int q8 = nwg >> 3, r8 = nwg & 7;
  const int xcd = orig & 7, idx8 = orig >> 3;
  const int wg = (xcd < r8 ? xcd * (q8 + 1) : r8 * (q8 + 1) + (xcd - r8) * q8) + idx8;
  const int bz = blockIdx.z;

  int bi = wg / tdim;
  const int bj = wg - bi * tdim;

  A += (long long)bz * sA;
  B += (long long)bz * sB;

  __shared__ __align__(16) short lA[2][BM * BK];   // 2 x 16 KB
  __shared__ __align__(16) short lB[2][BN * BK];   // 2 x 16 KB

  const int tid = threadIdx.x, wave = tid >> 6, lane = tid & 63;
  const int wr = wave >> 1, wc = wave & 1;
  const int brow = bi * BM, bcol = bj * BN;
  const int fr = lane & 15, h = lane >> 4;

  const int ck0 = ((h ^ (fr & 7))) * 8;            // 128B-row swizzle
  const int swc = ((tid & 7) ^ ((tid >> 3) & 7)) * 8;
  const short* pA = A + (long long)(brow + (tid >> 3)) * lda + swc;
  const short* pB = B + (long long)(bcol + (tid >> 3)) * ldb + swc;

  f32x4 acc[4][4] = {};
  const int nt = K / BK;

  auto stage = [&](int buf, int t) {
    const long long ko = (long long)t * BK;
#pragma unroll
    for (int j = 0; j < 4; ++j)
      gl_lds16(pA + (long long)(j * 32) * lda + ko, &lA[buf][j * 2048 + tid * 8]);
#pragma unroll
    for (int j = 0; j < 4; ++j)
      gl_lds16(pB + (long long)(j * 32) * ldb + ko, &lB[buf][j * 2048 + tid * 8]);
  };

  stage(0, 0);
  __syncthreads();

  int cur = 0;
  for (int t = 0; t < nt; ++t) {
    if (t + 1 < nt) stage(cur ^ 1, t + 1);

    const short* bufA = lA[cur];
    const short* bufB = lB[cur];
    bf16x8 af[4], bg[4];
#pragma unroll
    for (int m = 0; m < 4; ++m)
      af[m] = *(const bf16x8*)&bufA[(wr * 64 + m * 16 + fr) * BK + ck0];
#pragma unroll
    for (int n = 0; n < 4; ++n)
      bg[n] = *(const bf16x8*)&bufB[(wc * 64 + n * 16 + fr) * BK + ck0];
#pragma unroll
    for (int m = 0; m < 4; ++m)
#pragma unroll
      for (int n = 0; n < 4; ++n)
        acc[m][n] = __builtin_amdgcn_mfma_f32_16x16x32_bf16(af[m], bg[n], acc[m][n], 0, 0, 0);
#pragma unroll
    for (int m = 0; m < 4; ++m)
      af[m] = *(const bf16x8*)&bufA[((wr * 64 + m * 16 + fr) * BK + ck0) ^ 32];
#pragma unroll
    for (int n = 0; n < 4; ++n)
      bg[n] = *(const bf16x8*)&bufB[((wc * 64 + n * 16 + fr) * BK + ck0) ^ 32];
#pragma unroll
    for (int m = 0; m < 4; ++m)
#pragma unroll
      for (int n = 0; n < 4; ++n)
        acc[m][n] = __builtin_amdgcn_mfma_f32_16x16x32_bf16(af[m], bg[n], acc[m][n], 0, 0, 0);

    __syncthreads();
    cur ^= 1;
  }

  const int lrow = h * 4;
  float* Cf = (float*)Cv + (long long)bz * sC;
  short* Cs = (short*)Cv + (long long)bz * sC;
  int colg[4]; float bvv[4];
#pragma unroll
  for (int n = 0; n < 4; ++n) {
    colg[n] = bcol + wc * 64 + n * 16 + fr;
    bvv[n] = (BIASMODE == 1) ? b0[colg[n]] : 0.f;
  }
#pragma unroll
  for (int m = 0; m < 4; ++m) {
    const int row = brow + wr * 64 + m * 16 + lrow;
#pragma unroll
    for (int j = 0; j < 4; ++j) {
#pragma unroll
      for (int n = 0; n < 4; ++n) {
        const float val = (acc[m][n][j] + bvv[n]) * scale;
        if constexpr (OUTF32) Cf[(long long)(row + j) * ldc + colg[n]] = val;
        else                  Cs[(long long)(row + j) * ldc + colg[n]] = f2bf(val);
      }
    }
  }
}

// ===========================================================================
// Single-buffered 128x128 core (32 KB LDS, 4 blocks/CU) — the occ-4 engine.
// G kernel: G = (ybf @ MTb^T + wvec)/32, 512 wgs.
// ===========================================================================
__global__ __launch_bounds__(256, 4)
void gemm_g(const short* __restrict__ ybf, const short* __restrict__ MTb,
            short* __restrict__ G, const float* __restrict__ wvec)
{
  const int orig = blockIdx.x;                  // 512 wgs
  const int xcd = orig & 7, idx8 = orig >> 3;
  const int wg = xcd * 64 + idx8;               // q8=64, r8=0
  const int bi = wg >> 3, bj = wg & 7;

  __shared__ __align__(16) short lA[BM * BK];   // 16 KB
  __shared__ __align__(16) short lB[BN * BK];   // 16 KB

  const int tid = threadIdx.x, wave = tid >> 6, lane = tid & 63;
  const int wr = wave >> 1, wc = wave & 1;
  const int brow = bi * BM, bcol = bj * BN;
  const int fr = lane & 15, h = lane >> 4;

  const int ck0 = ((h ^ (fr & 7))) * 8;
  const int swc = ((tid & 7) ^ ((tid >> 3) & 7)) * 8;
  const short* pA = ybf + (long long)(brow + (tid >> 3)) * 1024 + swc;
  const short* pB = MTb + (long long)(bcol + (tid >> 3)) * 1024 + swc;

  f32x4 acc[4][4] = {};

  for (int t = 0; t < 16; ++t) {
    const long long ko = (long long)t * BK;
#pragma unroll
    for (int j = 0; j < 4; ++j)
      gl_lds16(pA + (long long)(j * 32) * 1024 + ko, &lA[j * 2048 + tid * 8]);
#pragma unroll
    for (int j = 0; j < 4; ++j)
      gl_lds16(pB + (long long)(j * 32) * 1024 + ko, &lB[j * 2048 + tid * 8]);
    __syncthreads();

    bf16x8 af[4], bg[4];
#pragma unroll
    for (int m = 0; m < 4; ++m)
      af[m] = *(const bf16x8*)&lA[(wr * 64 + m * 16 + fr) * BK + ck0];
#pragma unroll
    for (int n = 0; n < 4; ++n)
      bg[n] = *(const bf16x8*)&lB[(wc * 64 + n * 16 + fr) * BK + ck0];
#pragma unroll
    for (int m = 0; m < 4; ++m)
#pragma unroll
      for (int n = 0; n < 4; ++n)
        acc[m][n] = __builtin_amdgcn_mfma_f32_16x16x32_bf16(af[m], bg[n], acc[m][n], 0, 0, 0);
#pragma unroll
    for (int m = 0; m < 4; ++m)
      af[m] = *(const bf16x8*)&lA[((wr * 64 + m * 16 + fr) * BK + ck0) ^ 32];
#pragma unroll
    for (int n = 0; n < 4; ++n)
      bg[n] = *(const bf16x8*)&lB[((wc * 64 + n * 16 + fr) * BK + ck0) ^ 32];
#pragma unroll
    for (int m = 0; m < 4; ++m)
#pragma unroll
      for (int n = 0; n < 4; ++n)
        acc[m][n] = __builtin_amdgcn_mfma_f32_16x16x32_bf16(af[m], bg[n], acc[m][n], 0, 0, 0);
    __syncthreads();
  }

  const int lrow = h * 4;
  int colg[4]; float bvv[4];
#pragma unroll
  for (int n = 0; n < 4; ++n) {
    colg[n] = bcol + wc * 64 + n * 16 + fr;
    bvv[n] = wvec[colg[n]];
  }
#pragma unroll
  for (int m = 0; m < 4; ++m) {
    const int row = brow + wr * 64 + m * 16 + lrow;
#pragma unroll
    for (int j = 0; j < 4; ++j)
#pragma unroll
      for (int n = 0; n < 4; ++n)
        G[(long long)(row + j) * 1024 + colg[n]] =
            f2bf((acc[m][n][j] + bvv[n]) * (1.f / 32.f));
  }
}

// ===========================================================================
// Merged scores+zT dispatch, single-buffered, 1056 wgs = 4.1 blocks/CU.
// R22-measured: 53.6us, 662 TF, MfmaUtil 25.8, Occ 23.8.
// ===========================================================================
__global__ __launch_bounds__(256, 4)
void gemm_sz(const short* __restrict__ G, const short* __restrict__ ybf,
             const short* __restrict__ WvoT, short* __restrict__ scores,
             short* __restrict__ zT)
{
  const int orig = blockIdx.x;                  // 1056 wgs
  const int xcd = orig & 7, idx8 = orig >> 3;
  const int wg = xcd * 132 + idx8;              // q8=132, r8=0

  const short *A, *B; short* C; int ldc, bi, bj;
  if (wg < 544) {
    const int z = wg / 136, t = wg - z * 136;
    int b = (int)((__fsqrt_rn(8.f * (float)t + 1.f) - 1.f) * 0.5f);
    if ((b + 1) * (b + 2) / 2 <= t) ++b;
    if (b * (b + 1) / 2 > t) --b;
    bi = b; bj = t - b * (b + 1) / 2;
    A = G + (long long)z * 2048 * 1024;
    B = ybf + (long long)z * 2048 * 1024;
    C = scores + (long long)z * 2048 * 2048;
    ldc = 2048;
  } else {
    const int lwg = wg - 544;
    bi = lwg >> 6; bj = lwg & 63;
    A = WvoT; B = ybf; C = zT; ldc = 8192;
  }

  __shared__ __align__(16) short lA[BM * BK];   // 16 KB
  __shared__ __align__(16) short lB[BN * BK];   // 16 KB

  const int tid = threadIdx.x, wave = tid >> 6, lane = tid & 63;
  const int wr = wave >> 1, wc = wave & 1;
  const int brow = bi * BM, bcol = bj * BN;
  const int fr = lane & 15, h = lane >> 4;

  const int ck0 = ((h ^ (fr & 7))) * 8;
  const int swc = ((tid & 7) ^ ((tid >> 3) & 7)) * 8;
  const short* pA = A + (long long)(brow + (tid >> 3)) * 1024 + swc;
  const short* pB = B + (long long)(bcol + (tid >> 3)) * 1024 + swc;

  f32x4 acc[4][4] = {};

  for (int t = 0; t < 16; ++t) {
    const long long ko = (long long)t * BK;
#pragma unroll
    for (int j = 0; j < 4; ++j)
      gl_lds16(pA + (long long)(j * 32) * 1024 + ko, &lA[j * 2048 + tid * 8]);
#pragma unroll
    for (int j = 0; j < 4; ++j)
      gl_lds16(pB + (long long)(j * 32) * 1024 + ko, &lB[j * 2048 + tid * 8]);
    __syncthreads();

    bf16x8 af[4], bg[4];
#pragma unroll
    for (int m = 0; m < 4; ++m)
      af[m] = *(const bf16x8*)&lA[(wr * 64 + m * 16 + fr) * BK + ck0];
#pragma unroll
    for (int n = 0; n < 4; ++n)
      bg[n] = *(const bf16x8*)&lB[(wc * 64 + n * 16 + fr) * BK + ck0];
#pragma unroll
    for (int m = 0; m < 4; ++m)
#pragma unroll
      for (int n = 0; n < 4; ++n)
        acc[m][n] = __builtin_amdgcn_mfma_f32_16x16x32_bf16(af[m], bg[n], acc[m][n], 0, 0, 0);
#pragma unroll
    for (int m = 0; m < 4; ++m)
      af[m] = *(const bf16x8*)&lA[((wr * 64 + m * 16 + fr) * BK + ck0) ^ 32];
#pragma unroll
    for (int n = 0; n < 4; ++n)
      bg[n] = *(const bf16x8*)&lB[((wc * 64 + n * 16 + fr) * BK + ck0) ^ 32];
#pragma unroll
    for (int m = 0; m < 4; ++m)
#pragma unroll
      for (int n = 0; n < 4; ++n)
        acc[m][n] = __builtin_amdgcn_mfma_f32_16x16x32_bf16(af[m], bg[n], acc[m][n], 0, 0, 0);
    __syncthreads();
  }

  const int lrow = h * 4;
  int colg[4];
#pragma unroll
  for (int n = 0; n < 4; ++n) colg[n] = bcol + wc * 64 + n * 16 + fr;
#pragma unroll
  for (int m = 0; m < 4; ++m) {
    const int row = brow + wr * 64 + m * 16 + lrow;
#pragma unroll
    for (int j = 0; j < 4; ++j)
#pragma unroll
      for (int n = 0; n < 4; ++n)
        C[(long long)(row + j) * ldc + colg[n]] = f2bf(acc[m][n][j]);
  }
}

// ===========================================================================
// R23: PV as 64x64-tile single-buffered kernel, 2048 wgs (8/CU work supply,
// 6/CU resident -> queue backfill). Parity-interleaved decode
// bi = ((idx8>>4)<<1)|(xcd&1) makes per-CU Snt spread ~1.2:1 (vs 3:1 naive).
// Causal kend at 64-row granularity. out = P @ z + bias (final fp32).
// ===========================================================================
__global__ __launch_bounds__(256, 6)
void gemm_pv(const short* __restrict__ scores, const short* __restrict__ zT,
             float* __restrict__ out, const float* __restrict__ bias)
{
  const int orig = blockIdx.x;                 // 2048 wgs
  const int xcd = orig & 7, idx8 = orig >> 3;  // idx8 in [0,256)
  const int z = xcd >> 1;                      // batch
  const int bi = ((idx8 >> 4) << 1) | (xcd & 1);   // 0..31, parity-interleaved
  const int bj = idx8 & 15;                        // 0..15

  const short* A = scores + (long long)z * 2048 * 2048;
  const int nt = bi + 1;                       // kend = (bi+1)*64, causal

  __shared__ __align__(16) short lA[64 * 64];  // 8 KB
  __shared__ __align__(16) short lB[64 * 64];  // 8 KB

  const int tid = threadIdx.x, wave = tid >> 6, lane = tid & 63;
  const int wm = wave >> 1, wn = wave & 1;
  const int brow = bi * 64, bcol = bj * 64;
  const int fr = lane & 15, h = lane >> 4;

  const int ck0 = ((h ^ (fr & 7))) * 8;
  const int swc = ((tid & 7) ^ ((tid >> 3) & 7)) * 8;
  const short* pA = A + (long long)(brow + (tid >> 3)) * 2048 + swc;
  const short* pB = zT + (long long)(bcol + (tid >> 3)) * 8192 + z * 2048 + swc;

  f32x4 acc[2][2] = {};

  for (int t = 0; t < nt; ++t) {
    const long long ko = (long long)t * 64;
#pragma unroll
    for (int j = 0; j < 2; ++j)
      gl_lds16(pA + (long long)(j * 32) * 2048 + ko, &lA[j * 2048 + tid * 8]);
#pragma unroll
    for (int j = 0; j < 2; ++j)
      gl_lds16(pB + (long long)(j * 32) * 8192 + ko, &lB[j * 2048 + tid * 8]);
    __syncthreads();

    bf16x8 af[2], bg[2];
#pragma unroll
    for (int m = 0; m < 2; ++m)
      af[m] = *(const bf16x8*)&lA[(wm * 32 + m * 16 + fr) * 64 + ck0];
#pragma unroll
    for (int n = 0; n < 2; ++n)
      bg[n] = *(const bf16x8*)&lB[(wn * 32 + n * 16 + fr) * 64 + ck0];
#pragma unroll
    for (int m = 0; m < 2; ++m)
#pragma unroll
      for (int n = 0; n < 2; ++n)
        acc[m][n] = __builtin_amdgcn_mfma_f32_16x16x32_bf16(af[m], bg[n], acc[m][n], 0, 0, 0);
#pragma unroll
    for (int m = 0; m < 2; ++m)
      af[m] = *(const bf16x8*)&lA[((wm * 32 + m * 16 + fr) * 64 + ck0) ^ 32];
#pragma unroll
    for (int n = 0; n < 2; ++n)
      bg[n] = *(const bf16x8*)&lB[((wn * 32 + n * 16 + fr) * 64 + ck0) ^ 32];
#pragma unroll
    for (int m = 0; m < 2; ++m)
#pragma unroll
      for (int n = 0; n < 2; ++n)
        acc[m][n] = __builtin_amdgcn_mfma_f32_16x16x32_bf16(af[m], bg[n], acc[m][n], 0, 0, 0);
    __syncthreads();
  }

  const int lrow = h * 4;
  int colg[2]; float bvv[2];
#pragma unroll
  for (int n = 0; n < 2; ++n) {
    colg[n] = bcol + wn * 32 + n * 16 + fr;
    bvv[n] = bias[colg[n]];
  }
#pragma unroll
  for (int m = 0; m < 2; ++m) {
    const int row = brow + wm * 32 + m * 16 + lrow;
#pragma unroll
    for (int j = 0; j < 4; ++j)
#pragma unroll
      for (int n = 0; n < 2; ++n)
        out[(long long)(z * 2048 + row + j) * 1024 + colg[n]] = acc[m][n][j] + bvv[n];
  }
}

// ---------------------------------------------------------------------------
// Causal-trimmed softmax: row t has t+1 live cols; load only chunks c0<=t,
// store only c0<roundup128(t+1)... wlim now 64-aligned for the 64-row PV
// tiles: roundup64(t+1) covers every col PV reads (kend=(bi+1)*64).
__global__ __launch_bounds__(256)
void softmax_causal_bf16_k(short* __restrict__ sc)
{
  const int T = 2048;
  const long long row = blockIdx.x;
  const int t = (int)(row & (T - 1));
  short* ps = sc + row * (long long)T;
  const int tid = threadIdx.x, wave = tid >> 6, lane = tid & 63;
  const int c0 = tid * 8;
  const int wlim = ((t >> 6) + 1) << 6;   // exclusive write limit, 64-aligned

  bf16x8 v = {};
  if (c0 <= t) v = *(const bf16x8*)&ps[c0];
  float x[8];
#pragma unroll
  for (int j = 0; j < 8; ++j) x[j] = bf2f(v[j]);

  float mx = -3.0e38f;
#pragma unroll
  for (int j = 0; j < 8; ++j) if (c0 + j <= t) mx = fmaxf(mx, x[j]);
#pragma unroll
  for (int o = 32; o; o >>= 1) mx = fmaxf(mx, __shfl_xor(mx, o, 64));
  __shared__ float red[8];
  if (lane == 0) red[wave] = mx;
  __syncthreads();
  const float M = fmaxf(fmaxf(red[0], red[1]), fmaxf(red[2], red[3]));

  float e[8], s = 0.f;
#pragma unroll
  for (int j = 0; j < 8; ++j) { e[j] = (c0 + j <= t) ? __expf(x[j] - M) : 0.f; s += e[j]; }
#pragma unroll
  for (int o = 32; o; o >>= 1) s += __shfl_xor(s, o, 64);
  if (lane == 0) red[4 + wave] = s;
  __syncthreads();
  const float inv = 1.f / (red[4] + red[5] + red[6] + red[7]);

  if (c0 < wlim) {
    bf16x8 ov;
#pragma unroll
    for (int j = 0; j < 8; ++j) ov[j] = f2bf(e[j] * inv);
    *(bf16x8*)&ps[c0] = ov;
  }
}

// ---------------------------------------------------------------------------
__global__ __launch_bounds__(256)
void cvt_y_k(const float* __restrict__ y, short* __restrict__ ybf)
{
  const long long i = (long long)blockIdx.x * 256 + threadIdx.x;
  const float4 v0 = ((const float4*)y)[i * 2];
  const float4 v1 = ((const float4*)y)[i * 2 + 1];
  bf16x8 o;
  o[0] = f2bf(v0.x); o[1] = f2bf(v0.y); o[2] = f2bf(v0.z); o[3] = f2bf(v0.w);
  o[4] = f2bf(v1.x); o[5] = f2bf(v1.y); o[6] = f2bf(v1.z); o[7] = f2bf(v1.w);
  ((bf16x8*)ybf)[i] = o;
}

// z=0: Wq plain; z=1: Wk plain; z=2: Wo TRANSPOSE -> WoT; z=3: Wv plain
__global__ __launch_bounds__(256)
void cvt_w_all_k(const float* __restrict__ w0, const float* __restrict__ w1,
                 const float* __restrict__ w2, const float* __restrict__ w3,
                 short* __restrict__ o0, short* __restrict__ o1,
                 short* __restrict__ o2, short* __restrict__ o3)
{
  const int tx = threadIdx.x & 31, ty = threadIdx.x >> 5;
  const int r0 = blockIdx.y * 32, c0 = blockIdx.x * 32;
  if (blockIdx.z != 2) {
    const float* in = (blockIdx.z == 0) ? w0 : (blockIdx.z == 1 ? w1 : w3);
    short* out      = (blockIdx.z == 0) ? o0 : (blockIdx.z == 1 ? o1 : o3);
#pragma unroll
    for (int i = 0; i < 4; ++i)
      out[(long long)(r0 + ty + 8 * i) * 1024 + c0 + tx] =
          f2bf(in[(long long)(r0 + ty + 8 * i) * 1024 + c0 + tx]);
    return;
  }
  __shared__ float tile[32][33];
#pragma unroll
  for (int i = 0; i < 4; ++i)
    tile[ty + 8 * i][tx] = w2[(long long)(r0 + ty + 8 * i) * 1024 + c0 + tx];
  __syncthreads();
#pragma unroll
  for (int i = 0; i < 4; ++i)
    o2[(long long)(c0 + ty + 8 * i) * 1024 + r0 + tx] = f2bf(tile[tx][ty + 8 * i]);
}

// outb[j] = bo[j]
__global__ __launch_bounds__(256)
void bias_init_k(const float* __restrict__ bo, float* __restrict__ outb)
{
  const int j = blockIdx.x * 256 + threadIdx.x;
  outb[j] = bo[j];
}

// outb[j] += sum over 16 rows of bv[r]*Wo[r][j]
__global__ __launch_bounds__(256)
void bias_fold_k(const float* __restrict__ bv, const float* __restrict__ Wo,
                 float* __restrict__ outb)
{
  const int r0 = blockIdx.x * 16;
  const int c4 = threadIdx.x;
  float4 acc = make_float4(0.f, 0.f, 0.f, 0.f);
  for (int r = 0; r < 16; ++r) {
    const float s = bv[r0 + r];
    const float4 w = ((const float4*)(Wo + (long long)(r0 + r) * 1024))[c4];
    acc.x += s * w.x; acc.y += s * w.y; acc.z += s * w.z; acc.w += s * w.w;
  }
  atomicAdd(&outb[c4 * 4 + 0], acc.x);
  atomicAdd(&outb[c4 * 4 + 1], acc.y);
  atomicAdd(&outb[c4 * 4 + 2], acc.z);
  atomicAdd(&outb[c4 * 4 + 3], acc.w);
}

// w[row] = sum_d Wk[row][d] * bq[d]   (fp32 GEMV, 1024 rows)
__global__ __launch_bounds__(256)
void wkbq_gemv_k(const float* __restrict__ Wk, const float* __restrict__ bq,
                 float* __restrict__ w)
{
  const int row = blockIdx.x, tid = threadIdx.x;
  const float4 a = ((const float4*)(Wk + (long long)row * 1024))[tid];
  const float4 b = ((const float4*)bq)[tid];
  float s = a.x * b.x + a.y * b.y + a.z * b.z + a.w * b.w;
#pragma unroll
  for (int o = 32; o; o >>= 1) s += __shfl_xor(s, o, 64);
  __shared__ float red[4];
  if ((tid & 63) == 0) red[tid >> 6] = s;
  __syncthreads();
  if (tid == 0) w[row] = red[0] + red[1] + red[2] + red[3];
}

// out = bf16( part0 + part1 + part2 + part3 )  (split-K combine, 1M elems)
__global__ __launch_bounds__(256)
void combine4_k(const float* __restrict__ p, short* __restrict__ out)
{
  const long long i = (long long)blockIdx.x * 256 + threadIdx.x;
  const float4 a = ((const float4*)p)[i];
  const float4 b = ((const float4*)(p + 1048576))[i];
  const float4 c = ((const float4*)(p + 2097152))[i];
  const float4 d = ((const float4*)(p + 3145728))[i];
  bf16x4 o;
  o[0] = f2bf(a.x + b.x + c.x + d.x);
  o[1] = f2bf(a.y + b.y + c.y + d.y);
  o[2] = f2bf(a.z + b.z + c.z + d.z);
  o[3] = f2bf(a.w + b.w + c.w + d.w);
  ((bf16x4*)out)[i] = o;
}

// ---------------------------------------------------------------------------
extern "C" void kernel_launch(void* const* d_in, const int* in_sizes, int n_in,
                              void* d_out, int out_size, void* d_ws, size_t ws_size,
                              hipStream_t stream)
{
  (void)in_sizes; (void)n_in; (void)out_size; (void)ws_size;
  const float* y  = (const float*)d_in[0];
  const float* Wq = (const float*)d_in[1];
  const float* bq = (const float*)d_in[2];
  const float* Wk = (const float*)d_in[3];
  const float* bk = (const float*)d_in[4];
  const float* Wv = (const float*)d_in[5];
  const float* bv = (const float*)d_in[6];
  const float* Wo = (const float*)d_in[7];
  const float* bo = (const float*)d_in[8];
  float* out = (float*)d_out;
  (void)bk;   // bk only contributes row-constant score terms -> softmax-invariant

  const int T = 2048;
  const long long MT = 8192;                          // B*T
  const long long MM = 1048576;                       // 1024*1024

  // workspace layout (shorts); ~113 MB
  short* ws    = (short*)d_ws;
  short* ybf   = ws;                                  // 16 MB
  short* WqBf  = ybf + MT * 1024;                     // 2 MB
  short* WkBf  = WqBf + MM;
  short* WoT   = WkBf + MM;
  short* WvBf  = WoT + MM;
  short* MTb   = WvBf + MM;                           // (Wk Wq^T) bf16
  short* WvoT  = MTb + MM;                            // ((Wv Wo)^T) bf16
  short* G     = WvoT + MM;                           // 8192x1024 bf16
  short* zT    = G + MT * 1024;                       // 1024x8192 bf16
  short* scores = zT + MT * 1024;                     // 4*T*T bf16 (32 MB)
  float* bvWoBo = (float*)(scores + 4ll * T * T);     // 1024 fp32
  float* wvec   = bvWoBo + 1024;                      // 1024 fp32
  float* part   = wvec + 1024;                        // 4 x 1M fp32 (16 MB, shared)

  // 1. conversions + small precomputes
  cvt_y_k<<<4096, 256, 0, stream>>>(y, ybf);
  cvt_w_all_k<<<dim3(32, 32, 4), 256, 0, stream>>>(
      Wq, Wk, Wo, Wv, WqBf, WkBf, WoT, WvBf);
  bias_init_k<<<4, 256, 0, stream>>>(bo, bvWoBo);
  bias_fold_k<<<64, 256, 0, stream>>>(bv, Wo, bvWoBo);      // bv@Wo + bo
  wkbq_gemv_k<<<1024, 256, 0, stream>>>(Wk, bq, wvec);      // w = Wk @ bq

  // 2. MTb = Wk @ Wq^T : split-K x4 fp32 partials, combine (part reused)
  gemm_bt<0, 0, true, 0><<<dim3(64, 1, 4), 256, 0, stream>>>(
      WkBf, WqBf, part, nullptr, 1.f, 256, 1024, 1024, 1024,
      256, 256, 1048576, 8);
  combine4_k<<<1024, 256, 0, stream>>>(part, MTb);

  // 3. WvoT = (Wv@Wo)^T : split-K x4 fp32 partials, combine (part reused)
  gemm_bt<0, 0, true, 0><<<dim3(64, 1, 4), 256, 0, stream>>>(
      WoT, WvBf, part, nullptr, 1.f, 256, 1024, 1024, 1024,
      256, 256, 1048576, 8);
  combine4_k<<<1024, 256, 0, stream>>>(part, WvoT);

  // 4. G = (y @ M + w) / 32 : SB occ-4 core, 512 wgs
  gemm_g<<<512, 256, 0, stream>>>(ybf, MTb, G, wvec);

  // 5. merged scores (triangular, 544) + zT (512): 1056 wgs, 4.1 blocks/CU
  gemm_sz<<<1056, 256, 0, stream>>>(G, ybf, WvoT, scores, zT);

  // 6. causal softmax in place (trimmed to live columns)
  softmax_causal_bf16_k<<<(int)MT, 256, 0, stream>>>(scores);

  // 7. out = P @ z + (bv@Wo + bo) : 64x64 SB occ-6 core, 2048 wgs
  gemm_pv<<<2048, 256, 0, stream>>>(scores, zT, out, bvWoBo);
}

// Round 8
// 162.627 us; speedup vs baseline: 1.1866x; 1.0777x over previous
//
#include <hip/hip_runtime.h>
#include <hip/hip_bf16.h>
#include <cstdint>

#define DEVI __device__ __forceinline__

typedef __attribute__((ext_vector_type(8))) short bf16x8;
typedef __attribute__((ext_vector_type(4))) short bf16x4;
typedef __attribute__((ext_vector_type(4))) float f32x4;

DEVI short f2bf(float f) {
  unsigned u = __float_as_uint(f);
  u += 0x7fff + ((u >> 16) & 1);   // round-to-nearest-even
  return (short)(u >> 16);
}
DEVI float bf2f(short s) { return __uint_as_float(((unsigned)(unsigned short)s) << 16); }

DEVI void gl_lds16(const short* g, short* l) {
  __builtin_amdgcn_global_load_lds((const __attribute__((address_space(1))) unsigned*)g,
                                   (__attribute__((address_space(3))) unsigned*)l, 16, 0, 0);
}

// ===========================================================================
// Occupancy ladder (R20-R23, measured): K=1024-class GEMMs at
//   occ-2 dbuf 128^2      = 372-614 TF
//   occ-4 SB   128^2      = 662-715 TF  (gemm_sz R22: 53.6us, Occ 24%)
//   occ-6 SB   64^2 (PV)  = ~540 TF on thin causal shape
// R24: gemm_sz & gemm_g -> 128x64 tiles, 24KB LDS, occ-6, 2x grid supply.
// ===========================================================================

// ---------------------------------------------------------------------------
// gemm_ww: BOTH split-K weight precomputes in one dispatch (512 wgs).
//   job 0: partM[z] = WkBf @ WqBf^T  (k-quarter z)
//   job 1: partW[z] = WoT  @ WvBf^T
// 128x128 SB core, K=256 per z (4 steps), fp32 partials.
// ---------------------------------------------------------------------------
__global__ __launch_bounds__(256, 4)
void gemm_ww(const short* __restrict__ WkBf, const short* __restrict__ WqBf,
             const short* __restrict__ WoT, const short* __restrict__ WvBf,
             float* __restrict__ partM, float* __restrict__ partW)
{
  const int orig = blockIdx.x;                  // 512 wgs
  const int xcd = orig & 7, idx8 = orig >> 3;
  const int wg = xcd * 64 + idx8;               // q8=64
  const int job = wg >> 8, rem = wg & 255;
  const int z = rem >> 6, t = rem & 63;
  const int bi = t >> 3, bj = t & 7;

  const short* A = job ? WoT  : WkBf;
  const short* B = job ? WvBf : WqBf;
  float* Cf = (job ? partW : partM) + (long long)z * 1048576;

  __shared__ __align__(16) short lA[128 * 64];  // 16 KB
  __shared__ __align__(16) short lB[128 * 64];  // 16 KB

  const int tid = threadIdx.x, wave = tid >> 6, lane = tid & 63;
  const int wr = wave >> 1, wc = wave & 1;
  const int brow = bi * 128, bcol = bj * 128;
  const int fr = lane & 15, h = lane >> 4;

  const int ck0 = ((h ^ (fr & 7))) * 8;
  const int swc = ((tid & 7) ^ ((tid >> 3) & 7)) * 8;
  const short* pA = A + (long long)(brow + (tid >> 3)) * 1024 + swc;
  const short* pB = B + (long long)(bcol + (tid >> 3)) * 1024 + swc;

  f32x4 acc[4][4] = {};
  const long long ko0 = (long long)z * 256;

  for (int t2 = 0; t2 < 4; ++t2) {
    const long long ko = ko0 + t2 * 64;
#pragma unroll
    for (int j = 0; j < 4; ++j)
      gl_lds16(pA + (long long)(j * 32) * 1024 + ko, &lA[j * 2048 + tid * 8]);
#pragma unroll
    for (int j = 0; j < 4; ++j)
      gl_lds16(pB + (long long)(j * 32) * 1024 + ko, &lB[j * 2048 + tid * 8]);
    __syncthreads();

    bf16x8 af[4], bg[4];
#pragma unroll
    for (int m = 0; m < 4; ++m)
      af[m] = *(const bf16x8*)&lA[(wr * 64 + m * 16 + fr) * 64 + ck0];
#pragma unroll
    for (int n = 0; n < 4; ++n)
      bg[n] = *(const bf16x8*)&lB[(wc * 64 + n * 16 + fr) * 64 + ck0];
#pragma unroll
    for (int m = 0; m < 4; ++m)
#pragma unroll
      for (int n = 0; n < 4; ++n)
        acc[m][n] = __builtin_amdgcn_mfma_f32_16x16x32_bf16(af[m], bg[n], acc[m][n], 0, 0, 0);
#pragma unroll
    for (int m = 0; m < 4; ++m)
      af[m] = *(const bf16x8*)&lA[((wr * 64 + m * 16 + fr) * 64 + ck0) ^ 32];
#pragma unroll
    for (int n = 0; n < 4; ++n)
      bg[n] = *(const bf16x8*)&lB[((wc * 64 + n * 16 + fr) * 64 + ck0) ^ 32];
#pragma unroll
    for (int m = 0; m < 4; ++m)
#pragma unroll
      for (int n = 0; n < 4; ++n)
        acc[m][n] = __builtin_amdgcn_mfma_f32_16x16x32_bf16(af[m], bg[n], acc[m][n], 0, 0, 0);
    __syncthreads();
  }

  const int lrow = h * 4;
#pragma unroll
  for (int m = 0; m < 4; ++m) {
    const int row = brow + wr * 64 + m * 16 + lrow;
#pragma unroll
    for (int j = 0; j < 4; ++j)
#pragma unroll
      for (int n = 0; n < 4; ++n)
        Cf[(long long)(row + j) * 1024 + bcol + wc * 64 + n * 16 + fr] = acc[m][n][j];
  }
}

// combine both split-K results: wg<1024 -> MTb, else WvoT (1M elems each)
__global__ __launch_bounds__(256)
void combine_ww(const float* __restrict__ partM, const float* __restrict__ partW,
                short* __restrict__ MTb, short* __restrict__ WvoT)
{
  const int wg = blockIdx.x;
  const float* p = (wg < 1024) ? partM : partW;
  short* out = (wg < 1024) ? MTb : WvoT;
  const long long i = (long long)(wg & 1023) * 256 + threadIdx.x;  // float4 idx
  const float4 a = ((const float4*)p)[i];
  const float4 b = ((const float4*)(p + 1048576))[i];
  const float4 c = ((const float4*)(p + 2097152))[i];
  const float4 d = ((const float4*)(p + 3145728))[i];
  bf16x4 o;
  o[0] = f2bf(a.x + b.x + c.x + d.x);
  o[1] = f2bf(a.y + b.y + c.y + d.y);
  o[2] = f2bf(a.z + b.z + c.z + d.z);
  o[3] = f2bf(a.w + b.w + c.w + d.w);
  ((bf16x4*)out)[i] = o;
}

// ---------------------------------------------------------------------------
// gemm_g2: G = (ybf @ MTb^T + wvec)/32. 128x64 tiles, occ-6, 1024 wgs.
// ---------------------------------------------------------------------------
__global__ __launch_bounds__(256, 6)
void gemm_g2(const short* __restrict__ ybf, const short* __restrict__ MTb,
             short* __restrict__ G, const float* __restrict__ wvec)
{
  const int orig = blockIdx.x;                  // 1024 wgs
  const int xcd = orig & 7, idx8 = orig >> 3;
  const int wg = xcd * 128 + idx8;              // q8=128
  const int bi = wg >> 4, bj = wg & 15;         // 64 row-tiles x 16 col-tiles

  __shared__ __align__(16) short lA[128 * 64];  // 16 KB
  __shared__ __align__(16) short lB[64 * 64];   // 8 KB

  const int tid = threadIdx.x, wave = tid >> 6, lane = tid & 63;
  const int wr = wave >> 1, wc = wave & 1;
  const int brow = bi * 128, bcol = bj * 64;
  const int fr = lane & 15, h = lane >> 4;

  const int ck0 = ((h ^ (fr & 7))) * 8;
  const int swc = ((tid & 7) ^ ((tid >> 3) & 7)) * 8;
  const short* pA = ybf + (long long)(brow + (tid >> 3)) * 1024 + swc;
  const short* pB = MTb + (long long)(bcol + (tid >> 3)) * 1024 + swc;

  f32x4 acc[4][2] = {};

  for (int t = 0; t < 16; ++t) {
    const long long ko = (long long)t * 64;
#pragma unroll
    for (int j = 0; j < 4; ++j)
      gl_lds16(pA + (long long)(j * 32) * 1024 + ko, &lA[j * 2048 + tid * 8]);
#pragma unroll
    for (int j = 0; j < 2; ++j)
      gl_lds16(pB + (long long)(j * 32) * 1024 + ko, &lB[j * 2048 + tid * 8]);
    __syncthreads();

    bf16x8 af[4], bg[2];
#pragma unroll
    for (int m = 0; m < 4; ++m)
      af[m] = *(const bf16x8*)&lA[(wr * 64 + m * 16 + fr) * 64 + ck0];
#pragma unroll
    for (int n = 0; n < 2; ++n)
      bg[n] = *(const bf16x8*)&lB[(wc * 32 + n * 16 + fr) * 64 + ck0];
#pragma unroll
    for (int m = 0; m < 4; ++m)
#pragma unroll
      for (int n = 0; n < 2; ++n)
        acc[m][n] = __builtin_amdgcn_mfma_f32_16x16x32_bf16(af[m], bg[n], acc[m][n], 0, 0, 0);
#pragma unroll
    for (int m = 0; m < 4; ++m)
      af[m] = *(const bf16x8*)&lA[((wr * 64 + m * 16 + fr) * 64 + ck0) ^ 32];
#pragma unroll
    for (int n = 0; n < 2; ++n)
      bg[n] = *(const bf16x8*)&lB[((wc * 32 + n * 16 + fr) * 64 + ck0) ^ 32];
#pragma unroll
    for (int m = 0; m < 4; ++m)
#pragma unroll
      for (int n = 0; n < 2; ++n)
        acc[m][n] = __builtin_amdgcn_mfma_f32_16x16x32_bf16(af[m], bg[n], acc[m][n], 0, 0, 0);
    __syncthreads();
  }

  const int lrow = h * 4;
  int colg[2]; float bvv[2];
#pragma unroll
  for (int n = 0; n < 2; ++n) {
    colg[n] = bcol + wc * 32 + n * 16 + fr;
    bvv[n] = wvec[colg[n]];
  }
#pragma unroll
  for (int m = 0; m < 4; ++m) {
    const int row = brow + wr * 64 + m * 16 + lrow;
#pragma unroll
    for (int j = 0; j < 4; ++j)
#pragma unroll
      for (int n = 0; n < 2; ++n)
        G[(long long)(row + j) * 1024 + colg[n]] =
            f2bf((acc[m][n][j] + bvv[n]) * (1.f / 32.f));
  }
}

// ---------------------------------------------------------------------------
// gemm_sz2: merged scores+zT, 128x64 tiles, occ-6, 2112 wgs (8.25/CU supply).
//   wg < 1088: scores — z = wg/272, t in [0,272): bi = (sqrt(4t+1)-1)/2,
//              bj = t - bi(bi+1), bj < 2(bi+1) (finer causal trim than 128^2).
//              scores[z] tile (bi*128 rows, bj*64 cols) = G[z] @ ybf[z]^T.
//   wg >= 1088: zT — lwg: bi=lwg>>7 (8 x 128-row tiles), bj=lwg&127 (64-col),
//              zT = WvoT @ ybf^T (ldc 8192).
// ---------------------------------------------------------------------------
__global__ __launch_bounds__(256, 6)
void gemm_sz2(const short* __restrict__ G, const short* __restrict__ ybf,
              const short* __restrict__ WvoT, short* __restrict__ scores,
              short* __restrict__ zT)
{
  const int orig = blockIdx.x;                  // 2112 wgs
  const int xcd = orig & 7, idx8 = orig >> 3;
  const int wg = xcd * 264 + idx8;              // q8=264

  const short *A, *B; short* C; int ldc, bi, bj;
  if (wg < 1088) {
    const int z = wg / 272, t = wg - z * 272;
    int b = (int)((__fsqrt_rn(4.f * (float)t + 1.f) - 1.f) * 0.5f);
    if ((b + 1) * (b + 2) <= t) ++b;            // float-edge fixups
    if (b * (b + 1) > t) --b;
    bi = b; bj = t - b * (b + 1);
    A = G + (long long)z * 2048 * 1024;
    B = ybf + (long long)z * 2048 * 1024;
    C = scores + (long long)z * 2048 * 2048;
    ldc = 2048;
  } else {
    const int lwg = wg - 1088;
    bi = lwg >> 7; bj = lwg & 127;
    A = WvoT; B = ybf; C = zT; ldc = 8192;
  }

  __shared__ __align__(16) short lA[128 * 64];  // 16 KB
  __shared__ __align__(16) short lB[64 * 64];   // 8 KB

  const int tid = threadIdx.x, wave = tid >> 6, lane = tid & 63;
  const int wr = wave >> 1, wc = wave & 1;
  const int brow = bi * 128, bcol = bj * 64;
  const int fr = lane & 15, h = lane >> 4;

  const int ck0 = ((h ^ (fr & 7))) * 8;
  const int swc = ((tid & 7) ^ ((tid >> 3) & 7)) * 8;
  const short* pA = A + (long long)(brow + (tid >> 3)) * 1024 + swc;
  const short* pB = B + (long long)(bcol + (tid >> 3)) * 1024 + swc;

  f32x4 acc[4][2] = {};

  for (int t = 0; t < 16; ++t) {
    const long long ko = (long long)t * 64;
#pragma unroll
    for (int j = 0; j < 4; ++j)
      gl_lds16(pA + (long long)(j * 32) * 1024 + ko, &lA[j * 2048 + tid * 8]);
#pragma unroll
    for (int j = 0; j < 2; ++j)
      gl_lds16(pB + (long long)(j * 32) * 1024 + ko, &lB[j * 2048 + tid * 8]);
    __syncthreads();

    bf16x8 af[4], bg[2];
#pragma unroll
    for (int m = 0; m < 4; ++m)
      af[m] = *(const bf16x8*)&lA[(wr * 64 + m * 16 + fr) * 64 + ck0];
#pragma unroll
    for (int n = 0; n < 2; ++n)
      bg[n] = *(const bf16x8*)&lB[(wc * 32 + n * 16 + fr) * 64 + ck0];
#pragma unroll
    for (int m = 0; m < 4; ++m)
#pragma unroll
      for (int n = 0; n < 2; ++n)
        acc[m][n] = __builtin_amdgcn_mfma_f32_16x16x32_bf16(af[m], bg[n], acc[m][n], 0, 0, 0);
#pragma unroll
    for (int m = 0; m < 4; ++m)
      af[m] = *(const bf16x8*)&lA[((wr * 64 + m * 16 + fr) * 64 + ck0) ^ 32];
#pragma unroll
    for (int n = 0; n < 2; ++n)
      bg[n] = *(const bf16x8*)&lB[((wc * 32 + n * 16 + fr) * 64 + ck0) ^ 32];
#pragma unroll
    for (int m = 0; m < 4; ++m)
#pragma unroll
      for (int n = 0; n < 2; ++n)
        acc[m][n] = __builtin_amdgcn_mfma_f32_16x16x32_bf16(af[m], bg[n], acc[m][n], 0, 0, 0);
    __syncthreads();
  }

  const int lrow = h * 4;
  int colg[2];
#pragma unroll
  for (int n = 0; n < 2; ++n) colg[n] = bcol + wc * 32 + n * 16 + fr;
#pragma unroll
  for (int m = 0; m < 4; ++m) {
    const int row = brow + wr * 64 + m * 16 + lrow;
#pragma unroll
    for (int j = 0; j < 4; ++j)
#pragma unroll
      for (int n = 0; n < 2; ++n)
        C[(long long)(row + j) * ldc + colg[n]] = f2bf(acc[m][n][j]);
  }
}

// ===========================================================================
// PV: 64x64 tiles, occ-6, 2048 wgs, parity-interleaved causal decode (R23:
// removed PV from top-5). bias = bo + bvWo (bv@Wo accumulated via atomics).
// ===========================================================================
__global__ __launch_bounds__(256, 6)
void gemm_pv(const short* __restrict__ scores, const short* __restrict__ zT,
             float* __restrict__ out, const float* __restrict__ bo,
             const float* __restrict__ bvWo)
{
  const int orig = blockIdx.x;                 // 2048 wgs
  const int xcd = orig & 7, idx8 = orig >> 3;  // idx8 in [0,256)
  const int z = xcd >> 1;                      // batch
  const int bi = ((idx8 >> 4) << 1) | (xcd & 1);   // 0..31, parity-interleaved
  const int bj = idx8 & 15;                        // 0..15

  const short* A = scores + (long long)z * 2048 * 2048;
  const int nt = bi + 1;                       // kend = (bi+1)*64, causal

  __shared__ __align__(16) short lA[64 * 64];  // 8 KB
  __shared__ __align__(16) short lB[64 * 64];  // 8 KB

  const int tid = threadIdx.x, wave = tid >> 6, lane = tid & 63;
  const int wm = wave >> 1, wn = wave & 1;
  const int brow = bi * 64, bcol = bj * 64;
  const int fr = lane & 15, h = lane >> 4;

  const int ck0 = ((h ^ (fr & 7))) * 8;
  const int swc = ((tid & 7) ^ ((tid >> 3) & 7)) * 8;
  const short* pA = A + (long long)(brow + (tid >> 3)) * 2048 + swc;
  const short* pB = zT + (long long)(bcol + (tid >> 3)) * 8192 + z * 2048 + swc;

  f32x4 acc[2][2] = {};

  for (int t = 0; t < nt; ++t) {
    const long long ko = (long long)t * 64;
#pragma unroll
    for (int j = 0; j < 2; ++j)
      gl_lds16(pA + (long long)(j * 32) * 2048 + ko, &lA[j * 2048 + tid * 8]);
#pragma unroll
    for (int j = 0; j < 2; ++j)
      gl_lds16(pB + (long long)(j * 32) * 8192 + ko, &lB[j * 2048 + tid * 8]);
    __syncthreads();

    bf16x8 af[2], bg[2];
#pragma unroll
    for (int m = 0; m < 2; ++m)
      af[m] = *(const bf16x8*)&lA[(wm * 32 + m * 16 + fr) * 64 + ck0];
#pragma unroll
    for (int n = 0; n < 2; ++n)
      bg[n] = *(const bf16x8*)&lB[(wn * 32 + n * 16 + fr) * 64 + ck0];
#pragma unroll
    for (int m = 0; m < 2; ++m)
#pragma unroll
      for (int n = 0; n < 2; ++n)
        acc[m][n] = __builtin_amdgcn_mfma_f32_16x16x32_bf16(af[m], bg[n], acc[m][n], 0, 0, 0);
#pragma unroll
    for (int m = 0; m < 2; ++m)
      af[m] = *(const bf16x8*)&lA[((wm * 32 + m * 16 + fr) * 64 + ck0) ^ 32];
#pragma unroll
    for (int n = 0; n < 2; ++n)
      bg[n] = *(const bf16x8*)&lB[((wn * 32 + n * 16 + fr) * 64 + ck0) ^ 32];
#pragma unroll
    for (int m = 0; m < 2; ++m)
#pragma unroll
      for (int n = 0; n < 2; ++n)
        acc[m][n] = __builtin_amdgcn_mfma_f32_16x16x32_bf16(af[m], bg[n], acc[m][n], 0, 0, 0);
    __syncthreads();
  }

  const int lrow = h * 4;
  int colg[2]; float bvv[2];
#pragma unroll
  for (int n = 0; n < 2; ++n) {
    colg[n] = bcol + wn * 32 + n * 16 + fr;
    bvv[n] = bo[colg[n]] + bvWo[colg[n]];
  }
#pragma unroll
  for (int m = 0; m < 2; ++m) {
    const int row = brow + wm * 32 + m * 16 + lrow;
#pragma unroll
    for (int j = 0; j < 4; ++j)
#pragma unroll
      for (int n = 0; n < 2; ++n)
        out[(long long)(z * 2048 + row + j) * 1024 + colg[n]] = acc[m][n][j] + bvv[n];
  }
}

// ---------------------------------------------------------------------------
// Causal-trimmed softmax (wlim 64-aligned for 64-row PV tiles).
__global__ __launch_bounds__(256)
void softmax_causal_bf16_k(short* __restrict__ sc)
{
  const int T = 2048;
  const long long row = blockIdx.x;
  const int t = (int)(row & (T - 1));
  short* ps = sc + row * (long long)T;
  const int tid = threadIdx.x, wave = tid >> 6, lane = tid & 63;
  const int c0 = tid * 8;
  const int wlim = ((t >> 6) + 1) << 6;

  bf16x8 v = {};
  if (c0 <= t) v = *(const bf16x8*)&ps[c0];
  float x[8];
#pragma unroll
  for (int j = 0; j < 8; ++j) x[j] = bf2f(v[j]);

  float mx = -3.0e38f;
#pragma unroll
  for (int j = 0; j < 8; ++j) if (c0 + j <= t) mx = fmaxf(mx, x[j]);
#pragma unroll
  for (int o = 32; o; o >>= 1) mx = fmaxf(mx, __shfl_xor(mx, o, 64));
  __shared__ float red[8];
  if (lane == 0) red[wave] = mx;
  __syncthreads();
  const float M = fmaxf(fmaxf(red[0], red[1]), fmaxf(red[2], red[3]));

  float e[8], s = 0.f;
#pragma unroll
  for (int j = 0; j < 8; ++j) { e[j] = (c0 + j <= t) ? __expf(x[j] - M) : 0.f; s += e[j]; }
#pragma unroll
  for (int o = 32; o; o >>= 1) s += __shfl_xor(s, o, 64);
  if (lane == 0) red[4 + wave] = s;
  __syncthreads();
  const float inv = 1.f / (red[4] + red[5] + red[6] + red[7]);

  if (c0 < wlim) {
    bf16x8 ov;
#pragma unroll
    for (int j = 0; j < 8; ++j) ov[j] = f2bf(e[j] * inv);
    *(bf16x8*)&ps[c0] = ov;
  }
}

// ---------------------------------------------------------------------------
// cvt_all: ALL independent prep work in one dispatch (9280 wgs):
//   wg <  4096: y fp32 -> ybf (8-elem vectorized chunks)
//   wg <  8192: weight tile job (z<4 layout of old cvt_w: Wq/Wk plain,
//               Wo transpose -> WoT, Wv plain)
//   wg <  9216: wkbq GEMV row (wvec = Wk @ bq, fp32)
//   wg <  9280: bias_fold (bvWo += bv[16-row-block] @ Wo, atomics;
//               bvWo pre-zeroed via hipMemsetAsync)
// ---------------------------------------------------------------------------
__global__ __launch_bounds__(256)
void cvt_all(const float* __restrict__ y, const float* __restrict__ Wq,
             const float* __restrict__ Wk, const float* __restrict__ Wo,
             const float* __restrict__ Wv, const float* __restrict__ bq,
             const float* __restrict__ bv,
             short* __restrict__ ybf, short* __restrict__ WqBf,
             short* __restrict__ WkBf, short* __restrict__ WoT,
             short* __restrict__ WvBf, float* __restrict__ wvec,
             float* __restrict__ bvWo)
{
  const int wg = blockIdx.x, tid = threadIdx.x;
  __shared__ float tile[32][33];
  __shared__ float red[4];

  if (wg < 4096) {                    // ---- y convert
    const long long i = (long long)wg * 256 + tid;
    const float4 v0 = ((const float4*)y)[i * 2];
    const float4 v1 = ((const float4*)y)[i * 2 + 1];
    bf16x8 o;
    o[0] = f2bf(v0.x); o[1] = f2bf(v0.y); o[2] = f2bf(v0.z); o[3] = f2bf(v0.w);
    o[4] = f2bf(v1.x); o[5] = f2bf(v1.y); o[6] = f2bf(v1.z); o[7] = f2bf(v1.w);
    ((bf16x8*)ybf)[i] = o;
  } else if (wg < 8192) {             // ---- weight converts
    const int lwg = wg - 4096;
    const int bx = lwg & 31, by = (lwg >> 5) & 31, bz = lwg >> 10;
    const int tx = tid & 31, ty = tid >> 5;
    const int r0 = by * 32, c0 = bx * 32;
    if (bz != 2) {
      const float* in = (bz == 0) ? Wq : (bz == 1 ? Wk : Wv);
      short* out      = (bz == 0) ? WqBf : (bz == 1 ? WkBf : WvBf);
#pragma unroll
      for (int i = 0; i < 4; ++i)
        out[(long long)(r0 + ty + 8 * i) * 1024 + c0 + tx] =
            f2bf(in[(long long)(r0 + ty + 8 * i) * 1024 + c0 + tx]);
    } else {
#pragma unroll
      for (int i = 0; i < 4; ++i)
        tile[ty + 8 * i][tx] = Wo[(long long)(r0 + ty + 8 * i) * 1024 + c0 + tx];
      __syncthreads();
#pragma unroll
      for (int i = 0; i < 4; ++i)
        WoT[(long long)(c0 + ty + 8 * i) * 1024 + r0 + tx] = f2bf(tile[tx][ty + 8 * i]);
    }
  } else if (wg < 9216) {             // ---- wkbq GEMV
    const int row = wg - 8192;
    const float4 a = ((const float4*)(Wk + (long long)row * 1024))[tid];
    const float4 b = ((const float4*)bq)[tid];
    float s = a.x * b.x + a.y * b.y + a.z * b.z + a.w * b.w;
#pragma unroll
    for (int o = 32; o; o >>= 1) s += __shfl_xor(s, o, 64);
    if ((tid & 63) == 0) red[tid >> 6] = s;
    __syncthreads();
    if (tid == 0) wvec[row] = red[0] + red[1] + red[2] + red[3];
  } else {                            // ---- bias fold (bvWo pre-zeroed)
    const int r0 = (wg - 9216) * 16;
    const int c4 = tid;
    float4 acc = make_float4(0.f, 0.f, 0.f, 0.f);
    for (int r = 0; r < 16; ++r) {
      const float s = bv[r0 + r];
      const float4 w = ((const float4*)(Wo + (long long)(r0 + r) * 1024))[c4];
      acc.x += s * w.x; acc.y += s * w.y; acc.z += s * w.z; acc.w += s * w.w;
    }
    atomicAdd(&bvWo[c4 * 4 + 0], acc.x);
    atomicAdd(&bvWo[c4 * 4 + 1], acc.y);
    atomicAdd(&bvWo[c4 * 4 + 2], acc.z);
    atomicAdd(&bvWo[c4 * 4 + 3], acc.w);
  }
}

// ---------------------------------------------------------------------------
extern "C" void kernel_launch(void* const* d_in, const int* in_sizes, int n_in,
                              void* d_out, int out_size, void* d_ws, size_t ws_size,
                              hipStream_t stream)
{
  (void)in_sizes; (void)n_in; (void)out_size; (void)ws_size;
  const float* y  = (const float*)d_in[0];
  const float* Wq = (const float*)d_in[1];
  const float* bq = (const float*)d_in[2];
  const float* Wk = (const float*)d_in[3];
  const float* bk = (const float*)d_in[4];
  const float* Wv = (const float*)d_in[5];
  const float* bv = (const float*)d_in[6];
  const float* Wo = (const float*)d_in[7];
  const float* bo = (const float*)d_in[8];
  float* out = (float*)d_out;
  (void)bk;   // bk only contributes row-constant score terms -> softmax-invariant

  const int T = 2048;
  const long long MT = 8192;                          // B*T
  const long long MM = 1048576;                       // 1024*1024

  // workspace layout (shorts); ~124 MB
  short* ws    = (short*)d_ws;
  short* ybf   = ws;                                  // 16 MB
  short* WqBf  = ybf + MT * 1024;                     // 2 MB each
  short* WkBf  = WqBf + MM;
  short* WoT   = WkBf + MM;
  short* WvBf  = WoT + MM;
  short* MTb   = WvBf + MM;                           // (Wk Wq^T) bf16
  short* WvoT  = MTb + MM;                            // ((Wv Wo)^T) bf16
  short* G     = WvoT + MM;                           // 8192x1024 bf16
  short* zT    = G + MT * 1024;                       // 1024x8192 bf16
  short* scores = zT + MT * 1024;                     // 4*T*T bf16 (32 MB)
  float* bvWo  = (float*)(scores + 4ll * T * T);      // 1024 fp32
  float* wvec  = bvWo + 1024;                         // 1024 fp32
  float* partM = wvec + 1024;                         // 4 x 1M fp32 (16 MB)
  float* partW = partM + 4ll * MM;                    // 4 x 1M fp32 (16 MB)

  // 0. zero the bias accumulator (graph-safe stream op)
  hipMemsetAsync(bvWo, 0, 1024 * sizeof(float), stream);

  // 1. ALL independent prep in one dispatch
  cvt_all<<<9280, 256, 0, stream>>>(y, Wq, Wk, Wo, Wv, bq, bv,
                                    ybf, WqBf, WkBf, WoT, WvBf, wvec, bvWo);

  // 2. both weight GEMMs (split-K x4 each) in one dispatch + one combine
  gemm_ww<<<512, 256, 0, stream>>>(WkBf, WqBf, WoT, WvBf, partM, partW);
  combine_ww<<<2048, 256, 0, stream>>>(partM, partW, MTb, WvoT);

  // 3. G = (y @ M + w)/32 : 128x64 occ-6, 1024 wgs
  gemm_g2<<<1024, 256, 0, stream>>>(ybf, MTb, G, wvec);

  // 4. merged scores (triangular 1088) + zT (1024): 2112 wgs, occ-6
  gemm_sz2<<<2112, 256, 0, stream>>>(G, ybf, WvoT, scores, zT);

  // 5. causal softmax in place
  softmax_causal_bf16_k<<<(int)MT, 256, 0, stream>>>(scores);

  // 6. out = P @ z + (bo + bv@Wo) : 64x64 occ-6, 2048 wgs
  gemm_pv<<<2048, 256, 0, stream>>>(scores, zT, out, bo, bvWo);
}

// Round 9
// 161.374 us; speedup vs baseline: 1.1958x; 1.0078x over previous
//
#include <hip/hip_runtime.h>
#include <hip/hip_bf16.h>
#include <cstdint>

#define DEVI __device__ __forceinline__

typedef __attribute__((ext_vector_type(8))) short bf16x8;
typedef __attribute__((ext_vector_type(4))) short bf16x4;
typedef __attribute__((ext_vector_type(4))) float f32x4;

DEVI short f2bf(float f) {
  unsigned u = __float_as_uint(f);
  u += 0x7fff + ((u >> 16) & 1);   // round-to-nearest-even
  return (short)(u >> 16);
}
DEVI float bf2f(short s) { return __uint_as_float(((unsigned)(unsigned short)s) << 16); }

DEVI void gl_lds16(const short* g, short* l) {
  __builtin_amdgcn_global_load_lds((const __attribute__((address_space(1))) unsigned*)g,
                                   (__attribute__((address_space(3))) unsigned*)l, 16, 0, 0);
}

// ===========================================================================
// Occupancy ladder (R20-R24, measured): occ-2 dbuf 372-614 TF; occ-4 SB
// 662-715; occ-6 SB = occ-4 (54us plateau, lever saturated at R24).
// R25: the plateau correlates with FETCH 92.7MB vs 34MB unique (2.7x):
// per-XCD working set (full z triangle: G_z 4MB + ybf_z 4MB = 8MB) thrashes
// the 4MB per-XCD L2; in an SB loop every K-step pays the miss latency at
// the vmcnt(0) barrier. Fix: 2D-banded triangular decode (bi-bands of 4 x
// bj-blocks of 8 -> ~2MB working set, L2-resident).
// ===========================================================================

// ---------------------------------------------------------------------------
// gemm_ww: BOTH split-K weight precomputes in one dispatch (512 wgs).
//   job 0: partM[z] = WkBf @ WqBf^T  (k-quarter z)
//   job 1: partW[z] = WoT  @ WvBf^T
// ---------------------------------------------------------------------------
__global__ __launch_bounds__(256, 4)
void gemm_ww(const short* __restrict__ WkBf, const short* __restrict__ WqBf,
             const short* __restrict__ WoT, const short* __restrict__ WvBf,
             float* __restrict__ partM, float* __restrict__ partW)
{
  const int orig = blockIdx.x;                  // 512 wgs
  const int xcd = orig & 7, idx8 = orig >> 3;
  const int wg = xcd * 64 + idx8;               // q8=64
  const int job = wg >> 8, rem = wg & 255;
  const int z = rem >> 6, t = rem & 63;
  const int bi = t >> 3, bj = t & 7;

  const short* A = job ? WoT  : WkBf;
  const short* B = job ? WvBf : WqBf;
  float* Cf = (job ? partW : partM) + (long long)z * 1048576;

  __shared__ __align__(16) short lA[128 * 64];  // 16 KB
  __shared__ __align__(16) short lB[128 * 64];  // 16 KB

  const int tid = threadIdx.x, wave = tid >> 6, lane = tid & 63;
  const int wr = wave >> 1, wc = wave & 1;
  const int brow = bi * 128, bcol = bj * 128;
  const int fr = lane & 15, h = lane >> 4;

  const int ck0 = ((h ^ (fr & 7))) * 8;
  const int swc = ((tid & 7) ^ ((tid >> 3) & 7)) * 8;
  const short* pA = A + (long long)(brow + (tid >> 3)) * 1024 + swc;
  const short* pB = B + (long long)(bcol + (tid >> 3)) * 1024 + swc;

  f32x4 acc[4][4] = {};
  const long long ko0 = (long long)z * 256;

  for (int t2 = 0; t2 < 4; ++t2) {
    const long long ko = ko0 + t2 * 64;
#pragma unroll
    for (int j = 0; j < 4; ++j)
      gl_lds16(pA + (long long)(j * 32) * 1024 + ko, &lA[j * 2048 + tid * 8]);
#pragma unroll
    for (int j = 0; j < 4; ++j)
      gl_lds16(pB + (long long)(j * 32) * 1024 + ko, &lB[j * 2048 + tid * 8]);
    __syncthreads();

    bf16x8 af[4], bg[4];
#pragma unroll
    for (int m = 0; m < 4; ++m)
      af[m] = *(const bf16x8*)&lA[(wr * 64 + m * 16 + fr) * 64 + ck0];
#pragma unroll
    for (int n = 0; n < 4; ++n)
      bg[n] = *(const bf16x8*)&lB[(wc * 64 + n * 16 + fr) * 64 + ck0];
#pragma unroll
    for (int m = 0; m < 4; ++m)
#pragma unroll
      for (int n = 0; n < 4; ++n)
        acc[m][n] = __builtin_amdgcn_mfma_f32_16x16x32_bf16(af[m], bg[n], acc[m][n], 0, 0, 0);
#pragma unroll
    for (int m = 0; m < 4; ++m)
      af[m] = *(const bf16x8*)&lA[((wr * 64 + m * 16 + fr) * 64 + ck0) ^ 32];
#pragma unroll
    for (int n = 0; n < 4; ++n)
      bg[n] = *(const bf16x8*)&lB[((wc * 64 + n * 16 + fr) * 64 + ck0) ^ 32];
#pragma unroll
    for (int m = 0; m < 4; ++m)
#pragma unroll
      for (int n = 0; n < 4; ++n)
        acc[m][n] = __builtin_amdgcn_mfma_f32_16x16x32_bf16(af[m], bg[n], acc[m][n], 0, 0, 0);
    __syncthreads();
  }

  const int lrow = h * 4;
#pragma unroll
  for (int m = 0; m < 4; ++m) {
    const int row = brow + wr * 64 + m * 16 + lrow;
#pragma unroll
    for (int j = 0; j < 4; ++j)
#pragma unroll
      for (int n = 0; n < 4; ++n)
        Cf[(long long)(row + j) * 1024 + bcol + wc * 64 + n * 16 + fr] = acc[m][n][j];
  }
}

// combine both split-K results: wg<1024 -> MTb, else WvoT (1M elems each)
__global__ __launch_bounds__(256)
void combine_ww(const float* __restrict__ partM, const float* __restrict__ partW,
                short* __restrict__ MTb, short* __restrict__ WvoT)
{
  const int wg = blockIdx.x;
  const float* p = (wg < 1024) ? partM : partW;
  short* out = (wg < 1024) ? MTb : WvoT;
  const long long i = (long long)(wg & 1023) * 256 + threadIdx.x;  // float4 idx
  const float4 a = ((const float4*)p)[i];
  const float4 b = ((const float4*)(p + 1048576))[i];
  const float4 c = ((const float4*)(p + 2097152))[i];
  const float4 d = ((const float4*)(p + 3145728))[i];
  bf16x4 o;
  o[0] = f2bf(a.x + b.x + c.x + d.x);
  o[1] = f2bf(a.y + b.y + c.y + d.y);
  o[2] = f2bf(a.z + b.z + c.z + d.z);
  o[3] = f2bf(a.w + b.w + c.w + d.w);
  ((bf16x4*)out)[i] = o;
}

// ---------------------------------------------------------------------------
// gemm_g2: G = (ybf @ MTb^T + wvec)/32. 128x64 tiles, occ-6, 1024 wgs.
// (per-XCD working set: 8 A-panels 2MB + MTb 2MB = 4MB — at capacity, OK)
// ---------------------------------------------------------------------------
__global__ __launch_bounds__(256, 6)
void gemm_g2(const short* __restrict__ ybf, const short* __restrict__ MTb,
             short* __restrict__ G, const float* __restrict__ wvec)
{
  const int orig = blockIdx.x;                  // 1024 wgs
  const int xcd = orig & 7, idx8 = orig >> 3;
  const int wg = xcd * 128 + idx8;              // q8=128
  const int bi = wg >> 4, bj = wg & 15;         // 64 row-tiles x 16 col-tiles

  __shared__ __align__(16) short lA[128 * 64];  // 16 KB
  __shared__ __align__(16) short lB[64 * 64];   // 8 KB

  const int tid = threadIdx.x, wave = tid >> 6, lane = tid & 63;
  const int wr = wave >> 1, wc = wave & 1;
  const int brow = bi * 128, bcol = bj * 64;
  const int fr = lane & 15, h = lane >> 4;

  const int ck0 = ((h ^ (fr & 7))) * 8;
  const int swc = ((tid & 7) ^ ((tid >> 3) & 7)) * 8;
  const short* pA = ybf + (long long)(brow + (tid >> 3)) * 1024 + swc;
  const short* pB = MTb + (long long)(bcol + (tid >> 3)) * 1024 + swc;

  f32x4 acc[4][2] = {};

  for (int t = 0; t < 16; ++t) {
    const long long ko = (long long)t * 64;
#pragma unroll
    for (int j = 0; j < 4; ++j)
      gl_lds16(pA + (long long)(j * 32) * 1024 + ko, &lA[j * 2048 + tid * 8]);
#pragma unroll
    for (int j = 0; j < 2; ++j)
      gl_lds16(pB + (long long)(j * 32) * 1024 + ko, &lB[j * 2048 + tid * 8]);
    __syncthreads();

    bf16x8 af[4], bg[2];
#pragma unroll
    for (int m = 0; m < 4; ++m)
      af[m] = *(const bf16x8*)&lA[(wr * 64 + m * 16 + fr) * 64 + ck0];
#pragma unroll
    for (int n = 0; n < 2; ++n)
      bg[n] = *(const bf16x8*)&lB[(wc * 32 + n * 16 + fr) * 64 + ck0];
#pragma unroll
    for (int m = 0; m < 4; ++m)
#pragma unroll
      for (int n = 0; n < 2; ++n)
        acc[m][n] = __builtin_amdgcn_mfma_f32_16x16x32_bf16(af[m], bg[n], acc[m][n], 0, 0, 0);
#pragma unroll
    for (int m = 0; m < 4; ++m)
      af[m] = *(const bf16x8*)&lA[((wr * 64 + m * 16 + fr) * 64 + ck0) ^ 32];
#pragma unroll
    for (int n = 0; n < 2; ++n)
      bg[n] = *(const bf16x8*)&lB[((wc * 32 + n * 16 + fr) * 64 + ck0) ^ 32];
#pragma unroll
    for (int m = 0; m < 4; ++m)
#pragma unroll
      for (int n = 0; n < 2; ++n)
        acc[m][n] = __builtin_amdgcn_mfma_f32_16x16x32_bf16(af[m], bg[n], acc[m][n], 0, 0, 0);
    __syncthreads();
  }

  const int lrow = h * 4;
  int colg[2]; float bvv[2];
#pragma unroll
  for (int n = 0; n < 2; ++n) {
    colg[n] = bcol + wc * 32 + n * 16 + fr;
    bvv[n] = wvec[colg[n]];
  }
#pragma unroll
  for (int m = 0; m < 4; ++m) {
    const int row = brow + wr * 64 + m * 16 + lrow;
#pragma unroll
    for (int j = 0; j < 4; ++j)
#pragma unroll
      for (int n = 0; n < 2; ++n)
        G[(long long)(row + j) * 1024 + colg[n]] =
            f2bf((acc[m][n][j] + bvv[n]) * (1.f / 32.f));
  }
}

// ---------------------------------------------------------------------------
// gemm_sz2: merged scores+zT, 128x64 tiles, occ-6, 2112 wgs.
// R25: scores decode is 2D-BANDED for L2 residency. Per z, tiles (bi<16,
// bj<2(bi+1)) enumerated as: bi-bands of 4 (k=0..3, boundaries 16k^2+4k),
// within band: full col-blocks of 8 (cb<k: 32 tiles each), then the ragged
// diagonal block (20 tiles, rows give 2/4/6/8 cols). Working set per XCD
// window: 4 A-panels (1MB) + 8 B-panels (1MB) << 4MB L2.
//   wg >= 1088: zT — bi=lwg>>7, bj=lwg&127: zT = WvoT @ ybf^T (ldc 8192);
//   working set = WvoT 2MB resident + streaming B. Already L2-fit.
// ---------------------------------------------------------------------------
__global__ __launch_bounds__(256, 6)
void gemm_sz2(const short* __restrict__ G, const short* __restrict__ ybf,
              const short* __restrict__ WvoT, short* __restrict__ scores,
              short* __restrict__ zT)
{
  const int orig = blockIdx.x;                  // 2112 wgs
  const int xcd = orig & 7, idx8 = orig >> 3;
  const int wg = xcd * 264 + idx8;              // q8=264

  const short *A, *B; short* C; int ldc, bi, bj;
  if (wg < 1088) {
    const int z = wg / 272, t = wg - z * 272;
    // banded decode: k = band (4 bi-rows), u = index within band
    const int k = (t >= 20) + (t >= 72) + (t >= 156);
    const int u = t - (16 * k * k + 4 * k);
    int r, col;
    if (u < 32 * k) {                 // full 8-col blocks
      const int cb = u >> 5, w = u & 31;
      r = w >> 3; col = cb * 8 + (w & 7);
    } else {                          // ragged diagonal block (2/4/6/8 cols)
      const int u2 = u - 32 * k;
      r = (u2 >= 2) + (u2 >= 6) + (u2 >= 12);
      const int cum = (r == 0) ? 0 : (r == 1) ? 2 : (r == 2) ? 6 : 12;
      col = 8 * k + (u2 - cum);
    }
    bi = 4 * k + r; bj = col;
    A = G + (long long)z * 2048 * 1024;
    B = ybf + (long long)z * 2048 * 1024;
    C = scores + (long long)z * 2048 * 2048;
    ldc = 2048;
  } else {
    const int lwg = wg - 1088;
    bi = lwg >> 7; bj = lwg & 127;
    A = WvoT; B = ybf; C = zT; ldc = 8192;
  }

  __shared__ __align__(16) short lA[128 * 64];  // 16 KB
  __shared__ __align__(16) short lB[64 * 64];   // 8 KB

  const int tid = threadIdx.x, wave = tid >> 6, lane = tid & 63;
  const int wr = wave >> 1, wc = wave & 1;
  const int brow = bi * 128, bcol = bj * 64;
  const int fr = lane & 15, h = lane >> 4;

  const int ck0 = ((h ^ (fr & 7))) * 8;
  const int swc = ((tid & 7) ^ ((tid >> 3) & 7)) * 8;
  const short* pA = A + (long long)(brow + (tid >> 3)) * 1024 + swc;
  const short* pB = B + (long long)(bcol + (tid >> 3)) * 1024 + swc;

  f32x4 acc[4][2] = {};

  for (int t = 0; t < 16; ++t) {
    const long long ko = (long long)t * 64;
#pragma unroll
    for (int j = 0; j < 4; ++j)
      gl_lds16(pA + (long long)(j * 32) * 1024 + ko, &lA[j * 2048 + tid * 8]);
#pragma unroll
    for (int j = 0; j < 2; ++j)
      gl_lds16(pB + (long long)(j * 32) * 1024 + ko, &lB[j * 2048 + tid * 8]);
    __syncthreads();

    bf16x8 af[4], bg[2];
#pragma unroll
    for (int m = 0; m < 4; ++m)
      af[m] = *(const bf16x8*)&lA[(wr * 64 + m * 16 + fr) * 64 + ck0];
#pragma unroll
    for (int n = 0; n < 2; ++n)
      bg[n] = *(const bf16x8*)&lB[(wc * 32 + n * 16 + fr) * 64 + ck0];
#pragma unroll
    for (int m = 0; m < 4; ++m)
#pragma unroll
      for (int n = 0; n < 2; ++n)
        acc[m][n] = __builtin_amdgcn_mfma_f32_16x16x32_bf16(af[m], bg[n], acc[m][n], 0, 0, 0);
#pragma unroll
    for (int m = 0; m < 4; ++m)
      af[m] = *(const bf16x8*)&lA[((wr * 64 + m * 16 + fr) * 64 + ck0) ^ 32];
#pragma unroll
    for (int n = 0; n < 2; ++n)
      bg[n] = *(const bf16x8*)&lB[((wc * 32 + n * 16 + fr) * 64 + ck0) ^ 32];
#pragma unroll
    for (int m = 0; m < 4; ++m)
#pragma unroll
      for (int n = 0; n < 2; ++n)
        acc[m][n] = __builtin_amdgcn_mfma_f32_16x16x32_bf16(af[m], bg[n], acc[m][n], 0, 0, 0);
    __syncthreads();
  }

  const int lrow = h * 4;
  int colg[2];
#pragma unroll
  for (int n = 0; n < 2; ++n) colg[n] = bcol + wc * 32 + n * 16 + fr;
#pragma unroll
  for (int m = 0; m < 4; ++m) {
    const int row = brow + wr * 64 + m * 16 + lrow;
#pragma unroll
    for (int j = 0; j < 4; ++j)
#pragma unroll
      for (int n = 0; n < 2; ++n)
        C[(long long)(row + j) * ldc + colg[n]] = f2bf(acc[m][n][j]);
  }
}

// ===========================================================================
// PV: 64x64 tiles, occ-6, 2048 wgs, parity-interleaved causal decode.
// bj-inner ordering keeps zT cols (2MB) L2-resident, A streams — already fit.
// ===========================================================================
__global__ __launch_bounds__(256, 6)
void gemm_pv(const short* __restrict__ scores, const short* __restrict__ zT,
             float* __restrict__ out, const float* __restrict__ bo,
             const float* __restrict__ bvWo)
{
  const int orig = blockIdx.x;                 // 2048 wgs
  const int xcd = orig & 7, idx8 = orig >> 3;  // idx8 in [0,256)
  const int z = xcd >> 1;                      // batch
  const int bi = ((idx8 >> 4) << 1) | (xcd & 1);   // 0..31, parity-interleaved
  const int bj = idx8 & 15;                        // 0..15

  const short* A = scores + (long long)z * 2048 * 2048;
  const int nt = bi + 1;                       // kend = (bi+1)*64, causal

  __shared__ __align__(16) short lA[64 * 64];  // 8 KB
  __shared__ __align__(16) short lB[64 * 64];  // 8 KB

  const int tid = threadIdx.x, wave = tid >> 6, lane = tid & 63;
  const int wm = wave >> 1, wn = wave & 1;
  const int brow = bi * 64, bcol = bj * 64;
  const int fr = lane & 15, h = lane >> 4;

  const int ck0 = ((h ^ (fr & 7))) * 8;
  const int swc = ((tid & 7) ^ ((tid >> 3) & 7)) * 8;
  const short* pA = A + (long long)(brow + (tid >> 3)) * 2048 + swc;
  const short* pB = zT + (long long)(bcol + (tid >> 3)) * 8192 + z * 2048 + swc;

  f32x4 acc[2][2] = {};

  for (int t = 0; t < nt; ++t) {
    const long long ko = (long long)t * 64;
#pragma unroll
    for (int j = 0; j < 2; ++j)
      gl_lds16(pA + (long long)(j * 32) * 2048 + ko, &lA[j * 2048 + tid * 8]);
#pragma unroll
    for (int j = 0; j < 2; ++j)
      gl_lds16(pB + (long long)(j * 32) * 8192 + ko, &lB[j * 2048 + tid * 8]);
    __syncthreads();

    bf16x8 af[2], bg[2];
#pragma unroll
    for (int m = 0; m < 2; ++m)
      af[m] = *(const bf16x8*)&lA[(wm * 32 + m * 16 + fr) * 64 + ck0];
#pragma unroll
    for (int n = 0; n < 2; ++n)
      bg[n] = *(const bf16x8*)&lB[(wn * 32 + n * 16 + fr) * 64 + ck0];
#pragma unroll
    for (int m = 0; m < 2; ++m)
#pragma unroll
      for (int n = 0; n < 2; ++n)
        acc[m][n] = __builtin_amdgcn_mfma_f32_16x16x32_bf16(af[m], bg[n], acc[m][n], 0, 0, 0);
#pragma unroll
    for (int m = 0; m < 2; ++m)
      af[m] = *(const bf16x8*)&lA[((wm * 32 + m * 16 + fr) * 64 + ck0) ^ 32];
#pragma unroll
    for (int n = 0; n < 2; ++n)
      bg[n] = *(const bf16x8*)&lB[((wn * 32 + n * 16 + fr) * 64 + ck0) ^ 32];
#pragma unroll
    for (int m = 0; m < 2; ++m)
#pragma unroll
      for (int n = 0; n < 2; ++n)
        acc[m][n] = __builtin_amdgcn_mfma_f32_16x16x32_bf16(af[m], bg[n], acc[m][n], 0, 0, 0);
    __syncthreads();
  }

  const int lrow = h * 4;
  int colg[2]; float bvv[2];
#pragma unroll
  for (int n = 0; n < 2; ++n) {
    colg[n] = bcol + wn * 32 + n * 16 + fr;
    bvv[n] = bo[colg[n]] + bvWo[colg[n]];
  }
#pragma unroll
  for (int m = 0; m < 2; ++m) {
    const int row = brow + wm * 32 + m * 16 + lrow;
#pragma unroll
    for (int j = 0; j < 4; ++j)
#pragma unroll
      for (int n = 0; n < 2; ++n)
        out[(long long)(z * 2048 + row + j) * 1024 + colg[n]] = acc[m][n][j] + bvv[n];
  }
}

// ---------------------------------------------------------------------------
// Causal-trimmed softmax (wlim 64-aligned for 64-row PV tiles).
__global__ __launch_bounds__(256)
void softmax_causal_bf16_k(short* __restrict__ sc)
{
  const int T = 2048;
  const long long row = blockIdx.x;
  const int t = (int)(row & (T - 1));
  short* ps = sc + row * (long long)T;
  const int tid = threadIdx.x, wave = tid >> 6, lane = tid & 63;
  const int c0 = tid * 8;
  const int wlim = ((t >> 6) + 1) << 6;

  bf16x8 v = {};
  if (c0 <= t) v = *(const bf16x8*)&ps[c0];
  float x[8];
#pragma unroll
  for (int j = 0; j < 8; ++j) x[j] = bf2f(v[j]);

  float mx = -3.0e38f;
#pragma unroll
  for (int j = 0; j < 8; ++j) if (c0 + j <= t) mx = fmaxf(mx, x[j]);
#pragma unroll
  for (int o = 32; o; o >>= 1) mx = fmaxf(mx, __shfl_xor(mx, o, 64));
  __shared__ float red[8];
  if (lane == 0) red[wave] = mx;
  __syncthreads();
  const float M = fmaxf(fmaxf(red[0], red[1]), fmaxf(red[2], red[3]));

  float e[8], s = 0.f;
#pragma unroll
  for (int j = 0; j < 8; ++j) { e[j] = (c0 + j <= t) ? __expf(x[j] - M) : 0.f; s += e[j]; }
#pragma unroll
  for (int o = 32; o; o >>= 1) s += __shfl_xor(s, o, 64);
  if (lane == 0) red[4 + wave] = s;
  __syncthreads();
  const float inv = 1.f / (red[4] + red[5] + red[6] + red[7]);

  if (c0 < wlim) {
    bf16x8 ov;
#pragma unroll
    for (int j = 0; j < 8; ++j) ov[j] = f2bf(e[j] * inv);
    *(bf16x8*)&ps[c0] = ov;
  }
}

// ---------------------------------------------------------------------------
// cvt_all: ALL independent prep work in one dispatch (9280 wgs):
//   wg <  4096: y fp32 -> ybf
//   wg <  8192: weight converts (Wq/Wk/Wv plain, Wo transpose)
//   wg <  9216: wkbq GEMV row (wvec = Wk @ bq)
//   wg <  9280: bias_fold (bvWo += bv block @ Wo, atomics; pre-zeroed)
// ---------------------------------------------------------------------------
__global__ __launch_bounds__(256)
void cvt_all(const float* __restrict__ y, const float* __restrict__ Wq,
             const float* __restrict__ Wk, const float* __restrict__ Wo,
             const float* __restrict__ Wv, const float* __restrict__ bq,
             const float* __restrict__ bv,
             short* __restrict__ ybf, short* __restrict__ WqBf,
             short* __restrict__ WkBf, short* __restrict__ WoT,
             short* __restrict__ WvBf, float* __restrict__ wvec,
             float* __restrict__ bvWo)
{
  const int wg = blockIdx.x, tid = threadIdx.x;
  __shared__ float tile[32][33];
  __shared__ float red[4];

  if (wg < 4096) {                    // ---- y convert
    const long long i = (long long)wg * 256 + tid;
    const float4 v0 = ((const float4*)y)[i * 2];
    const float4 v1 = ((const float4*)y)[i * 2 + 1];
    bf16x8 o;
    o[0] = f2bf(v0.x); o[1] = f2bf(v0.y); o[2] = f2bf(v0.z); o[3] = f2bf(v0.w);
    o[4] = f2bf(v1.x); o[5] = f2bf(v1.y); o[6] = f2bf(v1.z); o[7] = f2bf(v1.w);
    ((bf16x8*)ybf)[i] = o;
  } else if (wg < 8192) {             // ---- weight converts
    const int lwg = wg - 4096;
    const int bx = lwg & 31, by = (lwg >> 5) & 31, bz = lwg >> 10;
    const int tx = tid & 31, ty = tid >> 5;
    const int r0 = by * 32, c0 = bx * 32;
    if (bz != 2) {
      const float* in = (bz == 0) ? Wq : (bz == 1 ? Wk : Wv);
      short* out      = (bz == 0) ? WqBf : (bz == 1 ? WkBf : WvBf);
#pragma unroll
      for (int i = 0; i < 4; ++i)
        out[(long long)(r0 + ty + 8 * i) * 1024 + c0 + tx] =
            f2bf(in[(long long)(r0 + ty + 8 * i) * 1024 + c0 + tx]);
    } else {
#pragma unroll
      for (int i = 0; i < 4; ++i)
        tile[ty + 8 * i][tx] = Wo[(long long)(r0 + ty + 8 * i) * 1024 + c0 + tx];
      __syncthreads();
#pragma unroll
      for (int i = 0; i < 4; ++i)
        WoT[(long long)(c0 + ty + 8 * i) * 1024 + r0 + tx] = f2bf(tile[tx][ty + 8 * i]);
    }
  } else if (wg < 9216) {             // ---- wkbq GEMV
    const int row = wg - 8192;
    const float4 a = ((const float4*)(Wk + (long long)row * 1024))[tid];
    const float4 b = ((const float4*)bq)[tid];
    float s = a.x * b.x + a.y * b.y + a.z * b.z + a.w * b.w;
#pragma unroll
    for (int o = 32; o; o >>= 1) s += __shfl_xor(s, o, 64);
    if ((tid & 63) == 0) red[tid >> 6] = s;
    __syncthreads();
    if (tid == 0) wvec[row] = red[0] + red[1] + red[2] + red[3];
  } else {                            // ---- bias fold (bvWo pre-zeroed)
    const int r0 = (wg - 9216) * 16;
    const int c4 = tid;
    float4 acc = make_float4(0.f, 0.f, 0.f, 0.f);
    for (int r = 0; r < 16; ++r) {
      const float s = bv[r0 + r];
      const float4 w = ((const float4*)(Wo + (long long)(r0 + r) * 1024))[c4];
      acc.x += s * w.x; acc.y += s * w.y; acc.z += s * w.z; acc.w += s * w.w;
    }
    atomicAdd(&bvWo[c4 * 4 + 0], acc.x);
    atomicAdd(&bvWo[c4 * 4 + 1], acc.y);
    atomicAdd(&bvWo[c4 * 4 + 2], acc.z);
    atomicAdd(&bvWo[c4 * 4 + 3], acc.w);
  }
}

// ---------------------------------------------------------------------------
extern "C" void kernel_launch(void* const* d_in, const int* in_sizes, int n_in,
                              void* d_out, int out_size, void* d_ws, size_t ws_size,
                              hipStream_t stream)
{
  (void)in_sizes; (void)n_in; (void)out_size; (void)ws_size;
  const float* y  = (const float*)d_in[0];
  const float* Wq = (const float*)d_in[1];
  const float* bq = (const float*)d_in[2];
  const float* Wk = (const float*)d_in[3];
  const float* bk = (const float*)d_in[4];
  const float* Wv = (const float*)d_in[5];
  const float* bv = (const float*)d_in[6];
  const float* Wo = (const float*)d_in[7];
  const float* bo = (const float*)d_in[8];
  float* out = (float*)d_out;
  (void)bk;   // bk only contributes row-constant score terms -> softmax-invariant

  const int T = 2048;
  const long long MT = 8192;                          // B*T
  const long long MM = 1048576;                       // 1024*1024

  // workspace layout (shorts); ~124 MB
  short* ws    = (short*)d_ws;
  short* ybf   = ws;                                  // 16 MB
  short* WqBf  = ybf + MT * 1024;                     // 2 MB each
  short* WkBf  = WqBf + MM;
  short* WoT   = WkBf + MM;
  short* WvBf  = WoT + MM;
  short* MTb   = WvBf + MM;                           // (Wk Wq^T) bf16
  short* WvoT  = MTb + MM;                            // ((Wv Wo)^T) bf16
  short* G     = WvoT + MM;                           // 8192x1024 bf16
  short* zT    = G + MT * 1024;                       // 1024x8192 bf16
  short* scores = zT + MT * 1024;                     // 4*T*T bf16 (32 MB)
  float* bvWo  = (float*)(scores + 4ll * T * T);      // 1024 fp32
  float* wvec  = bvWo + 1024;                         // 1024 fp32
  float* partM = wvec + 1024;                         // 4 x 1M fp32 (16 MB)
  float* partW = partM + 4ll * MM;                    // 4 x 1M fp32 (16 MB)

  // 0. zero the bias accumulator (graph-safe stream op)
  hipMemsetAsync(bvWo, 0, 1024 * sizeof(float), stream);

  // 1. ALL independent prep in one dispatch
  cvt_all<<<9280, 256, 0, stream>>>(y, Wq, Wk, Wo, Wv, bq, bv,
                                    ybf, WqBf, WkBf, WoT, WvBf, wvec, bvWo);

  // 2. both weight GEMMs (split-K x4 each) in one dispatch + one combine
  gemm_ww<<<512, 256, 0, stream>>>(WkBf, WqBf, WoT, WvBf, partM, partW);
  combine_ww<<<2048, 256, 0, stream>>>(partM, partW, MTb, WvoT);

  // 3. G = (y @ M + w)/32 : 128x64 occ-6, 1024 wgs
  gemm_g2<<<1024, 256, 0, stream>>>(ybf, MTb, G, wvec);

  // 4. merged scores (banded triangular 1088) + zT (1024): 2112 wgs, occ-6
  gemm_sz2<<<2112, 256, 0, stream>>>(G, ybf, WvoT, scores, zT);

  // 5. causal softmax in place
  softmax_causal_bf16_k<<<(int)MT, 256, 0, stream>>>(scores);

  // 6. out = P @ z + (bo + bv@Wo) : 64x64 occ-6, 2048 wgs
  gemm_pv<<<2048, 256, 0, stream>>>(scores, zT, out, bo, bvWo);
}

// Round 10
// 159.748 us; speedup vs baseline: 1.2080x; 1.0102x over previous
//
#include <hip/hip_runtime.h>
#include <hip/hip_bf16.h>
#include <cstdint>

#define DEVI __device__ __forceinline__

typedef __attribute__((ext_vector_type(8))) short bf16x8;
typedef __attribute__((ext_vector_type(4))) short bf16x4;
typedef __attribute__((ext_vector_type(4))) float f32x4;

DEVI short f2bf(float f) {
  unsigned u = __float_as_uint(f);
  u += 0x7fff + ((u >> 16) & 1);   // round-to-nearest-even
  return (short)(u >> 16);
}
DEVI float bf2f(short s) { return __uint_as_float(((unsigned)(unsigned short)s) << 16); }

DEVI void gl_lds16(const short* g, short* l) {
  __builtin_amdgcn_global_load_lds((const __attribute__((address_space(1))) unsigned*)g,
                                   (__attribute__((address_space(3))) unsigned*)l, 16, 0, 0);
}

// ===========================================================================
// Ladder status (R20-R25, measured):
//   occ-2 dbuf(drain0) 372-614 TF | occ-4 SB 662 | occ-6 SB 662 (saturated)
//   R25 banding: FETCH 92.7->90MB (null — concurrency width ~192 tiles >>
//   32-tile band window; L2 locality unfixable by ordering at occ-6).
// R26: the one shared defect of ALL variants is the implicit vmcnt(0) in
// __syncthreads draining the prefetch every K-step (m97-ceiling mechanism;
// m233: that drain = ~72% of a 2-phase loop). gemm_sz2 now: dbuf 48KB occ-3
// + raw s_barrier + COUNTED s_waitcnt vmcnt(6) — prefetch stays in flight
// across the barrier (m218: counted-vs-drain0 = +38-73%). g2/PV = controls.
// ===========================================================================

// ---------------------------------------------------------------------------
// gemm_ww: BOTH split-K weight precomputes in one dispatch (512 wgs).
//   job 0: partM[z] = WkBf @ WqBf^T  (k-quarter z)
//   job 1: partW[z] = WoT  @ WvBf^T
// ---------------------------------------------------------------------------
__global__ __launch_bounds__(256, 4)
void gemm_ww(const short* __restrict__ WkBf, const short* __restrict__ WqBf,
             const short* __restrict__ WoT, const short* __restrict__ WvBf,
             float* __restrict__ partM, float* __restrict__ partW)
{
  const int orig = blockIdx.x;                  // 512 wgs
  const int xcd = orig & 7, idx8 = orig >> 3;
  const int wg = xcd * 64 + idx8;               // q8=64
  const int job = wg >> 8, rem = wg & 255;
  const int z = rem >> 6, t = rem & 63;
  const int bi = t >> 3, bj = t & 7;

  const short* A = job ? WoT  : WkBf;
  const short* B = job ? WvBf : WqBf;
  float* Cf = (job ? partW : partM) + (long long)z * 1048576;

  __shared__ __align__(16) short lA[128 * 64];  // 16 KB
  __shared__ __align__(16) short lB[128 * 64];  // 16 KB

  const int tid = threadIdx.x, wave = tid >> 6, lane = tid & 63;
  const int wr = wave >> 1, wc = wave & 1;
  const int brow = bi * 128, bcol = bj * 128;
  const int fr = lane & 15, h = lane >> 4;

  const int ck0 = ((h ^ (fr & 7))) * 8;
  const int swc = ((tid & 7) ^ ((tid >> 3) & 7)) * 8;
  const short* pA = A + (long long)(brow + (tid >> 3)) * 1024 + swc;
  const short* pB = B + (long long)(bcol + (tid >> 3)) * 1024 + swc;

  f32x4 acc[4][4] = {};
  const long long ko0 = (long long)z * 256;

  for (int t2 = 0; t2 < 4; ++t2) {
    const long long ko = ko0 + t2 * 64;
#pragma unroll
    for (int j = 0; j < 4; ++j)
      gl_lds16(pA + (long long)(j * 32) * 1024 + ko, &lA[j * 2048 + tid * 8]);
#pragma unroll
    for (int j = 0; j < 4; ++j)
      gl_lds16(pB + (long long)(j * 32) * 1024 + ko, &lB[j * 2048 + tid * 8]);
    __syncthreads();

    bf16x8 af[4], bg[4];
#pragma unroll
    for (int m = 0; m < 4; ++m)
      af[m] = *(const bf16x8*)&lA[(wr * 64 + m * 16 + fr) * 64 + ck0];
#pragma unroll
    for (int n = 0; n < 4; ++n)
      bg[n] = *(const bf16x8*)&lB[(wc * 64 + n * 16 + fr) * 64 + ck0];
#pragma unroll
    for (int m = 0; m < 4; ++m)
#pragma unroll
      for (int n = 0; n < 4; ++n)
        acc[m][n] = __builtin_amdgcn_mfma_f32_16x16x32_bf16(af[m], bg[n], acc[m][n], 0, 0, 0);
#pragma unroll
    for (int m = 0; m < 4; ++m)
      af[m] = *(const bf16x8*)&lA[((wr * 64 + m * 16 + fr) * 64 + ck0) ^ 32];
#pragma unroll
    for (int n = 0; n < 4; ++n)
      bg[n] = *(const bf16x8*)&lB[((wc * 64 + n * 16 + fr) * 64 + ck0) ^ 32];
#pragma unroll
    for (int m = 0; m < 4; ++m)
#pragma unroll
      for (int n = 0; n < 4; ++n)
        acc[m][n] = __builtin_amdgcn_mfma_f32_16x16x32_bf16(af[m], bg[n], acc[m][n], 0, 0, 0);
    __syncthreads();
  }

  const int lrow = h * 4;
#pragma unroll
  for (int m = 0; m < 4; ++m) {
    const int row = brow + wr * 64 + m * 16 + lrow;
#pragma unroll
    for (int j = 0; j < 4; ++j)
#pragma unroll
      for (int n = 0; n < 4; ++n)
        Cf[(long long)(row + j) * 1024 + bcol + wc * 64 + n * 16 + fr] = acc[m][n][j];
  }
}

// combine both split-K results: wg<1024 -> MTb, else WvoT (1M elems each)
__global__ __launch_bounds__(256)
void combine_ww(const float* __restrict__ partM, const float* __restrict__ partW,
                short* __restrict__ MTb, short* __restrict__ WvoT)
{
  const int wg = blockIdx.x;
  const float* p = (wg < 1024) ? partM : partW;
  short* out = (wg < 1024) ? MTb : WvoT;
  const long long i = (long long)(wg & 1023) * 256 + threadIdx.x;  // float4 idx
  const float4 a = ((const float4*)p)[i];
  const float4 b = ((const float4*)(p + 1048576))[i];
  const float4 c = ((const float4*)(p + 2097152))[i];
  const float4 d = ((const float4*)(p + 3145728))[i];
  bf16x4 o;
  o[0] = f2bf(a.x + b.x + c.x + d.x);
  o[1] = f2bf(a.y + b.y + c.y + d.y);
  o[2] = f2bf(a.z + b.z + c.z + d.z);
  o[3] = f2bf(a.w + b.w + c.w + d.w);
  ((bf16x4*)out)[i] = o;
}

// ---------------------------------------------------------------------------
// gemm_g2: G = (ybf @ MTb^T + wvec)/32. 128x64 tiles, occ-6, 1024 wgs.
// (control this round: unchanged SB structure)
// ---------------------------------------------------------------------------
__global__ __launch_bounds__(256, 6)
void gemm_g2(const short* __restrict__ ybf, const short* __restrict__ MTb,
             short* __restrict__ G, const float* __restrict__ wvec)
{
  const int orig = blockIdx.x;                  // 1024 wgs
  const int xcd = orig & 7, idx8 = orig >> 3;
  const int wg = xcd * 128 + idx8;              // q8=128
  const int bi = wg >> 4, bj = wg & 15;         // 64 row-tiles x 16 col-tiles

  __shared__ __align__(16) short lA[128 * 64];  // 16 KB
  __shared__ __align__(16) short lB[64 * 64];   // 8 KB

  const int tid = threadIdx.x, wave = tid >> 6, lane = tid & 63;
  const int wr = wave >> 1, wc = wave & 1;
  const int brow = bi * 128, bcol = bj * 64;
  const int fr = lane & 15, h = lane >> 4;

  const int ck0 = ((h ^ (fr & 7))) * 8;
  const int swc = ((tid & 7) ^ ((tid >> 3) & 7)) * 8;
  const short* pA = ybf + (long long)(brow + (tid >> 3)) * 1024 + swc;
  const short* pB = MTb + (long long)(bcol + (tid >> 3)) * 1024 + swc;

  f32x4 acc[4][2] = {};

  for (int t = 0; t < 16; ++t) {
    const long long ko = (long long)t * 64;
#pragma unroll
    for (int j = 0; j < 4; ++j)
      gl_lds16(pA + (long long)(j * 32) * 1024 + ko, &lA[j * 2048 + tid * 8]);
#pragma unroll
    for (int j = 0; j < 2; ++j)
      gl_lds16(pB + (long long)(j * 32) * 1024 + ko, &lB[j * 2048 + tid * 8]);
    __syncthreads();

    bf16x8 af[4], bg[2];
#pragma unroll
    for (int m = 0; m < 4; ++m)
      af[m] = *(const bf16x8*)&lA[(wr * 64 + m * 16 + fr) * 64 + ck0];
#pragma unroll
    for (int n = 0; n < 2; ++n)
      bg[n] = *(const bf16x8*)&lB[(wc * 32 + n * 16 + fr) * 64 + ck0];
#pragma unroll
    for (int m = 0; m < 4; ++m)
#pragma unroll
      for (int n = 0; n < 2; ++n)
        acc[m][n] = __builtin_amdgcn_mfma_f32_16x16x32_bf16(af[m], bg[n], acc[m][n], 0, 0, 0);
#pragma unroll
    for (int m = 0; m < 4; ++m)
      af[m] = *(const bf16x8*)&lA[((wr * 64 + m * 16 + fr) * 64 + ck0) ^ 32];
#pragma unroll
    for (int n = 0; n < 2; ++n)
      bg[n] = *(const bf16x8*)&lB[((wc * 32 + n * 16 + fr) * 64 + ck0) ^ 32];
#pragma unroll
    for (int m = 0; m < 4; ++m)
#pragma unroll
      for (int n = 0; n < 2; ++n)
        acc[m][n] = __builtin_amdgcn_mfma_f32_16x16x32_bf16(af[m], bg[n], acc[m][n], 0, 0, 0);
    __syncthreads();
  }

  const int lrow = h * 4;
  int colg[2]; float bvv[2];
#pragma unroll
  for (int n = 0; n < 2; ++n) {
    colg[n] = bcol + wc * 32 + n * 16 + fr;
    bvv[n] = wvec[colg[n]];
  }
#pragma unroll
  for (int m = 0; m < 4; ++m) {
    const int row = brow + wr * 64 + m * 16 + lrow;
#pragma unroll
    for (int j = 0; j < 4; ++j)
#pragma unroll
      for (int n = 0; n < 2; ++n)
        G[(long long)(row + j) * 1024 + colg[n]] =
            f2bf((acc[m][n][j] + bvv[n]) * (1.f / 32.f));
  }
}

// ---------------------------------------------------------------------------
// gemm_sz2: merged scores+zT, 128x64 tiles, 2112 wgs.
// R26: DOUBLE-buffered (48KB LDS, occ-3) with raw s_barrier + counted
// s_waitcnt vmcnt(6): the next tile's 6 gl_lds stay in flight across the
// barrier while the current tile computes. Epilogue step drains vmcnt(0).
// Hazards: buf overwritten at step t was last read at t-1 behind barrier-2;
// each wave's own vmcnt(6) before barrier-1 => its current-tile loads landed,
// barrier-1 => ALL waves' loads landed.
// Decode unchanged from R25 (banded triangular scores + zT).
// ---------------------------------------------------------------------------
__global__ __launch_bounds__(256, 3)
void gemm_sz2(const short* __restrict__ G, const short* __restrict__ ybf,
              const short* __restrict__ WvoT, short* __restrict__ scores,
              short* __restrict__ zT)
{
  const int orig = blockIdx.x;                  // 2112 wgs
  const int xcd = orig & 7, idx8 = orig >> 3;
  const int wg = xcd * 264 + idx8;              // q8=264

  const short *A, *B; short* C; int ldc, bi, bj;
  if (wg < 1088) {
    const int z = wg / 272, t = wg - z * 272;
    // banded decode: k = band (4 bi-rows), u = index within band
    const int k = (t >= 20) + (t >= 72) + (t >= 156);
    const int u = t - (16 * k * k + 4 * k);
    int r, col;
    if (u < 32 * k) {                 // full 8-col blocks
      const int cb = u >> 5, w = u & 31;
      r = w >> 3; col = cb * 8 + (w & 7);
    } else {                          // ragged diagonal block (2/4/6/8 cols)
      const int u2 = u - 32 * k;
      r = (u2 >= 2) + (u2 >= 6) + (u2 >= 12);
      const int cum = (r == 0) ? 0 : (r == 1) ? 2 : (r == 2) ? 6 : 12;
      col = 8 * k + (u2 - cum);
    }
    bi = 4 * k + r; bj = col;
    A = G + (long long)z * 2048 * 1024;
    B = ybf + (long long)z * 2048 * 1024;
    C = scores + (long long)z * 2048 * 2048;
    ldc = 2048;
  } else {
    const int lwg = wg - 1088;
    bi = lwg >> 7; bj = lwg & 127;
    A = WvoT; B = ybf; C = zT; ldc = 8192;
  }

  __shared__ __align__(16) short lA[2][128 * 64];  // 32 KB
  __shared__ __align__(16) short lB[2][64 * 64];   // 16 KB

  const int tid = threadIdx.x, wave = tid >> 6, lane = tid & 63;
  const int wr = wave >> 1, wc = wave & 1;
  const int brow = bi * 128, bcol = bj * 64;
  const int fr = lane & 15, h = lane >> 4;

  const int ck0 = ((h ^ (fr & 7))) * 8;
  const int swc = ((tid & 7) ^ ((tid >> 3) & 7)) * 8;
  const short* pA = A + (long long)(brow + (tid >> 3)) * 1024 + swc;
  const short* pB = B + (long long)(bcol + (tid >> 3)) * 1024 + swc;

  f32x4 acc[4][2] = {};

  auto stage = [&](int buf, int t) {            // 6 gl_lds (4 A + 2 B)
    const long long ko = (long long)t * 64;
#pragma unroll
    for (int j = 0; j < 4; ++j)
      gl_lds16(pA + (long long)(j * 32) * 1024 + ko, &lA[buf][j * 2048 + tid * 8]);
#pragma unroll
    for (int j = 0; j < 2; ++j)
      gl_lds16(pB + (long long)(j * 32) * 1024 + ko, &lB[buf][j * 2048 + tid * 8]);
  };

  stage(0, 0);
  int cur = 0;
  for (int t = 0; t < 16; ++t) {
    if (t < 15) {
      stage(cur ^ 1, t + 1);                    // prefetch: 6 more in flight
      asm volatile("s_waitcnt vmcnt(6)" ::: "memory");   // current 6 landed
    } else {
      asm volatile("s_waitcnt vmcnt(0)" ::: "memory");
    }
    __builtin_amdgcn_s_barrier();               // all waves' current landed
    asm volatile("" ::: "memory");

    const short* bufA = lA[cur];
    const short* bufB = lB[cur];
    bf16x8 af[4], bg[2];
#pragma unroll
    for (int m = 0; m < 4; ++m)
      af[m] = *(const bf16x8*)&bufA[(wr * 64 + m * 16 + fr) * 64 + ck0];
#pragma unroll
    for (int n = 0; n < 2; ++n)
      bg[n] = *(const bf16x8*)&bufB[(wc * 32 + n * 16 + fr) * 64 + ck0];
#pragma unroll
    for (int m = 0; m < 4; ++m)
#pragma unroll
      for (int n = 0; n < 2; ++n)
        acc[m][n] = __builtin_amdgcn_mfma_f32_16x16x32_bf16(af[m], bg[n], acc[m][n], 0, 0, 0);
#pragma unroll
    for (int m = 0; m < 4; ++m)
      af[m] = *(const bf16x8*)&bufA[((wr * 64 + m * 16 + fr) * 64 + ck0) ^ 32];
#pragma unroll
    for (int n = 0; n < 2; ++n)
      bg[n] = *(const bf16x8*)&bufB[((wc * 32 + n * 16 + fr) * 64 + ck0) ^ 32];
#pragma unroll
    for (int m = 0; m < 4; ++m)
#pragma unroll
      for (int n = 0; n < 2; ++n)
        acc[m][n] = __builtin_amdgcn_mfma_f32_16x16x32_bf16(af[m], bg[n], acc[m][n], 0, 0, 0);

    asm volatile("" ::: "memory");
    __builtin_amdgcn_s_barrier();               // reads done -> t+1 may overwrite
    cur ^= 1;
  }

  const int lrow = h * 4;
  int colg[2];
#pragma unroll
  for (int n = 0; n < 2; ++n) colg[n] = bcol + wc * 32 + n * 16 + fr;
#pragma unroll
  for (int m = 0; m < 4; ++m) {
    const int row = brow + wr * 64 + m * 16 + lrow;
#pragma unroll
    for (int j = 0; j < 4; ++j)
#pragma unroll
      for (int n = 0; n < 2; ++n)
        C[(long long)(row + j) * ldc + colg[n]] = f2bf(acc[m][n][j]);
  }
}

// ===========================================================================
// PV: 64x64 tiles, occ-6, 2048 wgs, parity-interleaved causal decode.
// (control this round: unchanged)
// ===========================================================================
__global__ __launch_bounds__(256, 6)
void gemm_pv(const short* __restrict__ scores, const short* __restrict__ zT,
             float* __restrict__ out, const float* __restrict__ bo,
             const float* __restrict__ bvWo)
{
  const int orig = blockIdx.x;                 // 2048 wgs
  const int xcd = orig & 7, idx8 = orig >> 3;  // idx8 in [0,256)
  const int z = xcd >> 1;                      // batch
  const int bi = ((idx8 >> 4) << 1) | (xcd & 1);   // 0..31, parity-interleaved
  const int bj = idx8 & 15;                        // 0..15

  const short* A = scores + (long long)z * 2048 * 2048;
  const int nt = bi + 1;                       // kend = (bi+1)*64, causal

  __shared__ __align__(16) short lA[64 * 64];  // 8 KB
  __shared__ __align__(16) short lB[64 * 64];  // 8 KB

  const int tid = threadIdx.x, wave = tid >> 6, lane = tid & 63;
  const int wm = wave >> 1, wn = wave & 1;
  const int brow = bi * 64, bcol = bj * 64;
  const int fr = lane & 15, h = lane >> 4;

  const int ck0 = ((h ^ (fr & 7))) * 8;
  const int swc = ((tid & 7) ^ ((tid >> 3) & 7)) * 8;
  const short* pA = A + (long long)(brow + (tid >> 3)) * 2048 + swc;
  const short* pB = zT + (long long)(bcol + (tid >> 3)) * 8192 + z * 2048 + swc;

  f32x4 acc[2][2] = {};

  for (int t = 0; t < nt; ++t) {
    const long long ko = (long long)t * 64;
#pragma unroll
    for (int j = 0; j < 2; ++j)
      gl_lds16(pA + (long long)(j * 32) * 2048 + ko, &lA[j * 2048 + tid * 8]);
#pragma unroll
    for (int j = 0; j < 2; ++j)
      gl_lds16(pB + (long long)(j * 32) * 8192 + ko, &lB[j * 2048 + tid * 8]);
    __syncthreads();

    bf16x8 af[2], bg[2];
#pragma unroll
    for (int m = 0; m < 2; ++m)
      af[m] = *(const bf16x8*)&lA[(wm * 32 + m * 16 + fr) * 64 + ck0];
#pragma unroll
    for (int n = 0; n < 2; ++n)
      bg[n] = *(const bf16x8*)&lB[(wn * 32 + n * 16 + fr) * 64 + ck0];
#pragma unroll
    for (int m = 0; m < 2; ++m)
#pragma unroll
      for (int n = 0; n < 2; ++n)
        acc[m][n] = __builtin_amdgcn_mfma_f32_16x16x32_bf16(af[m], bg[n], acc[m][n], 0, 0, 0);
#pragma unroll
    for (int m = 0; m < 2; ++m)
      af[m] = *(const bf16x8*)&lA[((wm * 32 + m * 16 + fr) * 64 + ck0) ^ 32];
#pragma unroll
    for (int n = 0; n < 2; ++n)
      bg[n] = *(const bf16x8*)&lB[((wn * 32 + n * 16 + fr) * 64 + ck0) ^ 32];
#pragma unroll
    for (int m = 0; m < 2; ++m)
#pragma unroll
      for (int n = 0; n < 2; ++n)
        acc[m][n] = __builtin_amdgcn_mfma_f32_16x16x32_bf16(af[m], bg[n], acc[m][n], 0, 0, 0);
    __syncthreads();
  }

  const int lrow = h * 4;
  int colg[2]; float bvv[2];
#pragma unroll
  for (int n = 0; n < 2; ++n) {
    colg[n] = bcol + wn * 32 + n * 16 + fr;
    bvv[n] = bo[colg[n]] + bvWo[colg[n]];
  }
#pragma unroll
  for (int m = 0; m < 2; ++m) {
    const int row = brow + wm * 32 + m * 16 + lrow;
#pragma unroll
    for (int j = 0; j < 4; ++j)
#pragma unroll
      for (int n = 0; n < 2; ++n)
        out[(long long)(z * 2048 + row + j) * 1024 + colg[n]] = acc[m][n][j] + bvv[n];
  }
}

// ---------------------------------------------------------------------------
// Causal-trimmed softmax (wlim 64-aligned for 64-row PV tiles).
__global__ __launch_bounds__(256)
void softmax_causal_bf16_k(short* __restrict__ sc)
{
  const int T = 2048;
  const long long row = blockIdx.x;
  const int t = (int)(row & (T - 1));
  short* ps = sc + row * (long long)T;
  const int tid = threadIdx.x, wave = tid >> 6, lane = tid & 63;
  const int c0 = tid * 8;
  const int wlim = ((t >> 6) + 1) << 6;

  bf16x8 v = {};
  if (c0 <= t) v = *(const bf16x8*)&ps[c0];
  float x[8];
#pragma unroll
  for (int j = 0; j < 8; ++j) x[j] = bf2f(v[j]);

  float mx = -3.0e38f;
#pragma unroll
  for (int j = 0; j < 8; ++j) if (c0 + j <= t) mx = fmaxf(mx, x[j]);
#pragma unroll
  for (int o = 32; o; o >>= 1) mx = fmaxf(mx, __shfl_xor(mx, o, 64));
  __shared__ float red[8];
  if (lane == 0) red[wave] = mx;
  __syncthreads();
  const float M = fmaxf(fmaxf(red[0], red[1]), fmaxf(red[2], red[3]));

  float e[8], s = 0.f;
#pragma unroll
  for (int j = 0; j < 8; ++j) { e[j] = (c0 + j <= t) ? __expf(x[j] - M) : 0.f; s += e[j]; }
#pragma unroll
  for (int o = 32; o; o >>= 1) s += __shfl_xor(s, o, 64);
  if (lane == 0) red[4 + wave] = s;
  __syncthreads();
  const float inv = 1.f / (red[4] + red[5] + red[6] + red[7]);

  if (c0 < wlim) {
    bf16x8 ov;
#pragma unroll
    for (int j = 0; j < 8; ++j) ov[j] = f2bf(e[j] * inv);
    *(bf16x8*)&ps[c0] = ov;
  }
}

// ---------------------------------------------------------------------------
// cvt_all: ALL independent prep work in one dispatch (9280 wgs):
//   wg <  4096: y fp32 -> ybf
//   wg <  8192: weight converts (Wq/Wk/Wv plain, Wo transpose)
//   wg <  9216: wkbq GEMV row (wvec = Wk @ bq)
//   wg <  9280: bias_fold (bvWo += bv block @ Wo, atomics; pre-zeroed)
// ---------------------------------------------------------------------------
__global__ __launch_bounds__(256)
void cvt_all(const float* __restrict__ y, const float* __restrict__ Wq,
             const float* __restrict__ Wk, const float* __restrict__ Wo,
             const float* __restrict__ Wv, const float* __restrict__ bq,
             const float* __restrict__ bv,
             short* __restrict__ ybf, short* __restrict__ WqBf,
             short* __restrict__ WkBf, short* __restrict__ WoT,
             short* __restrict__ WvBf, float* __restrict__ wvec,
             float* __restrict__ bvWo)
{
  const int wg = blockIdx.x, tid = threadIdx.x;
  __shared__ float tile[32][33];
  __shared__ float red[4];

  if (wg < 4096) {                    // ---- y convert
    const long long i = (long long)wg * 256 + tid;
    const float4 v0 = ((const float4*)y)[i * 2];
    const float4 v1 = ((const float4*)y)[i * 2 + 1];
    bf16x8 o;
    o[0] = f2bf(v0.x); o[1] = f2bf(v0.y); o[2] = f2bf(v0.z); o[3] = f2bf(v0.w);
    o[4] = f2bf(v1.x); o[5] = f2bf(v1.y); o[6] = f2bf(v1.z); o[7] = f2bf(v1.w);
    ((bf16x8*)ybf)[i] = o;
  } else if (wg < 8192) {             // ---- weight converts
    const int lwg = wg - 4096;
    const int bx = lwg & 31, by = (lwg >> 5) & 31, bz = lwg >> 10;
    const int tx = tid & 31, ty = tid >> 5;
    const int r0 = by * 32, c0 = bx * 32;
    if (bz != 2) {
      const float* in = (bz == 0) ? Wq : (bz == 1 ? Wk : Wv);
      short* out      = (bz == 0) ? WqBf : (bz == 1 ? WkBf : WvBf);
#pragma unroll
      for (int i = 0; i < 4; ++i)
        out[(long long)(r0 + ty + 8 * i) * 1024 + c0 + tx] =
            f2bf(in[(long long)(r0 + ty + 8 * i) * 1024 + c0 + tx]);
    } else {
#pragma unroll
      for (int i = 0; i < 4; ++i)
        tile[ty + 8 * i][tx] = Wo[(long long)(r0 + ty + 8 * i) * 1024 + c0 + tx];
      __syncthreads();
#pragma unroll
      for (int i = 0; i < 4; ++i)
        WoT[(long long)(c0 + ty + 8 * i) * 1024 + r0 + tx] = f2bf(tile[tx][ty + 8 * i]);
    }
  } else if (wg < 9216) {             // ---- wkbq GEMV
    const int row = wg - 8192;
    const float4 a = ((const float4*)(Wk + (long long)row * 1024))[tid];
    const float4 b = ((const float4*)bq)[tid];
    float s = a.x * b.x + a.y * b.y + a.z * b.z + a.w * b.w;
#pragma unroll
    for (int o = 32; o; o >>= 1) s += __shfl_xor(s, o, 64);
    if ((tid & 63) == 0) red[tid >> 6] = s;
    __syncthreads();
    if (tid == 0) wvec[row] = red[0] + red[1] + red[2] + red[3];
  } else {                            // ---- bias fold (bvWo pre-zeroed)
    const int r0 = (wg - 9216) * 16;
    const int c4 = tid;
    float4 acc = make_float4(0.f, 0.f, 0.f, 0.f);
    for (int r = 0; r < 16; ++r) {
      const float s = bv[r0 + r];
      const float4 w = ((const float4*)(Wo + (long long)(r0 + r) * 1024))[c4];
      acc.x += s * w.x; acc.y += s * w.y; acc.z += s * w.z; acc.w += s * w.w;
    }
    atomicAdd(&bvWo[c4 * 4 + 0], acc.x);
    atomicAdd(&bvWo[c4 * 4 + 1], acc.y);
    atomicAdd(&bvWo[c4 * 4 + 2], acc.z);
    atomicAdd(&bvWo[c4 * 4 + 3], acc.w);
  }
}

// ---------------------------------------------------------------------------
extern "C" void kernel_launch(void* const* d_in, const int* in_sizes, int n_in,
                              void* d_out, int out_size, void* d_ws, size_t ws_size,
                              hipStream_t stream)
{
  (void)in_sizes; (void)n_in; (void)out_size; (void)ws_size;
  const float* y  = (const float*)d_in[0];
  const float* Wq = (const float*)d_in[1];
  const float* bq = (const float*)d_in[2];
  const float* Wk = (const float*)d_in[3];
  const float* bk = (const float*)d_in[4];
  const float* Wv = (const float*)d_in[5];
  const float* bv = (const float*)d_in[6];
  const float* Wo = (const float*)d_in[7];
  const float* bo = (const float*)d_in[8];
  float* out = (float*)d_out;
  (void)bk;   // bk only contributes row-constant score terms -> softmax-invariant

  const int T = 2048;
  const long long MT = 8192;                          // B*T
  const long long MM = 1048576;                       // 1024*1024

  // workspace layout (shorts); ~124 MB
  short* ws    = (short*)d_ws;
  short* ybf   = ws;                                  // 16 MB
  short* WqBf  = ybf + MT * 1024;                     // 2 MB each
  short* WkBf  = WqBf + MM;
  short* WoT   = WkBf + MM;
  short* WvBf  = WoT + MM;
  short* MTb   = WvBf + MM;                           // (Wk Wq^T) bf16
  short* WvoT  = MTb + MM;                            // ((Wv Wo)^T) bf16
  short* G     = WvoT + MM;                           // 8192x1024 bf16
  short* zT    = G + MT * 1024;                       // 1024x8192 bf16
  short* scores = zT + MT * 1024;                     // 4*T*T bf16 (32 MB)
  float* bvWo  = (float*)(scores + 4ll * T * T);      // 1024 fp32
  float* wvec  = bvWo + 1024;                         // 1024 fp32
  float* partM = wvec + 1024;                         // 4 x 1M fp32 (16 MB)
  float* partW = partM + 4ll * MM;                    // 4 x 1M fp32 (16 MB)

  // 0. zero the bias accumulator (graph-safe stream op)
  hipMemsetAsync(bvWo, 0, 1024 * sizeof(float), stream);

  // 1. ALL independent prep in one dispatch
  cvt_all<<<9280, 256, 0, stream>>>(y, Wq, Wk, Wo, Wv, bq, bv,
                                    ybf, WqBf, WkBf, WoT, WvBf, wvec, bvWo);

  // 2. both weight GEMMs (split-K x4 each) in one dispatch + one combine
  gemm_ww<<<512, 256, 0, stream>>>(WkBf, WqBf, WoT, WvBf, partM, partW);
  combine_ww<<<2048, 256, 0, stream>>>(partM, partW, MTb, WvoT);

  // 3. G = (y @ M + w)/32 : 128x64 occ-6, 1024 wgs
  gemm_g2<<<1024, 256, 0, stream>>>(ybf, MTb, G, wvec);

  // 4. merged scores (banded triangular 1088) + zT (1024): 2112 wgs,
  //    counted-vmcnt dbuf occ-3
  gemm_sz2<<<2112, 256, 0, stream>>>(G, ybf, WvoT, scores, zT);

  // 5. causal softmax in place
  softmax_causal_bf16_k<<<(int)MT, 256, 0, stream>>>(scores);

  // 6. out = P @ z + (bo + bv@Wo) : 64x64 occ-6, 2048 wgs
  gemm_pv<<<2048, 256, 0, stream>>>(scores, zT, out, bo, bvWo);
}